// Round 1
// baseline (4527.879 us; speedup 1.0000x reference)
//
#include <hip/hip_runtime.h>
#include <math.h>

// ---------------- problem constants (match reference) ----------------
#define N_NODES 20000
#define N_EDGES 160000
#define G_GRAPHS 64
#define H_DIM 512
#define RH_DIM 128
#define NE_EXP 4
#define P_ROWS 20096   // 157 * 128, padded row count for GEMM tiles

// ---------------- GEMM config ----------------
#define BM 128
#define BN 128
#define BK 16
#define LDSA (BM + 4)  // pad to dodge LDS bank conflicts; keeps 16B alignment
#define LDSB (BN + 4)

// C = A1@W1 [+ A2@W2] + bias, optional relu.
// EPI: 0 = store to Cout
//      2 = Cout[r,c] += wcol[r*4] * v   (accumulating experts 1..3)
//      3 = Cout[r,c]  = wcol[r*4] * v   (expert 0, overwrites poison)
template<bool DUAL, bool RELU, int EPI>
__global__ __launch_bounds__(256)
void gemm_kernel(const float* __restrict__ A1, const float* __restrict__ W1,
                 const float* __restrict__ A2, const float* __restrict__ W2,
                 const float* __restrict__ bias, const float* __restrict__ wcol,
                 float* __restrict__ Cout, int Mstore, int Ncols, int Kdim)
{
    __shared__ float As[BK][LDSA];
    __shared__ float Bs[BK][LDSB];
    const int tid = threadIdx.x;
    const int tx = tid & 15;   // col group 0..15
    const int ty = tid >> 4;   // row group 0..15
    const int m0 = blockIdx.y * BM;
    const int n0 = blockIdx.x * BN;
    const int tx4 = tx * 4, ty4 = ty * 4;

    float acc[8][8];
#pragma unroll
    for (int i = 0; i < 8; ++i)
#pragma unroll
        for (int j = 0; j < 8; ++j) acc[i][j] = 0.f;

    const int npass = DUAL ? 2 : 1;
    for (int pass = 0; pass < npass; ++pass) {
        const float* __restrict__ A = pass ? A2 : A1;
        const float* __restrict__ W = pass ? W2 : W1;
        for (int kt = 0; kt < Kdim; kt += BK) {
            // ---- load A tile (BM x BK), store transposed As[k][m] ----
            {
                const int row = tid >> 2;   // 0..63
                const int kq  = tid & 3;    // 0..3 (each covers 4 k's)
#pragma unroll
                for (int p = 0; p < 2; ++p) {
                    const int r = row + p * 64;
                    const float4 v = *reinterpret_cast<const float4*>(
                        &A[(size_t)(m0 + r) * Kdim + kt + kq * 4]);
                    As[kq * 4 + 0][r] = v.x;
                    As[kq * 4 + 1][r] = v.y;
                    As[kq * 4 + 2][r] = v.z;
                    As[kq * 4 + 3][r] = v.w;
                }
            }
            // ---- load B tile (BK x BN) ----
            {
                const int krow = tid >> 5;  // 0..7
                const int nq   = tid & 31;  // 0..31
#pragma unroll
                for (int p = 0; p < 2; ++p) {
                    const int kk = krow + p * 8;
                    const float4 v = *reinterpret_cast<const float4*>(
                        &W[(size_t)(kt + kk) * Ncols + n0 + nq * 4]);
                    *reinterpret_cast<float4*>(&Bs[kk][nq * 4]) = v;
                }
            }
            __syncthreads();
#pragma unroll
            for (int k = 0; k < BK; ++k) {
                // split fragments (m: ty4 and 64+ty4, n: tx4 and 64+tx4)
                // spreads LDS reads over banks (2-way max -> free)
                const float4 a0 = *reinterpret_cast<const float4*>(&As[k][ty4]);
                const float4 a1 = *reinterpret_cast<const float4*>(&As[k][64 + ty4]);
                const float4 b0 = *reinterpret_cast<const float4*>(&Bs[k][tx4]);
                const float4 b1 = *reinterpret_cast<const float4*>(&Bs[k][64 + tx4]);
                const float av[8] = {a0.x, a0.y, a0.z, a0.w, a1.x, a1.y, a1.z, a1.w};
                const float bv[8] = {b0.x, b0.y, b0.z, b0.w, b1.x, b1.y, b1.z, b1.w};
#pragma unroll
                for (int i = 0; i < 8; ++i)
#pragma unroll
                    for (int j = 0; j < 8; ++j)
                        acc[i][j] = fmaf(av[i], bv[j], acc[i][j]);
            }
            __syncthreads();
        }
    }

    // ---- epilogue ----
#pragma unroll
    for (int i = 0; i < 8; ++i) {
        const int r = m0 + ((i < 4) ? (ty4 + i) : (64 + ty4 + (i - 4)));
        if (r >= Mstore) continue;
        float wrow = 0.f;
        if (EPI >= 2) wrow = wcol[(size_t)r * 4];
#pragma unroll
        for (int j = 0; j < 8; ++j) {
            const int c = n0 + ((j < 4) ? (tx4 + j) : (64 + tx4 + (j - 4)));
            float v = acc[i][j];
            if (bias != nullptr) v += bias[c];
            if (RELU) v = fmaxf(v, 0.f);
            const size_t off = (size_t)r * Ncols + c;
            if (EPI == 0) Cout[off] = v;
            else if (EPI == 2) Cout[off] += wrow * v;
            else /* EPI == 3 */ Cout[off] = wrow * v;
        }
    }
}

// t1 = relu(x[:,4:10] @ enc_W1 + enc_b1)
__global__ void encoder1_kernel(const float* __restrict__ x, const float* __restrict__ W1,
                                const float* __restrict__ b1, float* __restrict__ t1)
{
    const int idx = blockIdx.x * blockDim.x + threadIdx.x;
    if (idx >= N_NODES * H_DIM) return;
    const int i = idx / H_DIM, j = idx - i * H_DIM;
    const float* xr = &x[i * 16 + 4];
    float acc = b1[j];
#pragma unroll
    for (int k = 0; k < 6; ++k) acc = fmaf(xr[k], W1[k * H_DIM + j], acc);
    t1[idx] = fmaxf(acc, 0.f);
}

__global__ void zero_ints_kernel(int* __restrict__ p, int n)
{
    const int idx = blockIdx.x * blockDim.x + threadIdx.x;
    if (idx < n) p[idx] = 0;
}

// per-graph node/edge counts + in-degree
__global__ void count_kernel(const int* __restrict__ batch, const int* __restrict__ src,
                             const int* __restrict__ dst,
                             int* __restrict__ cnt_n, int* __restrict__ cnt_e,
                             int* __restrict__ deg)
{
    const int idx = blockIdx.x * blockDim.x + threadIdx.x;
    if (idx < N_NODES) atomicAdd(&cnt_n[batch[idx]], 1);
    if (idx < N_EDGES) {
        atomicAdd(&cnt_e[batch[src[idx]]], 1);
        atomicAdd(&deg[dst[idx]], 1);
    }
}

// 64 threads (one wave): log/normalize per-graph features
__global__ void stats_finalize_kernel(const int* __restrict__ cnt_n, const int* __restrict__ cnt_e,
                                      float* __restrict__ f_norm, float* __restrict__ size_norm)
{
    const int g = threadIdx.x;  // exactly 64
    const float nn = fmaxf((float)cnt_n[g], 1.0f);
    const float ee = (float)cnt_e[g];
    const float ln = logf(nn);
    const float le = log1pf(ee);
    float s0 = ln, s1 = le;
#pragma unroll
    for (int o = 32; o > 0; o >>= 1) { s0 += __shfl_xor(s0, o); s1 += __shfl_xor(s1, o); }
    const float m0 = s0 / 64.f, m1 = s1 / 64.f;
    const float d0 = ln - m0, d1 = le - m1;
    float v0 = d0 * d0, v1 = d1 * d1;
#pragma unroll
    for (int o = 32; o > 0; o >>= 1) { v0 += __shfl_xor(v0, o); v1 += __shfl_xor(v1, o); }
    const float sd0 = sqrtf(v0 / 64.f), sd1 = sqrtf(v1 / 64.f);
    float mn = ln, mx = ln;
#pragma unroll
    for (int o = 32; o > 0; o >>= 1) {
        mn = fminf(mn, __shfl_xor(mn, o));
        mx = fmaxf(mx, __shfl_xor(mx, o));
    }
    f_norm[g * 2 + 0] = d0 / (sd0 + 1e-6f);
    f_norm[g * 2 + 1] = d1 / (sd1 + 1e-6f);
    size_norm[g] = (ln - mn) / (mx - mn + 1e-6f);
}

// single-block exclusive scan of deg -> row_ptr (and duplicate into cursor)
__global__ void scan_kernel(const int* __restrict__ in, int* __restrict__ row_ptr,
                            int* __restrict__ cursor, int n)
{
    __shared__ int buf[1024];
    __shared__ int carry;
    const int tid = threadIdx.x;
    if (tid == 0) carry = 0;
    __syncthreads();
    for (int base = 0; base < n; base += 1024) {
        const int idx = base + tid;
        const int v = (idx < n) ? in[idx] : 0;
        buf[tid] = v;
        __syncthreads();
        for (int off2 = 1; off2 < 1024; off2 <<= 1) {
            const int t = (tid >= off2) ? buf[tid - off2] : 0;
            __syncthreads();
            buf[tid] += t;
            __syncthreads();
        }
        const int incl = buf[tid];
        const int excl = incl - v + carry;
        if (idx < n) { row_ptr[idx] = excl; cursor[idx] = excl; }
        const int total = buf[1023];
        __syncthreads();
        if (tid == 0) carry += total;
        __syncthreads();
    }
    if (tid == 0) row_ptr[n] = carry;
}

__global__ void scatter_kernel(const int* __restrict__ src, const int* __restrict__ dst,
                               int* __restrict__ cursor, int* __restrict__ csr_col)
{
    const int e = blockIdx.x * blockDim.x + threadIdx.x;
    if (e >= N_EDGES) return;
    const int d = dst[e];
    const int slot = atomicAdd(&cursor[d], 1);
    csr_col[slot] = src[e];
}

// sort each adjacency list ascending -> deterministic float-sum order
__global__ void sort_adj_kernel(const int* __restrict__ row_ptr, int* __restrict__ csr_col)
{
    const int i = blockIdx.x * blockDim.x + threadIdx.x;
    if (i >= N_NODES) return;
    const int b = row_ptr[i], e = row_ptr[i + 1];
    for (int p = b + 1; p < e; ++p) {
        const int key = csr_col[p];
        int q = p - 1;
        while (q >= b && csr_col[q] > key) { csr_col[q + 1] = csr_col[q]; --q; }
        csr_col[q + 1] = key;
    }
}

// agg[i,:] = sum over in-edges of z[src,:]   (one block per node, 2 cols/thread)
__global__ __launch_bounds__(256)
void aggregate_kernel(const float* __restrict__ z, const int* __restrict__ row_ptr,
                      const int* __restrict__ csr_col, float* __restrict__ agg)
{
    const int i = blockIdx.x;
    const int t = threadIdx.x;
    const int b = row_ptr[i], e = row_ptr[i + 1];
    float2 acc = make_float2(0.f, 0.f);
    const float2* z2 = reinterpret_cast<const float2*>(z);
    for (int p = b; p < e; ++p) {
        const int s = csr_col[p];
        const float2 v = z2[(size_t)s * 256 + t];
        acc.x += v.x; acc.y += v.y;
    }
    reinterpret_cast<float2*>(agg)[(size_t)i * 256 + t] = acc;
}

// router tail: +size-feature cols, +bias, LayerNorm, relu, 128x4 matmul,
// prior blend, softmax, top-2 renormalized -> weights[N,4]
__global__ __launch_bounds__(128)
void router_kernel(const float* __restrict__ rtmp, const int* __restrict__ batch,
                   const float* __restrict__ rW1, const float* __restrict__ rb1,
                   const float* __restrict__ lng, const float* __restrict__ lnb,
                   const float* __restrict__ rW2, const float* __restrict__ rb2,
                   const float* __restrict__ centers,
                   const float* __restrict__ f_norm, const float* __restrict__ size_norm,
                   float* __restrict__ weights)
{
    const int i = blockIdx.x;
    const int j = threadIdx.x;
    const int g = batch[i];
    const float f0 = f_norm[g * 2], f1 = f_norm[g * 2 + 1];
    float r = rtmp[(size_t)i * RH_DIM + j]
            + f0 * rW1[512 * RH_DIM + j] + f1 * rW1[513 * RH_DIM + j] + rb1[j];

    __shared__ float part[2];
    __shared__ float rbuf[RH_DIM];
    __shared__ float lbuf[4];
    const int lane = j & 63, wv = j >> 6;

    float s = r;
#pragma unroll
    for (int o = 32; o > 0; o >>= 1) s += __shfl_xor(s, o);
    if (lane == 0) part[wv] = s;
    __syncthreads();
    const float mean = (part[0] + part[1]) / 128.f;
    __syncthreads();
    const float d = r - mean;
    float v = d * d;
#pragma unroll
    for (int o = 32; o > 0; o >>= 1) v += __shfl_xor(v, o);
    if (lane == 0) part[wv] = v;
    __syncthreads();
    const float var = (part[0] + part[1]) / 128.f;
    const float rn = d / sqrtf(var + 1e-5f) * lng[j] + lnb[j];
    rbuf[j] = fmaxf(rn, 0.f);
    __syncthreads();

    if (j < 4) {
        float acc = rb2[j];
        for (int t = 0; t < RH_DIM; ++t) acc = fmaf(rbuf[t], rW2[t * 4 + j], acc);
        const float sn = size_norm[g];
        const float dd = sn - centers[j];
        lbuf[j] = 0.7f * acc + 0.3f * (-(dd * dd));  // (1-SPS)*logits + SPS*prior
    }
    __syncthreads();
    if (j == 0) {
        float p[4];
        const float mx = fmaxf(fmaxf(lbuf[0], lbuf[1]), fmaxf(lbuf[2], lbuf[3]));
#pragma unroll
        for (int c = 0; c < 4; ++c) p[c] = expf(lbuf[c] - mx);
        const float ssum = p[0] + p[1] + p[2] + p[3];
#pragma unroll
        for (int c = 0; c < 4; ++c) p[c] /= ssum;
        int i1 = 0;
#pragma unroll
        for (int c = 1; c < 4; ++c) if (p[c] > p[i1]) i1 = c;   // strict > : lowest idx on tie
        int i2 = -1;
#pragma unroll
        for (int c = 0; c < 4; ++c) {
            if (c == i1) continue;
            if (i2 < 0 || p[c] > p[i2]) i2 = c;
        }
        const float vs = p[i1] + p[i2] + 1e-8f;
        float wout[4] = {0.f, 0.f, 0.f, 0.f};
        wout[i1] = p[i1] / vs;
        wout[i2] = p[i2] / vs;
#pragma unroll
        for (int c = 0; c < 4; ++c) weights[(size_t)i * 4 + c] = wout[c];
    }
}

extern "C" void kernel_launch(void* const* d_in, const int* in_sizes, int n_in,
                              void* d_out, int out_size, void* d_ws, size_t ws_size,
                              hipStream_t stream)
{
    const float* x       = (const float*)d_in[0];
    const int*   ei      = (const int*)d_in[1];
    const int*   batch   = (const int*)d_in[2];
    const float* enc_W1  = (const float*)d_in[4];
    const float* enc_b1  = (const float*)d_in[5];
    const float* enc_W2  = (const float*)d_in[6];
    const float* enc_b2  = (const float*)d_in[7];
    const float* r_W1    = (const float*)d_in[8];
    const float* r_b1    = (const float*)d_in[9];
    const float* ln_g    = (const float*)d_in[10];
    const float* ln_b    = (const float*)d_in[11];
    const float* r_W2    = (const float*)d_in[12];
    const float* r_b2    = (const float*)d_in[13];
    const float* centers = (const float*)d_in[14];
    const float* W_rel   = (const float*)d_in[15];
    const float* b_rel   = (const float*)d_in[16];
    const float* W_root  = (const float*)d_in[17];
    const int* src = ei;
    const int* dst = ei + N_EDGES;
    float* out = (float*)d_out;

    // ---- workspace layout (all 256B aligned); ~166 MB total ----
    char* wsp = (char*)d_ws;
    size_t off = 0;
    auto alloc = [&](size_t bytes) -> char* {
        char* p = wsp + off;
        off = (off + bytes + 255) & ~(size_t)255;
        return p;
    };
    float* h    = (float*)alloc((size_t)P_ROWS * H_DIM * 4);
    float* zA   = (float*)alloc((size_t)P_ROWS * H_DIM * 4);
    float* zB   = (float*)alloc((size_t)P_ROWS * H_DIM * 4);  // also reused as rtmp
    float* agg  = (float*)alloc((size_t)P_ROWS * H_DIM * 4);
    float* weights = (float*)alloc((size_t)P_ROWS * 4 * 4);
    int* ints   = (int*)alloc((size_t)(N_NODES + 2 * G_GRAPHS) * 4); // deg | cnt_n | cnt_e
    int* deg    = ints;
    int* cnt_n  = ints + N_NODES;
    int* cnt_e  = ints + N_NODES + G_GRAPHS;
    int* row_ptr = (int*)alloc((size_t)(N_NODES + 1) * 4);
    int* cursor  = (int*)alloc((size_t)N_NODES * 4);
    int* csr_col = (int*)alloc((size_t)N_EDGES * 4);
    float* f_norm    = (float*)alloc((size_t)G_GRAPHS * 2 * 4);
    float* size_norm = (float*)alloc((size_t)G_GRAPHS * 4);
    (void)ws_size; (void)in_sizes; (void)n_in; (void)out_size;

    const dim3 gemm_grid(H_DIM / BN, P_ROWS / BM);   // (4, 157)
    const dim3 gemm_grid_r(1, P_ROWS / BM);          // router: 128 cols

    // 0) zero counters
    zero_ints_kernel<<<(N_NODES + 2 * G_GRAPHS + 255) / 256, 256, 0, stream>>>(
        ints, N_NODES + 2 * G_GRAPHS);
    // 1) encoder
    encoder1_kernel<<<(N_NODES * H_DIM + 255) / 256, 256, 0, stream>>>(x, enc_W1, enc_b1, zA);
    gemm_kernel<false, false, 0><<<gemm_grid, 256, 0, stream>>>(
        zA, enc_W2, nullptr, nullptr, enc_b2, nullptr, h, P_ROWS, H_DIM, H_DIM);
    // 2) graph stats
    count_kernel<<<(N_EDGES + 255) / 256, 256, 0, stream>>>(batch, src, dst, cnt_n, cnt_e, deg);
    stats_finalize_kernel<<<1, 64, 0, stream>>>(cnt_n, cnt_e, f_norm, size_norm);
    // 3) router: rtmp = h @ r_W1[0:512,:]  (zB reused as rtmp)
    gemm_kernel<false, false, 0><<<gemm_grid_r, 256, 0, stream>>>(
        h, r_W1, nullptr, nullptr, nullptr, nullptr, zB, P_ROWS, RH_DIM, H_DIM);
    router_kernel<<<N_NODES, 128, 0, stream>>>(zB, batch, r_W1, r_b1, ln_g, ln_b,
                                               r_W2, r_b2, centers, f_norm, size_norm, weights);
    // 4) CSR build (deterministic: sorted adjacency)
    scan_kernel<<<1, 1024, 0, stream>>>(deg, row_ptr, cursor, N_NODES);
    scatter_kernel<<<(N_EDGES + 255) / 256, 256, 0, stream>>>(src, dst, cursor, csr_col);
    sort_adj_kernel<<<(N_NODES + 255) / 256, 256, 0, stream>>>(row_ptr, csr_col);

    // 5) experts
    for (int e = 0; e < NE_EXP; ++e) {
        const float* Wr0 = W_rel  + (size_t)(e * 3 + 0) * H_DIM * H_DIM;
        const float* Wr1 = W_rel  + (size_t)(e * 3 + 1) * H_DIM * H_DIM;
        const float* Wr2 = W_rel  + (size_t)(e * 3 + 2) * H_DIM * H_DIM;
        const float* Wo0 = W_root + (size_t)(e * 3 + 0) * H_DIM * H_DIM;
        const float* Wo1 = W_root + (size_t)(e * 3 + 1) * H_DIM * H_DIM;
        const float* Wo2 = W_root + (size_t)(e * 3 + 2) * H_DIM * H_DIM;
        const float* br0 = b_rel + (size_t)(e * 3 + 0) * H_DIM;
        const float* br1 = b_rel + (size_t)(e * 3 + 1) * H_DIM;
        const float* br2 = b_rel + (size_t)(e * 3 + 2) * H_DIM;

        aggregate_kernel<<<N_NODES, 256, 0, stream>>>(h, row_ptr, csr_col, agg);
        gemm_kernel<true, true, 0><<<gemm_grid, 256, 0, stream>>>(
            agg, Wr0, h, Wo0, br0, nullptr, zA, P_ROWS, H_DIM, H_DIM);

        aggregate_kernel<<<N_NODES, 256, 0, stream>>>(zA, row_ptr, csr_col, agg);
        gemm_kernel<true, true, 0><<<gemm_grid, 256, 0, stream>>>(
            agg, Wr1, zA, Wo1, br1, nullptr, zB, P_ROWS, H_DIM, H_DIM);

        aggregate_kernel<<<N_NODES, 256, 0, stream>>>(zB, row_ptr, csr_col, agg);
        if (e == 0) {
            gemm_kernel<true, false, 3><<<gemm_grid, 256, 0, stream>>>(
                agg, Wr2, zB, Wo2, br2, weights + e, out, N_NODES, H_DIM, H_DIM);
        } else {
            gemm_kernel<true, false, 2><<<gemm_grid, 256, 0, stream>>>(
                agg, Wr2, zB, Wo2, br2, weights + e, out, N_NODES, H_DIM, H_DIM);
        }
    }
}

// Round 2
// 1536.189 us; speedup vs baseline: 2.9475x; 2.9475x over previous
//
#include <hip/hip_runtime.h>
#include <math.h>

// ---------------- problem constants (match reference) ----------------
#define N_NODES 20000
#define N_EDGES 160000
#define G_GRAPHS 64
#define H_DIM 512
#define RH_DIM 128
#define NE_EXP 4
#define P_ROWS 20096   // 157 * 128, padded row count for GEMM tiles

// ================= bf16 helpers =================
typedef __attribute__((ext_vector_type(8))) short bf16x8;
typedef __attribute__((ext_vector_type(4))) float f32x4;

__device__ __forceinline__ ushort f2bf(float f) {
    uint u = __float_as_uint(f);
    return (ushort)((u + 0x7FFFu + ((u >> 16) & 1u)) >> 16);  // round-to-nearest-even
}
__device__ __forceinline__ float bf2f(ushort h) {
    return __uint_as_float(((uint)h) << 16);
}

__device__ __forceinline__ void async_copy16(const void* g, void* l) {
    __builtin_amdgcn_global_load_lds(
        (__attribute__((address_space(1))) void*)g,
        (__attribute__((address_space(3))) void*)l, 16, 0, 0);
}

// ================= bf16 MFMA dual GEMM =================
// C = A1@W1t^T + A2@W2t^T + bias  (Wt stored transposed: Wt[n][k])
// A1,A2: [P_ROWS][512] bf16 row-major. W1t,W2t: [512][512] bf16 (n-major).
// EPI 0: Z[r][c] = bf16(relu?(v))        (all P_ROWS rows)
// EPI 2: O[r][c] += wcol[r*4] * v  fp32  (rows < N_NODES)
// EPI 3: O[r][c]  = wcol[r*4] * v  fp32  (rows < N_NODES)
template<bool RELU, int EPI>
__global__ __launch_bounds__(256)
void gemm_bt_bf16(const ushort* __restrict__ A1, const ushort* __restrict__ W1t,
                  const ushort* __restrict__ A2, const ushort* __restrict__ W2t,
                  const float* __restrict__ bias, const float* __restrict__ wcol,
                  void* __restrict__ CoutV)
{
    __shared__ char smem[16384];   // A tile 128x32 bf16 (8KB) | B tile 128x32 bf16 (8KB)
    const int tid = threadIdx.x;
    const int w = tid >> 6, lane = tid & 63;
    const int m0 = blockIdx.y * 128;
    const int n0 = blockIdx.x * 128;

    f32x4 acc[4][4];
#pragma unroll
    for (int i = 0; i < 4; ++i)
#pragma unroll
        for (int j = 0; j < 4; ++j) acc[i][j] = (f32x4){0.f, 0.f, 0.f, 0.f};

    // staging decomposition: per wave-issue, lane covers row lane>>2, 16B chunk lane&3
    const int srow = lane >> 2, schk = lane & 3;
    // fragment read addresses
    const int wr = w >> 1, wc = w & 1;
    const int row16 = lane & 15;
    const uint koffB = (uint)(lane >> 4) * 16u;              // 8 bf16 = 16B per k-group
    const uint aoff0 = (uint)(wr * 64 + row16) * 64u + koffB;
    const uint boff0 = 8192u + (uint)(wc * 64 + row16) * 64u + koffB;

    for (int pass = 0; pass < 2; ++pass) {
        const ushort* __restrict__ A  = pass ? A2 : A1;
        const ushort* __restrict__ Wt = pass ? W2t : W1t;
        for (int kt = 0; kt < 512; kt += 32) {
#pragma unroll
            for (int c = 0; c < 2; ++c) {
                const int rb = c * 64 + w * 16;       // wave-uniform row base
                async_copy16(A  + (size_t)(m0 + rb + srow) * 512 + kt + schk * 8,
                             smem + rb * 64);
                async_copy16(Wt + (size_t)(n0 + rb + srow) * 512 + kt + schk * 8,
                             smem + 8192 + rb * 64);
            }
            __syncthreads();   // drains vmcnt(0): tiles resident
            bf16x8 af[4], bf[4];
#pragma unroll
            for (int i = 0; i < 4; ++i) af[i] = *(const bf16x8*)(smem + aoff0 + i * 1024);
#pragma unroll
            for (int j = 0; j < 4; ++j) bf[j] = *(const bf16x8*)(smem + boff0 + j * 1024);
#pragma unroll
            for (int i = 0; i < 4; ++i)
#pragma unroll
                for (int j = 0; j < 4; ++j)
                    acc[i][j] = __builtin_amdgcn_mfma_f32_16x16x32_bf16(af[i], bf[j], acc[i][j], 0, 0, 0);
            __syncthreads();   // protect LDS before next stage
        }
    }

    // ---- epilogue ----  C/D layout: col = lane&15, row = (lane>>4)*4 + q  [m89-verified]
    if (EPI == 0) {
        ushort* Z = (ushort*)CoutV;
#pragma unroll
        for (int i = 0; i < 4; ++i) {
            const int r0 = m0 + wr * 64 + i * 16 + (lane >> 4) * 4;
#pragma unroll
            for (int j = 0; j < 4; ++j) {
                const int c = n0 + wc * 64 + j * 16 + row16;
                const float bj = bias[c];
#pragma unroll
                for (int q = 0; q < 4; ++q) {
                    float v = acc[i][j][q] + bj;
                    if (RELU) v = fmaxf(v, 0.f);
                    Z[(size_t)(r0 + q) * 512 + c] = f2bf(v);
                }
            }
        }
    } else {
        float* O = (float*)CoutV;
#pragma unroll
        for (int i = 0; i < 4; ++i) {
            const int r0 = m0 + wr * 64 + i * 16 + (lane >> 4) * 4;
#pragma unroll
            for (int q = 0; q < 4; ++q) {
                const int r = r0 + q;
                if (r >= N_NODES) continue;
                const float wrow = wcol[(size_t)r * 4];
#pragma unroll
                for (int j = 0; j < 4; ++j) {
                    const int c = n0 + wc * 64 + j * 16 + row16;
                    const float v = acc[i][j][q] + bias[c];
                    if (EPI == 3) O[(size_t)r * 512 + c] = wrow * v;
                    else          O[(size_t)r * 512 + c] += wrow * v;
                }
            }
        }
    }
}

// ================= fp32 tiled GEMM (encoder + router path only) =================
#define BM 128
#define BN 128
#define BK 16
#define LDSA (BM + 4)
#define LDSB (BN + 4)

template<bool DUAL, bool RELU, int EPI>
__global__ __launch_bounds__(256)
void gemm_kernel(const float* __restrict__ A1, const float* __restrict__ W1,
                 const float* __restrict__ A2, const float* __restrict__ W2,
                 const float* __restrict__ bias, const float* __restrict__ wcol,
                 float* __restrict__ Cout, int Mstore, int Ncols, int Kdim)
{
    __shared__ float As[BK][LDSA];
    __shared__ float Bs[BK][LDSB];
    const int tid = threadIdx.x;
    const int tx = tid & 15;
    const int ty = tid >> 4;
    const int m0 = blockIdx.y * BM;
    const int n0 = blockIdx.x * BN;
    const int tx4 = tx * 4, ty4 = ty * 4;

    float acc[8][8];
#pragma unroll
    for (int i = 0; i < 8; ++i)
#pragma unroll
        for (int j = 0; j < 8; ++j) acc[i][j] = 0.f;

    const int npass = DUAL ? 2 : 1;
    for (int pass = 0; pass < npass; ++pass) {
        const float* __restrict__ A = pass ? A2 : A1;
        const float* __restrict__ W = pass ? W2 : W1;
        for (int kt = 0; kt < Kdim; kt += BK) {
            {
                const int row = tid >> 2;
                const int kq  = tid & 3;
#pragma unroll
                for (int p = 0; p < 2; ++p) {
                    const int r = row + p * 64;
                    const float4 v = *reinterpret_cast<const float4*>(
                        &A[(size_t)(m0 + r) * Kdim + kt + kq * 4]);
                    As[kq * 4 + 0][r] = v.x;
                    As[kq * 4 + 1][r] = v.y;
                    As[kq * 4 + 2][r] = v.z;
                    As[kq * 4 + 3][r] = v.w;
                }
            }
            {
                const int krow = tid >> 5;
                const int nq   = tid & 31;
#pragma unroll
                for (int p = 0; p < 2; ++p) {
                    const int kk = krow + p * 8;
                    const float4 v = *reinterpret_cast<const float4*>(
                        &W[(size_t)(kt + kk) * Ncols + n0 + nq * 4]);
                    *reinterpret_cast<float4*>(&Bs[kk][nq * 4]) = v;
                }
            }
            __syncthreads();
#pragma unroll
            for (int k = 0; k < BK; ++k) {
                const float4 a0 = *reinterpret_cast<const float4*>(&As[k][ty4]);
                const float4 a1 = *reinterpret_cast<const float4*>(&As[k][64 + ty4]);
                const float4 b0 = *reinterpret_cast<const float4*>(&Bs[k][tx4]);
                const float4 b1 = *reinterpret_cast<const float4*>(&Bs[k][64 + tx4]);
                const float av[8] = {a0.x, a0.y, a0.z, a0.w, a1.x, a1.y, a1.z, a1.w};
                const float bv[8] = {b0.x, b0.y, b0.z, b0.w, b1.x, b1.y, b1.z, b1.w};
#pragma unroll
                for (int i = 0; i < 8; ++i)
#pragma unroll
                    for (int j = 0; j < 8; ++j)
                        acc[i][j] = fmaf(av[i], bv[j], acc[i][j]);
            }
            __syncthreads();
        }
    }

#pragma unroll
    for (int i = 0; i < 8; ++i) {
        const int r = m0 + ((i < 4) ? (ty4 + i) : (64 + ty4 + (i - 4)));
        if (r >= Mstore) continue;
        float wrow = 0.f;
        if (EPI >= 2) wrow = wcol[(size_t)r * 4];
#pragma unroll
        for (int j = 0; j < 8; ++j) {
            const int c = n0 + ((j < 4) ? (tx4 + j) : (64 + tx4 + (j - 4)));
            float v = acc[i][j];
            if (bias != nullptr) v += bias[c];
            if (RELU) v = fmaxf(v, 0.f);
            const size_t off = (size_t)r * Ncols + c;
            if (EPI == 0) Cout[off] = v;
            else if (EPI == 2) Cout[off] += wrow * v;
            else Cout[off] = wrow * v;
        }
    }
}

// t1 = relu(x[:,4:10] @ enc_W1 + enc_b1)
__global__ void encoder1_kernel(const float* __restrict__ x, const float* __restrict__ W1,
                                const float* __restrict__ b1, float* __restrict__ t1)
{
    const int idx = blockIdx.x * blockDim.x + threadIdx.x;
    if (idx >= N_NODES * H_DIM) return;
    const int i = idx / H_DIM, j = idx - i * H_DIM;
    const float* xr = &x[i * 16 + 4];
    float acc = b1[j];
#pragma unroll
    for (int k = 0; k < 6; ++k) acc = fmaf(xr[k], W1[k * H_DIM + j], acc);
    t1[idx] = fmaxf(acc, 0.f);
}

__global__ void zero_ints_kernel(int* __restrict__ p, int n)
{
    const int idx = blockIdx.x * blockDim.x + threadIdx.x;
    if (idx < n) p[idx] = 0;
}

__global__ void count_kernel(const int* __restrict__ batch, const int* __restrict__ src,
                             const int* __restrict__ dst,
                             int* __restrict__ cnt_n, int* __restrict__ cnt_e,
                             int* __restrict__ deg)
{
    const int idx = blockIdx.x * blockDim.x + threadIdx.x;
    if (idx < N_NODES) atomicAdd(&cnt_n[batch[idx]], 1);
    if (idx < N_EDGES) {
        atomicAdd(&cnt_e[batch[src[idx]]], 1);
        atomicAdd(&deg[dst[idx]], 1);
    }
}

__global__ void stats_finalize_kernel(const int* __restrict__ cnt_n, const int* __restrict__ cnt_e,
                                      float* __restrict__ f_norm, float* __restrict__ size_norm)
{
    const int g = threadIdx.x;  // exactly 64
    const float nn = fmaxf((float)cnt_n[g], 1.0f);
    const float ee = (float)cnt_e[g];
    const float ln = logf(nn);
    const float le = log1pf(ee);
    float s0 = ln, s1 = le;
#pragma unroll
    for (int o = 32; o > 0; o >>= 1) { s0 += __shfl_xor(s0, o); s1 += __shfl_xor(s1, o); }
    const float m0 = s0 / 64.f, m1 = s1 / 64.f;
    const float d0 = ln - m0, d1 = le - m1;
    float v0 = d0 * d0, v1 = d1 * d1;
#pragma unroll
    for (int o = 32; o > 0; o >>= 1) { v0 += __shfl_xor(v0, o); v1 += __shfl_xor(v1, o); }
    const float sd0 = sqrtf(v0 / 64.f), sd1 = sqrtf(v1 / 64.f);
    float mn = ln, mx = ln;
#pragma unroll
    for (int o = 32; o > 0; o >>= 1) {
        mn = fminf(mn, __shfl_xor(mn, o));
        mx = fmaxf(mx, __shfl_xor(mx, o));
    }
    f_norm[g * 2 + 0] = d0 / (sd0 + 1e-6f);
    f_norm[g * 2 + 1] = d1 / (sd1 + 1e-6f);
    size_norm[g] = (ln - mn) / (mx - mn + 1e-6f);
}

__global__ void scan_kernel(const int* __restrict__ in, int* __restrict__ row_ptr,
                            int* __restrict__ cursor, int n)
{
    __shared__ int buf[1024];
    __shared__ int carry;
    const int tid = threadIdx.x;
    if (tid == 0) carry = 0;
    __syncthreads();
    for (int base = 0; base < n; base += 1024) {
        const int idx = base + tid;
        const int v = (idx < n) ? in[idx] : 0;
        buf[tid] = v;
        __syncthreads();
        for (int off2 = 1; off2 < 1024; off2 <<= 1) {
            const int t = (tid >= off2) ? buf[tid - off2] : 0;
            __syncthreads();
            buf[tid] += t;
            __syncthreads();
        }
        const int incl = buf[tid];
        const int excl = incl - v + carry;
        if (idx < n) { row_ptr[idx] = excl; cursor[idx] = excl; }
        const int total = buf[1023];
        __syncthreads();
        if (tid == 0) carry += total;
        __syncthreads();
    }
    if (tid == 0) row_ptr[n] = carry;
}

__global__ void scatter_kernel(const int* __restrict__ src, const int* __restrict__ dst,
                               int* __restrict__ cursor, int* __restrict__ csr_col)
{
    const int e = blockIdx.x * blockDim.x + threadIdx.x;
    if (e >= N_EDGES) return;
    const int d = dst[e];
    const int slot = atomicAdd(&cursor[d], 1);
    csr_col[slot] = src[e];
}

__global__ void sort_adj_kernel(const int* __restrict__ row_ptr, int* __restrict__ csr_col)
{
    const int i = blockIdx.x * blockDim.x + threadIdx.x;
    if (i >= N_NODES) return;
    const int b = row_ptr[i], e = row_ptr[i + 1];
    for (int p = b + 1; p < e; ++p) {
        const int key = csr_col[p];
        int q = p - 1;
        while (q >= b && csr_col[q] > key) { csr_col[q + 1] = csr_col[q]; --q; }
        csr_col[q + 1] = key;
    }
}

// agg[i,:] = sum over in-edges of z[src,:]  (bf16 in/out, fp32 accumulate)
__global__ __launch_bounds__(256)
void aggregate_bf16(const uint* __restrict__ z2, const int* __restrict__ row_ptr,
                    const int* __restrict__ csr_col, uint* __restrict__ agg2)
{
    const int i = blockIdx.x;
    const int t = threadIdx.x;   // 2 cols per thread (one uint = 2 bf16)
    const int b = row_ptr[i], e = row_ptr[i + 1];
    float ax = 0.f, ay = 0.f;
    for (int p = b; p < e; ++p) {
        const uint v = z2[(size_t)csr_col[p] * 256 + t];
        ax += bf2f((ushort)(v & 0xffffu));
        ay += bf2f((ushort)(v >> 16));
    }
    agg2[(size_t)i * 256 + t] = (uint)f2bf(ax) | ((uint)f2bf(ay) << 16);
}

// one 512x512 matrix per blockIdx.z: Wt[n][k] = bf16(W[k][n])
__global__ __launch_bounds__(256)
void transpose_f32_to_bf16(const float* __restrict__ W, ushort* __restrict__ Wt)
{
    __shared__ float tile[32][33];
    const float* Wm = W + (size_t)blockIdx.z * 512 * 512;
    ushort* Wtm = Wt + (size_t)blockIdx.z * 512 * 512;
    const int c0 = blockIdx.x * 32, r0 = blockIdx.y * 32;
    const int tc = threadIdx.x & 31, tr = threadIdx.x >> 5;
#pragma unroll
    for (int it = 0; it < 4; ++it)
        tile[tr + it * 8][tc] = Wm[(size_t)(r0 + tr + it * 8) * 512 + c0 + tc];
    __syncthreads();
#pragma unroll
    for (int it = 0; it < 4; ++it) {
        const int cr = tr + it * 8;
        Wtm[(size_t)(c0 + cr) * 512 + r0 + tc] = f2bf(tile[tc][cr]);
    }
}

__global__ void f32_to_bf16_kernel(const float* __restrict__ in, uint* __restrict__ out, int n2)
{
    const int idx = blockIdx.x * blockDim.x + threadIdx.x;  // 2 elems per thread
    if (idx >= n2) return;
    const float2 v = reinterpret_cast<const float2*>(in)[idx];
    out[idx] = (uint)f2bf(v.x) | ((uint)f2bf(v.y) << 16);
}

// router tail (unchanged, fp32)
__global__ __launch_bounds__(128)
void router_kernel(const float* __restrict__ rtmp, const int* __restrict__ batch,
                   const float* __restrict__ rW1, const float* __restrict__ rb1,
                   const float* __restrict__ lng, const float* __restrict__ lnb,
                   const float* __restrict__ rW2, const float* __restrict__ rb2,
                   const float* __restrict__ centers,
                   const float* __restrict__ f_norm, const float* __restrict__ size_norm,
                   float* __restrict__ weights)
{
    const int i = blockIdx.x;
    const int j = threadIdx.x;
    const int g = batch[i];
    const float f0 = f_norm[g * 2], f1 = f_norm[g * 2 + 1];
    float r = rtmp[(size_t)i * RH_DIM + j]
            + f0 * rW1[512 * RH_DIM + j] + f1 * rW1[513 * RH_DIM + j] + rb1[j];

    __shared__ float part[2];
    __shared__ float rbuf[RH_DIM];
    __shared__ float lbuf[4];
    const int lane = j & 63, wv = j >> 6;

    float s = r;
#pragma unroll
    for (int o = 32; o > 0; o >>= 1) s += __shfl_xor(s, o);
    if (lane == 0) part[wv] = s;
    __syncthreads();
    const float mean = (part[0] + part[1]) / 128.f;
    __syncthreads();
    const float d = r - mean;
    float v = d * d;
#pragma unroll
    for (int o = 32; o > 0; o >>= 1) v += __shfl_xor(v, o);
    if (lane == 0) part[wv] = v;
    __syncthreads();
    const float var = (part[0] + part[1]) / 128.f;
    const float rn = d / sqrtf(var + 1e-5f) * lng[j] + lnb[j];
    rbuf[j] = fmaxf(rn, 0.f);
    __syncthreads();

    if (j < 4) {
        float acc = rb2[j];
        for (int t = 0; t < RH_DIM; ++t) acc = fmaf(rbuf[t], rW2[t * 4 + j], acc);
        const float sn = size_norm[g];
        const float dd = sn - centers[j];
        lbuf[j] = 0.7f * acc + 0.3f * (-(dd * dd));
    }
    __syncthreads();
    if (j == 0) {
        float p[4];
        const float mx = fmaxf(fmaxf(lbuf[0], lbuf[1]), fmaxf(lbuf[2], lbuf[3]));
#pragma unroll
        for (int c = 0; c < 4; ++c) p[c] = expf(lbuf[c] - mx);
        const float ssum = p[0] + p[1] + p[2] + p[3];
#pragma unroll
        for (int c = 0; c < 4; ++c) p[c] /= ssum;
        int i1 = 0;
#pragma unroll
        for (int c = 1; c < 4; ++c) if (p[c] > p[i1]) i1 = c;
        int i2 = -1;
#pragma unroll
        for (int c = 0; c < 4; ++c) {
            if (c == i1) continue;
            if (i2 < 0 || p[c] > p[i2]) i2 = c;
        }
        const float vs = p[i1] + p[i2] + 1e-8f;
        float wout[4] = {0.f, 0.f, 0.f, 0.f};
        wout[i1] = p[i1] / vs;
        wout[i2] = p[i2] / vs;
#pragma unroll
        for (int c = 0; c < 4; ++c) weights[(size_t)i * 4 + c] = wout[c];
    }
}

extern "C" void kernel_launch(void* const* d_in, const int* in_sizes, int n_in,
                              void* d_out, int out_size, void* d_ws, size_t ws_size,
                              hipStream_t stream)
{
    const float* x       = (const float*)d_in[0];
    const int*   ei      = (const int*)d_in[1];
    const int*   batch   = (const int*)d_in[2];
    const float* enc_W1  = (const float*)d_in[4];
    const float* enc_b1  = (const float*)d_in[5];
    const float* enc_W2  = (const float*)d_in[6];
    const float* enc_b2  = (const float*)d_in[7];
    const float* r_W1    = (const float*)d_in[8];
    const float* r_b1    = (const float*)d_in[9];
    const float* ln_g    = (const float*)d_in[10];
    const float* ln_b    = (const float*)d_in[11];
    const float* r_W2    = (const float*)d_in[12];
    const float* r_b2    = (const float*)d_in[13];
    const float* centers = (const float*)d_in[14];
    const float* W_rel   = (const float*)d_in[15];
    const float* b_rel   = (const float*)d_in[16];
    const float* W_root  = (const float*)d_in[17];
    const int* src = ei;
    const int* dst = ei + N_EDGES;
    float* out = (float*)d_out;

    // ---- workspace layout (~158 MB) ----
    char* wsp = (char*)d_ws;
    size_t off = 0;
    auto alloc = [&](size_t bytes) -> char* {
        char* p = wsp + off;
        off = (off + bytes + 255) & ~(size_t)255;
        return p;
    };
    const size_t PF = (size_t)P_ROWS * H_DIM;
    float*  h      = (float*)alloc(PF * 4);          // fp32 h (router path needs it)
    char*   t1reg  = alloc(PF * 4);                  // t1 fp32, later zA16+zB16
    float*  t1     = (float*)t1reg;
    ushort* zA16   = (ushort*)t1reg;                 // alias (after t1 dead)
    ushort* zB16   = (ushort*)(t1reg + PF * 2);
    ushort* h16    = (ushort*)alloc(PF * 2);
    char*   aggreg = alloc(PF * 2);                  // agg16; aliased as rtmp fp32 earlier
    ushort* agg16  = (ushort*)aggreg;
    float*  rtmp   = (float*)aggreg;                 // P_ROWS*128*4 = 10.3MB < 20.6MB
    ushort* aggH16 = (ushort*)alloc(PF * 2);
    ushort* Wt_rel16  = (ushort*)alloc((size_t)12 * 512 * 512 * 2);
    ushort* Wt_root16 = (ushort*)alloc((size_t)12 * 512 * 512 * 2);
    float*  weights   = (float*)alloc((size_t)P_ROWS * 4 * 4);
    int* ints   = (int*)alloc((size_t)(N_NODES + 2 * G_GRAPHS) * 4);
    int* deg    = ints;
    int* cnt_n  = ints + N_NODES;
    int* cnt_e  = ints + N_NODES + G_GRAPHS;
    int* row_ptr = (int*)alloc((size_t)(N_NODES + 1) * 4);
    int* cursor  = (int*)alloc((size_t)N_NODES * 4);
    int* csr_col = (int*)alloc((size_t)N_EDGES * 4);
    float* f_norm    = (float*)alloc((size_t)G_GRAPHS * 2 * 4);
    float* size_norm = (float*)alloc((size_t)G_GRAPHS * 4);
    (void)ws_size; (void)in_sizes; (void)n_in; (void)out_size;

    const dim3 gemm_grid(H_DIM / BN, P_ROWS / BM);   // fp32 enc (4,157)
    const dim3 gemm_grid_r(1, P_ROWS / BM);          // fp32 router (1,157)
    const dim3 mfma_grid(4, P_ROWS / 128);           // bf16 experts (4,157)
    const dim3 tr_grid(16, 16, 12);

    // 0) zero counters + one-time weight transpose/convert
    zero_ints_kernel<<<(N_NODES + 2 * G_GRAPHS + 255) / 256, 256, 0, stream>>>(
        ints, N_NODES + 2 * G_GRAPHS);
    transpose_f32_to_bf16<<<tr_grid, 256, 0, stream>>>(W_rel, Wt_rel16);
    transpose_f32_to_bf16<<<tr_grid, 256, 0, stream>>>(W_root, Wt_root16);
    // 1) encoder (fp32 — feeds router selection, keep exact)
    encoder1_kernel<<<(N_NODES * H_DIM + 255) / 256, 256, 0, stream>>>(x, enc_W1, enc_b1, t1);
    gemm_kernel<false, false, 0><<<gemm_grid, 256, 0, stream>>>(
        t1, enc_W2, nullptr, nullptr, enc_b2, nullptr, h, P_ROWS, H_DIM, H_DIM);
    // 2) graph stats
    count_kernel<<<(N_EDGES + 255) / 256, 256, 0, stream>>>(batch, src, dst, cnt_n, cnt_e, deg);
    stats_finalize_kernel<<<1, 64, 0, stream>>>(cnt_n, cnt_e, f_norm, size_norm);
    // 3) router (fp32)
    gemm_kernel<false, false, 0><<<gemm_grid_r, 256, 0, stream>>>(
        h, r_W1, nullptr, nullptr, nullptr, nullptr, rtmp, P_ROWS, RH_DIM, H_DIM);
    router_kernel<<<N_NODES, 128, 0, stream>>>(rtmp, batch, r_W1, r_b1, ln_g, ln_b,
                                               r_W2, r_b2, centers, f_norm, size_norm, weights);
    // 4) CSR build (deterministic: sorted adjacency)
    scan_kernel<<<1, 1024, 0, stream>>>(deg, row_ptr, cursor, N_NODES);
    scatter_kernel<<<(N_EDGES + 255) / 256, 256, 0, stream>>>(src, dst, cursor, csr_col);
    sort_adj_kernel<<<(N_NODES + 255) / 256, 256, 0, stream>>>(row_ptr, csr_col);
    // 5) h -> bf16 (after router consumed fp32 h; t1 region now reusable)
    f32_to_bf16_kernel<<<(int)((PF / 2 + 255) / 256), 256, 0, stream>>>(h, (uint*)h16, (int)(PF / 2));
    // shared layer-0 aggregation (identical for all experts)
    aggregate_bf16<<<N_NODES, 256, 0, stream>>>((const uint*)h16, row_ptr, csr_col, (uint*)aggH16);

    // 6) experts (bf16 MFMA)
    for (int e = 0; e < NE_EXP; ++e) {
        const ushort* Wr0 = Wt_rel16  + (size_t)(e * 3 + 0) * 512 * 512;
        const ushort* Wr1 = Wt_rel16  + (size_t)(e * 3 + 1) * 512 * 512;
        const ushort* Wr2 = Wt_rel16  + (size_t)(e * 3 + 2) * 512 * 512;
        const ushort* Wo0 = Wt_root16 + (size_t)(e * 3 + 0) * 512 * 512;
        const ushort* Wo1 = Wt_root16 + (size_t)(e * 3 + 1) * 512 * 512;
        const ushort* Wo2 = Wt_root16 + (size_t)(e * 3 + 2) * 512 * 512;
        const float* br0 = b_rel + (size_t)(e * 3 + 0) * H_DIM;
        const float* br1 = b_rel + (size_t)(e * 3 + 1) * H_DIM;
        const float* br2 = b_rel + (size_t)(e * 3 + 2) * H_DIM;

        gemm_bt_bf16<true, 0><<<mfma_grid, 256, 0, stream>>>(
            aggH16, Wr0, h16, Wo0, br0, nullptr, zA16);

        aggregate_bf16<<<N_NODES, 256, 0, stream>>>((const uint*)zA16, row_ptr, csr_col, (uint*)agg16);
        gemm_bt_bf16<true, 0><<<mfma_grid, 256, 0, stream>>>(
            agg16, Wr1, zA16, Wo1, br1, nullptr, zB16);

        aggregate_bf16<<<N_NODES, 256, 0, stream>>>((const uint*)zB16, row_ptr, csr_col, (uint*)agg16);
        if (e == 0) {
            gemm_bt_bf16<false, 3><<<mfma_grid, 256, 0, stream>>>(
                agg16, Wr2, zB16, Wo2, br2, weights + e, out);
        } else {
            gemm_bt_bf16<false, 2><<<mfma_grid, 256, 0, stream>>>(
                agg16, Wr2, zB16, Wo2, br2, weights + e, out);
        }
    }
}

// Round 3
// 1221.423 us; speedup vs baseline: 3.7071x; 1.2577x over previous
//
#include <hip/hip_runtime.h>
#include <math.h>

// ---------------- problem constants (match reference) ----------------
#define N_NODES 20000
#define N_EDGES 160000
#define G_GRAPHS 64
#define H_DIM 512
#define RH_DIM 128
#define NE_EXP 4
#define P_ROWS 20096   // 157 * 128, padded row count for GEMM tiles
#define EH_BLOCKS 64   // edge-histogram partial blocks

// ================= bf16 helpers =================
typedef __attribute__((ext_vector_type(8))) short bf16x8;
typedef __attribute__((ext_vector_type(4))) float f32x4;

__device__ __forceinline__ ushort f2bf(float f) {
    uint u = __float_as_uint(f);
    return (ushort)((u + 0x7FFFu + ((u >> 16) & 1u)) >> 16);  // round-to-nearest-even
}
__device__ __forceinline__ float bf2f(ushort h) {
    return __uint_as_float(((uint)h) << 16);
}

__device__ __forceinline__ void async_copy16(const void* g, void* l) {
    __builtin_amdgcn_global_load_lds(
        (__attribute__((address_space(1))) void*)g,
        (__attribute__((address_space(3))) void*)l, 16, 0, 0);
}

// ================= bf16 MFMA dual GEMM (m97 structure) =================
// C = A1@W1t^T + A2@W2t^T + bias  (Wt stored transposed: Wt[n][k])
// EPI 0: Z[r][c] = bf16(relu?(v))        (all P_ROWS rows)
// EPI 2: O[r][c] += wcol[r*4] * v  fp32  (rows < N_NODES)
// EPI 3: O[r][c]  = wcol[r*4] * v  fp32  (rows < N_NODES)
template<bool RELU, int EPI>
__global__ __launch_bounds__(256)
void gemm_bt_bf16(const ushort* __restrict__ A1, const ushort* __restrict__ W1t,
                  const ushort* __restrict__ A2, const ushort* __restrict__ W2t,
                  const float* __restrict__ bias, const float* __restrict__ wcol,
                  void* __restrict__ CoutV)
{
    __shared__ char smem[16384];   // A tile 128x32 bf16 (8KB) | B tile 128x32 bf16 (8KB)
    const int tid = threadIdx.x;
    const int w = tid >> 6, lane = tid & 63;
    const int m0 = blockIdx.y * 128;
    const int n0 = blockIdx.x * 128;

    f32x4 acc[4][4];
#pragma unroll
    for (int i = 0; i < 4; ++i)
#pragma unroll
        for (int j = 0; j < 4; ++j) acc[i][j] = (f32x4){0.f, 0.f, 0.f, 0.f};

    const int srow = lane >> 2, schk = lane & 3;
    const int wr = w >> 1, wc = w & 1;
    const int row16 = lane & 15;
    const uint koffB = (uint)(lane >> 4) * 16u;
    const uint aoff0 = (uint)(wr * 64 + row16) * 64u + koffB;
    const uint boff0 = 8192u + (uint)(wc * 64 + row16) * 64u + koffB;

    for (int pass = 0; pass < 2; ++pass) {
        const ushort* __restrict__ A  = pass ? A2 : A1;
        const ushort* __restrict__ Wt = pass ? W2t : W1t;
        for (int kt = 0; kt < 512; kt += 32) {
#pragma unroll
            for (int c = 0; c < 2; ++c) {
                const int rb = c * 64 + w * 16;       // wave-uniform row base
                async_copy16(A  + (size_t)(m0 + rb + srow) * 512 + kt + schk * 8,
                             smem + rb * 64);
                async_copy16(Wt + (size_t)(n0 + rb + srow) * 512 + kt + schk * 8,
                             smem + 8192 + rb * 64);
            }
            __syncthreads();
            bf16x8 af[4], bfr[4];
#pragma unroll
            for (int i = 0; i < 4; ++i) af[i] = *(const bf16x8*)(smem + aoff0 + i * 1024);
#pragma unroll
            for (int j = 0; j < 4; ++j) bfr[j] = *(const bf16x8*)(smem + boff0 + j * 1024);
#pragma unroll
            for (int i = 0; i < 4; ++i)
#pragma unroll
                for (int j = 0; j < 4; ++j)
                    acc[i][j] = __builtin_amdgcn_mfma_f32_16x16x32_bf16(af[i], bfr[j], acc[i][j], 0, 0, 0);
            __syncthreads();
        }
    }

    // ---- epilogue ----  C/D layout: col = lane&15, row = (lane>>4)*4 + q
    if (EPI == 0) {
        ushort* Z = (ushort*)CoutV;
#pragma unroll
        for (int i = 0; i < 4; ++i) {
            const int r0 = m0 + wr * 64 + i * 16 + (lane >> 4) * 4;
#pragma unroll
            for (int j = 0; j < 4; ++j) {
                const int c = n0 + wc * 64 + j * 16 + row16;
                const float bj = bias[c];
#pragma unroll
                for (int q = 0; q < 4; ++q) {
                    float v = acc[i][j][q] + bj;
                    if (RELU) v = fmaxf(v, 0.f);
                    Z[(size_t)(r0 + q) * 512 + c] = f2bf(v);
                }
            }
        }
    } else {
        float* O = (float*)CoutV;
#pragma unroll
        for (int i = 0; i < 4; ++i) {
            const int r0 = m0 + wr * 64 + i * 16 + (lane >> 4) * 4;
#pragma unroll
            for (int q = 0; q < 4; ++q) {
                const int r = r0 + q;
                if (r >= N_NODES) continue;
                const float wrow = wcol[(size_t)r * 4];
#pragma unroll
                for (int j = 0; j < 4; ++j) {
                    const int c = n0 + wc * 64 + j * 16 + row16;
                    const float v = acc[i][j][q] + bias[c];
                    if (EPI == 3) O[(size_t)r * 512 + c] = wrow * v;
                    else          O[(size_t)r * 512 + c] += wrow * v;
                }
            }
        }
    }
}

// ================= fp32 tiled GEMM (encoder + router path only) =================
#define BM 128
#define BN 128
#define BK 16
#define LDSA (BM + 4)
#define LDSB (BN + 4)

// BF16OUT: also emit bf16 copy of the (pre-activation) result to Bf16 buffer
template<bool RELU, bool BF16OUT>
__global__ __launch_bounds__(256)
void gemm_kernel(const float* __restrict__ A1, const float* __restrict__ W1,
                 const float* __restrict__ bias, float* __restrict__ Cout,
                 ushort* __restrict__ Bf16, int Mstore, int Ncols, int Kdim)
{
    __shared__ float As[BK][LDSA];
    __shared__ float Bs[BK][LDSB];
    const int tid = threadIdx.x;
    const int tx = tid & 15;
    const int ty = tid >> 4;
    const int m0 = blockIdx.y * BM;
    const int n0 = blockIdx.x * BN;
    const int tx4 = tx * 4, ty4 = ty * 4;

    float acc[8][8];
#pragma unroll
    for (int i = 0; i < 8; ++i)
#pragma unroll
        for (int j = 0; j < 8; ++j) acc[i][j] = 0.f;

    for (int kt = 0; kt < Kdim; kt += BK) {
        {
            const int row = tid >> 2;
            const int kq  = tid & 3;
#pragma unroll
            for (int p = 0; p < 2; ++p) {
                const int r = row + p * 64;
                const float4 v = *reinterpret_cast<const float4*>(
                    &A1[(size_t)(m0 + r) * Kdim + kt + kq * 4]);
                As[kq * 4 + 0][r] = v.x;
                As[kq * 4 + 1][r] = v.y;
                As[kq * 4 + 2][r] = v.z;
                As[kq * 4 + 3][r] = v.w;
            }
        }
        {
            const int krow = tid >> 5;
            const int nq   = tid & 31;
#pragma unroll
            for (int p = 0; p < 2; ++p) {
                const int kk = krow + p * 8;
                const float4 v = *reinterpret_cast<const float4*>(
                    &W1[(size_t)(kt + kk) * Ncols + n0 + nq * 4]);
                *reinterpret_cast<float4*>(&Bs[kk][nq * 4]) = v;
            }
        }
        __syncthreads();
#pragma unroll
        for (int k = 0; k < BK; ++k) {
            const float4 a0 = *reinterpret_cast<const float4*>(&As[k][ty4]);
            const float4 a1 = *reinterpret_cast<const float4*>(&As[k][64 + ty4]);
            const float4 b0 = *reinterpret_cast<const float4*>(&Bs[k][tx4]);
            const float4 b1 = *reinterpret_cast<const float4*>(&Bs[k][64 + tx4]);
            const float av[8] = {a0.x, a0.y, a0.z, a0.w, a1.x, a1.y, a1.z, a1.w};
            const float bv[8] = {b0.x, b0.y, b0.z, b0.w, b1.x, b1.y, b1.z, b1.w};
#pragma unroll
            for (int i = 0; i < 8; ++i)
#pragma unroll
                for (int j = 0; j < 8; ++j)
                    acc[i][j] = fmaf(av[i], bv[j], acc[i][j]);
        }
        __syncthreads();
    }

#pragma unroll
    for (int i = 0; i < 8; ++i) {
        const int r = m0 + ((i < 4) ? (ty4 + i) : (64 + ty4 + (i - 4)));
        if (r >= Mstore) continue;
#pragma unroll
        for (int j = 0; j < 8; ++j) {
            const int c = n0 + ((j < 4) ? (tx4 + j) : (64 + tx4 + (j - 4)));
            float v = acc[i][j];
            if (bias != nullptr) v += bias[c];
            if (RELU) v = fmaxf(v, 0.f);
            const size_t off = (size_t)r * Ncols + c;
            Cout[off] = v;
            if (BF16OUT) Bf16[off] = f2bf(v);
        }
    }
}

// t1 = relu(x[:,4:10] @ enc_W1 + enc_b1)
__global__ void encoder1_kernel(const float* __restrict__ x, const float* __restrict__ W1,
                                const float* __restrict__ b1, float* __restrict__ t1)
{
    const int idx = blockIdx.x * blockDim.x + threadIdx.x;
    if (idx >= N_NODES * H_DIM) return;
    const int i = idx / H_DIM, j = idx - i * H_DIM;
    const float* xr = &x[i * 16 + 4];
    float acc = b1[j];
#pragma unroll
    for (int k = 0; k < 6; ++k) acc = fmaf(xr[k], W1[k * H_DIM + j], acc);
    t1[idx] = fmaxf(acc, 0.f);
}

__global__ void zero_ints_kernel(int* __restrict__ p, int n)
{
    const int idx = blockIdx.x * blockDim.x + threadIdx.x;
    if (idx < n) p[idx] = 0;
}

// 65 binary searches on sorted batch -> graph start offsets (no atomics)
__global__ void graph_bounds_kernel(const int* __restrict__ batch, int* __restrict__ gstart)
{
    const int g = threadIdx.x;
    if (g > G_GRAPHS) return;
    int lo = 0, hi = N_NODES;
    while (lo < hi) {
        const int mid = (lo + hi) >> 1;
        if (batch[mid] < g) lo = mid + 1; else hi = mid;
    }
    gstart[g] = lo;
}

// per-block LDS histogram of edge graphs + in-degree atomics (spread addresses)
__global__ __launch_bounds__(256)
void edge_hist_kernel(const int* __restrict__ src, const int* __restrict__ dst,
                      const int* __restrict__ batch,
                      int* __restrict__ part, int* __restrict__ deg)
{
    __shared__ int hist[G_GRAPHS];
    const int tid = threadIdx.x;
    if (tid < G_GRAPHS) hist[tid] = 0;
    __syncthreads();
    for (int e = blockIdx.x * 256 + tid; e < N_EDGES; e += EH_BLOCKS * 256) {
        atomicAdd(&deg[dst[e]], 1);
        atomicAdd(&hist[batch[src[e]]], 1);
    }
    __syncthreads();
    if (tid < G_GRAPHS) part[blockIdx.x * G_GRAPHS + tid] = hist[tid];
}

// 64 threads (one wave): reduce partials, log/normalize per-graph features
__global__ void stats_finalize_kernel(const int* __restrict__ gstart, const int* __restrict__ part,
                                      float* __restrict__ f_norm, float* __restrict__ size_norm)
{
    const int g = threadIdx.x;  // exactly 64
    const float nn = fmaxf((float)(gstart[g + 1] - gstart[g]), 1.0f);
    int ec = 0;
#pragma unroll 8
    for (int b = 0; b < EH_BLOCKS; ++b) ec += part[b * G_GRAPHS + g];
    const float ee = (float)ec;
    const float ln = logf(nn);
    const float le = log1pf(ee);
    float s0 = ln, s1 = le;
#pragma unroll
    for (int o = 32; o > 0; o >>= 1) { s0 += __shfl_xor(s0, o); s1 += __shfl_xor(s1, o); }
    const float m0 = s0 / 64.f, m1 = s1 / 64.f;
    const float d0 = ln - m0, d1 = le - m1;
    float v0 = d0 * d0, v1 = d1 * d1;
#pragma unroll
    for (int o = 32; o > 0; o >>= 1) { v0 += __shfl_xor(v0, o); v1 += __shfl_xor(v1, o); }
    const float sd0 = sqrtf(v0 / 64.f), sd1 = sqrtf(v1 / 64.f);
    float mn = ln, mx = ln;
#pragma unroll
    for (int o = 32; o > 0; o >>= 1) {
        mn = fminf(mn, __shfl_xor(mn, o));
        mx = fmaxf(mx, __shfl_xor(mx, o));
    }
    f_norm[g * 2 + 0] = d0 / (sd0 + 1e-6f);
    f_norm[g * 2 + 1] = d1 / (sd1 + 1e-6f);
    size_norm[g] = (ln - mn) / (mx - mn + 1e-6f);
}

// single-block shuffle-based exclusive scan of deg -> row_ptr (+copy to cursor)
__global__ void scan_kernel(const int* __restrict__ in, int* __restrict__ row_ptr,
                            int* __restrict__ cursor, int n)
{
    __shared__ int wsum[16];
    __shared__ int carry_s;
    const int tid = threadIdx.x;
    const int lane = tid & 63, wv = tid >> 6;
    if (tid == 0) carry_s = 0;
    __syncthreads();
    for (int base = 0; base < n; base += 1024) {
        const int idx = base + tid;
        const int v = (idx < n) ? in[idx] : 0;
        int x = v;
#pragma unroll
        for (int o = 1; o < 64; o <<= 1) { const int t = __shfl_up(x, o); if (lane >= o) x += t; }
        if (lane == 63) wsum[wv] = x;
        __syncthreads();
        const int carry = carry_s;
        if (wv == 0) {
            int y = (lane < 16) ? wsum[lane] : 0;
#pragma unroll
            for (int o = 1; o < 16; o <<= 1) { const int t = __shfl_up(y, o); if (lane >= o) y += t; }
            if (lane < 16) wsum[lane] = y;
        }
        __syncthreads();
        const int woff = (wv > 0) ? wsum[wv - 1] : 0;
        const int excl = x - v + woff + carry;
        if (idx < n) { row_ptr[idx] = excl; cursor[idx] = excl; }
        __syncthreads();
        if (tid == 0) carry_s = carry + wsum[15];
        __syncthreads();
    }
    if (tid == 0) row_ptr[n] = carry_s;
}

__global__ void scatter_kernel(const int* __restrict__ src, const int* __restrict__ dst,
                               int* __restrict__ cursor, int* __restrict__ csr_col)
{
    const int e = blockIdx.x * blockDim.x + threadIdx.x;
    if (e >= N_EDGES) return;
    const int d = dst[e];
    const int slot = atomicAdd(&cursor[d], 1);
    csr_col[slot] = src[e];
}

__global__ void sort_adj_kernel(const int* __restrict__ row_ptr, int* __restrict__ csr_col)
{
    const int i = blockIdx.x * blockDim.x + threadIdx.x;
    if (i >= N_NODES) return;
    const int b = row_ptr[i], e = row_ptr[i + 1];
    for (int p = b + 1; p < e; ++p) {
        const int key = csr_col[p];
        int q = p - 1;
        while (q >= b && csr_col[q] > key) { csr_col[q + 1] = csr_col[q]; --q; }
        csr_col[q + 1] = key;
    }
}

// agg[i,:] = sum over in-edges of z[src,:]  (bf16 in/out, fp32 accumulate, 4-wide ILP)
__global__ __launch_bounds__(256)
void aggregate_bf16(const uint* __restrict__ z2, const int* __restrict__ row_ptr,
                    const int* __restrict__ csr_col, uint* __restrict__ agg2)
{
    const int i = blockIdx.x;
    const int t = threadIdx.x;   // 2 cols per thread
    const int b = row_ptr[i], e = row_ptr[i + 1];
    float ax = 0.f, ay = 0.f;
    int p = b;
    for (; p + 4 <= e; p += 4) {
        const int s0 = csr_col[p + 0], s1 = csr_col[p + 1];
        const int s2 = csr_col[p + 2], s3 = csr_col[p + 3];
        const uint v0 = z2[(size_t)s0 * 256 + t];
        const uint v1 = z2[(size_t)s1 * 256 + t];
        const uint v2 = z2[(size_t)s2 * 256 + t];
        const uint v3 = z2[(size_t)s3 * 256 + t];
        ax += bf2f((ushort)(v0 & 0xffffu)) + bf2f((ushort)(v1 & 0xffffu))
            + bf2f((ushort)(v2 & 0xffffu)) + bf2f((ushort)(v3 & 0xffffu));
        ay += bf2f((ushort)(v0 >> 16)) + bf2f((ushort)(v1 >> 16))
            + bf2f((ushort)(v2 >> 16)) + bf2f((ushort)(v3 >> 16));
    }
    for (; p < e; ++p) {
        const uint v = z2[(size_t)csr_col[p] * 256 + t];
        ax += bf2f((ushort)(v & 0xffffu));
        ay += bf2f((ushort)(v >> 16));
    }
    agg2[(size_t)i * 256 + t] = (uint)f2bf(ax) | ((uint)f2bf(ay) << 16);
}

// one 512x512 matrix per blockIdx.z: Wt[n][k] = bf16(W[k][n])
__global__ __launch_bounds__(256)
void transpose_f32_to_bf16(const float* __restrict__ W, ushort* __restrict__ Wt)
{
    __shared__ float tile[32][33];
    const float* Wm = W + (size_t)blockIdx.z * 512 * 512;
    ushort* Wtm = Wt + (size_t)blockIdx.z * 512 * 512;
    const int c0 = blockIdx.x * 32, r0 = blockIdx.y * 32;
    const int tc = threadIdx.x & 31, tr = threadIdx.x >> 5;
#pragma unroll
    for (int it = 0; it < 4; ++it)
        tile[tr + it * 8][tc] = Wm[(size_t)(r0 + tr + it * 8) * 512 + c0 + tc];
    __syncthreads();
#pragma unroll
    for (int it = 0; it < 4; ++it) {
        const int cr = tr + it * 8;
        Wtm[(size_t)(c0 + cr) * 512 + r0 + tc] = f2bf(tile[tc][cr]);
    }
}

// router tail (unchanged, fp32)
__global__ __launch_bounds__(128)
void router_kernel(const float* __restrict__ rtmp, const int* __restrict__ batch,
                   const float* __restrict__ rW1, const float* __restrict__ rb1,
                   const float* __restrict__ lng, const float* __restrict__ lnb,
                   const float* __restrict__ rW2, const float* __restrict__ rb2,
                   const float* __restrict__ centers,
                   const float* __restrict__ f_norm, const float* __restrict__ size_norm,
                   float* __restrict__ weights)
{
    const int i = blockIdx.x;
    const int j = threadIdx.x;
    const int g = batch[i];
    const float f0 = f_norm[g * 2], f1 = f_norm[g * 2 + 1];
    float r = rtmp[(size_t)i * RH_DIM + j]
            + f0 * rW1[512 * RH_DIM + j] + f1 * rW1[513 * RH_DIM + j] + rb1[j];

    __shared__ float part[2];
    __shared__ float rbuf[RH_DIM];
    __shared__ float lbuf[4];
    const int lane = j & 63, wv = j >> 6;

    float s = r;
#pragma unroll
    for (int o = 32; o > 0; o >>= 1) s += __shfl_xor(s, o);
    if (lane == 0) part[wv] = s;
    __syncthreads();
    const float mean = (part[0] + part[1]) / 128.f;
    __syncthreads();
    const float d = r - mean;
    float v = d * d;
#pragma unroll
    for (int o = 32; o > 0; o >>= 1) v += __shfl_xor(v, o);
    if (lane == 0) part[wv] = v;
    __syncthreads();
    const float var = (part[0] + part[1]) / 128.f;
    const float rn = d / sqrtf(var + 1e-5f) * lng[j] + lnb[j];
    rbuf[j] = fmaxf(rn, 0.f);
    __syncthreads();

    if (j < 4) {
        float acc = rb2[j];
        for (int t = 0; t < RH_DIM; ++t) acc = fmaf(rbuf[t], rW2[t * 4 + j], acc);
        const float sn = size_norm[g];
        const float dd = sn - centers[j];
        lbuf[j] = 0.7f * acc + 0.3f * (-(dd * dd));
    }
    __syncthreads();
    if (j == 0) {
        float p[4];
        const float mx = fmaxf(fmaxf(lbuf[0], lbuf[1]), fmaxf(lbuf[2], lbuf[3]));
#pragma unroll
        for (int c = 0; c < 4; ++c) p[c] = expf(lbuf[c] - mx);
        const float ssum = p[0] + p[1] + p[2] + p[3];
#pragma unroll
        for (int c = 0; c < 4; ++c) p[c] /= ssum;
        int i1 = 0;
#pragma unroll
        for (int c = 1; c < 4; ++c) if (p[c] > p[i1]) i1 = c;
        int i2 = -1;
#pragma unroll
        for (int c = 0; c < 4; ++c) {
            if (c == i1) continue;
            if (i2 < 0 || p[c] > p[i2]) i2 = c;
        }
        const float vs = p[i1] + p[i2] + 1e-8f;
        float wout[4] = {0.f, 0.f, 0.f, 0.f};
        wout[i1] = p[i1] / vs;
        wout[i2] = p[i2] / vs;
#pragma unroll
        for (int c = 0; c < 4; ++c) weights[(size_t)i * 4 + c] = wout[c];
    }
}

extern "C" void kernel_launch(void* const* d_in, const int* in_sizes, int n_in,
                              void* d_out, int out_size, void* d_ws, size_t ws_size,
                              hipStream_t stream)
{
    const float* x       = (const float*)d_in[0];
    const int*   ei      = (const int*)d_in[1];
    const int*   batch   = (const int*)d_in[2];
    const float* enc_W1  = (const float*)d_in[4];
    const float* enc_b1  = (const float*)d_in[5];
    const float* enc_W2  = (const float*)d_in[6];
    const float* enc_b2  = (const float*)d_in[7];
    const float* r_W1    = (const float*)d_in[8];
    const float* r_b1    = (const float*)d_in[9];
    const float* ln_g    = (const float*)d_in[10];
    const float* ln_b    = (const float*)d_in[11];
    const float* r_W2    = (const float*)d_in[12];
    const float* r_b2    = (const float*)d_in[13];
    const float* centers = (const float*)d_in[14];
    const float* W_rel   = (const float*)d_in[15];
    const float* b_rel   = (const float*)d_in[16];
    const float* W_root  = (const float*)d_in[17];
    const int* src = ei;
    const int* dst = ei + N_EDGES;
    float* out = (float*)d_out;

    // ---- workspace layout ----
    char* wsp = (char*)d_ws;
    size_t off = 0;
    auto alloc = [&](size_t bytes) -> char* {
        char* p = wsp + off;
        off = (off + bytes + 255) & ~(size_t)255;
        return p;
    };
    const size_t PF = (size_t)P_ROWS * H_DIM;
    float*  h      = (float*)alloc(PF * 4);          // fp32 h (router path)
    char*   t1reg  = alloc(PF * 4);                  // t1 fp32, later zA16+zB16
    float*  t1     = (float*)t1reg;
    ushort* zA16   = (ushort*)t1reg;
    ushort* zB16   = (ushort*)(t1reg + PF * 2);
    ushort* h16    = (ushort*)alloc(PF * 2);
    char*   aggreg = alloc(PF * 2);                  // agg16; aliased as rtmp fp32 earlier
    ushort* agg16  = (ushort*)aggreg;
    float*  rtmp   = (float*)aggreg;
    ushort* aggH16 = (ushort*)alloc(PF * 2);
    ushort* Wt_rel16  = (ushort*)alloc((size_t)12 * 512 * 512 * 2);
    ushort* Wt_root16 = (ushort*)alloc((size_t)12 * 512 * 512 * 2);
    float*  weights   = (float*)alloc((size_t)P_ROWS * 4 * 4);
    int* deg     = (int*)alloc((size_t)N_NODES * 4);
    int* gstart  = (int*)alloc((size_t)(G_GRAPHS + 1) * 4);
    int* part    = (int*)alloc((size_t)EH_BLOCKS * G_GRAPHS * 4);
    int* row_ptr = (int*)alloc((size_t)(N_NODES + 1) * 4);
    int* cursor  = (int*)alloc((size_t)N_NODES * 4);
    int* csr_col = (int*)alloc((size_t)N_EDGES * 4);
    float* f_norm    = (float*)alloc((size_t)G_GRAPHS * 2 * 4);
    float* size_norm = (float*)alloc((size_t)G_GRAPHS * 4);
    (void)ws_size; (void)in_sizes; (void)n_in; (void)out_size;

    const dim3 gemm_grid(H_DIM / BN, P_ROWS / BM);   // fp32 enc (4,157)
    const dim3 gemm_grid_r(1, P_ROWS / BM);          // fp32 router (1,157)
    const dim3 mfma_grid(4, P_ROWS / 128);           // bf16 experts (4,157)
    const dim3 tr_grid(16, 16, 12);

    // 0) zero deg + one-time weight transpose/convert
    zero_ints_kernel<<<(N_NODES + 255) / 256, 256, 0, stream>>>(deg, N_NODES);
    transpose_f32_to_bf16<<<tr_grid, 256, 0, stream>>>(W_rel, Wt_rel16);
    transpose_f32_to_bf16<<<tr_grid, 256, 0, stream>>>(W_root, Wt_root16);
    // 1) graph stats (contention-free)
    graph_bounds_kernel<<<1, 128, 0, stream>>>(batch, gstart);
    edge_hist_kernel<<<EH_BLOCKS, 256, 0, stream>>>(src, dst, batch, part, deg);
    stats_finalize_kernel<<<1, 64, 0, stream>>>(gstart, part, f_norm, size_norm);
    // 2) encoder (fp32 — feeds router selection; bf16 copy fused into epilogue)
    encoder1_kernel<<<(N_NODES * H_DIM + 255) / 256, 256, 0, stream>>>(x, enc_W1, enc_b1, t1);
    gemm_kernel<false, true><<<gemm_grid, 256, 0, stream>>>(
        t1, enc_W2, enc_b2, h, h16, P_ROWS, H_DIM, H_DIM);
    // 3) router (fp32)
    gemm_kernel<false, false><<<gemm_grid_r, 256, 0, stream>>>(
        h, r_W1, nullptr, rtmp, nullptr, P_ROWS, RH_DIM, H_DIM);
    router_kernel<<<N_NODES, 128, 0, stream>>>(rtmp, batch, r_W1, r_b1, ln_g, ln_b,
                                               r_W2, r_b2, centers, f_norm, size_norm, weights);
    // 4) CSR build (deterministic: sorted adjacency)
    scan_kernel<<<1, 1024, 0, stream>>>(deg, row_ptr, cursor, N_NODES);
    scatter_kernel<<<(N_EDGES + 255) / 256, 256, 0, stream>>>(src, dst, cursor, csr_col);
    sort_adj_kernel<<<(N_NODES + 255) / 256, 256, 0, stream>>>(row_ptr, csr_col);
    // 5) shared layer-0 aggregation (identical for all experts)
    aggregate_bf16<<<N_NODES, 256, 0, stream>>>((const uint*)h16, row_ptr, csr_col, (uint*)aggH16);

    // 6) experts (bf16 MFMA)
    for (int e = 0; e < NE_EXP; ++e) {
        const ushort* Wr0 = Wt_rel16  + (size_t)(e * 3 + 0) * 512 * 512;
        const ushort* Wr1 = Wt_rel16  + (size_t)(e * 3 + 1) * 512 * 512;
        const ushort* Wr2 = Wt_rel16  + (size_t)(e * 3 + 2) * 512 * 512;
        const ushort* Wo0 = Wt_root16 + (size_t)(e * 3 + 0) * 512 * 512;
        const ushort* Wo1 = Wt_root16 + (size_t)(e * 3 + 1) * 512 * 512;
        const ushort* Wo2 = Wt_root16 + (size_t)(e * 3 + 2) * 512 * 512;
        const float* br0 = b_rel + (size_t)(e * 3 + 0) * H_DIM;
        const float* br1 = b_rel + (size_t)(e * 3 + 1) * H_DIM;
        const float* br2 = b_rel + (size_t)(e * 3 + 2) * H_DIM;

        gemm_bt_bf16<true, 0><<<mfma_grid, 256, 0, stream>>>(
            aggH16, Wr0, h16, Wo0, br0, nullptr, zA16);

        aggregate_bf16<<<N_NODES, 256, 0, stream>>>((const uint*)zA16, row_ptr, csr_col, (uint*)agg16);
        gemm_bt_bf16<true, 0><<<mfma_grid, 256, 0, stream>>>(
            agg16, Wr1, zA16, Wo1, br1, nullptr, zB16);

        aggregate_bf16<<<N_NODES, 256, 0, stream>>>((const uint*)zB16, row_ptr, csr_col, (uint*)agg16);
        if (e == 0) {
            gemm_bt_bf16<false, 3><<<mfma_grid, 256, 0, stream>>>(
                agg16, Wr2, zB16, Wo2, br2, weights + e, out);
        } else {
            gemm_bt_bf16<false, 2><<<mfma_grid, 256, 0, stream>>>(
                agg16, Wr2, zB16, Wo2, br2, weights + e, out);
        }
    }
}

// Round 4
// 974.560 us; speedup vs baseline: 4.6461x; 1.2533x over previous
//
#include <hip/hip_runtime.h>
#include <math.h>

// ---------------- problem constants (match reference) ----------------
#define N_NODES 20000
#define N_EDGES 160000
#define G_GRAPHS 64
#define H_DIM 512
#define RH_DIM 128
#define NE_EXP 4
#define P_ROWS 20096   // 157 * 128, padded row count for GEMM tiles
#define EH_BLOCKS 64   // edge-histogram partial blocks

// ================= bf16 helpers =================
typedef __attribute__((ext_vector_type(8))) short bf16x8;
typedef __attribute__((ext_vector_type(4))) float f32x4;

__device__ __forceinline__ ushort f2bf(float f) {
    uint u = __float_as_uint(f);
    return (ushort)((u + 0x7FFFu + ((u >> 16) & 1u)) >> 16);  // round-to-nearest-even
}
__device__ __forceinline__ float bf2f(ushort h) {
    return __uint_as_float(((uint)h) << 16);
}

__device__ __forceinline__ void async_copy16(const void* g, void* l) {
    __builtin_amdgcn_global_load_lds(
        (__attribute__((address_space(1))) void*)g,
        (__attribute__((address_space(3))) void*)l, 16, 0, 0);
}

// ================= unified bf16 MFMA GEMM, 2-phase pipelined =================
// C = sum_p A[p] @ W[p]^T (+ bias)   (W stored n-major: W[n][k], k-stride 512)
// A rows: P_ROWS, row stride 512. Output row stride = Ncols (128 or 512).
// EPI 0: out0[r][c] = bf16(relu?(v+bias))
// EPI 2: out0[r][c] += wcol[r*4]*(v+bias)  fp32, rows < N_NODES
// EPI 3: out0[r][c]  = wcol[r*4]*(v+bias)  fp32, rows < N_NODES
// EPI 4: hi/lo bf16 split -> out0/out1 (no relu)
// EPI 5: out0[r][c] = v  fp32
template<int NPASS, bool RELU, int EPI>
__global__ __launch_bounds__(256)
void gemm_mfma(const ushort* __restrict__ A0, const ushort* __restrict__ W0,
               const ushort* __restrict__ A1p, const ushort* __restrict__ W1p,
               const ushort* __restrict__ A2p, const ushort* __restrict__ W2p,
               const float* __restrict__ bias, const float* __restrict__ wcol,
               void* __restrict__ out0, void* __restrict__ out1, int Ncols)
{
    __shared__ char smem[32768];   // 2 bufs x (A 8KB | B 8KB)
    const int tid = threadIdx.x;
    const int w = tid >> 6, lane = tid & 63;
    const int m0 = blockIdx.y * 128;
    const int n0 = blockIdx.x * 128;

    f32x4 acc[4][4];
#pragma unroll
    for (int i = 0; i < 4; ++i)
#pragma unroll
        for (int j = 0; j < 4; ++j) acc[i][j] = (f32x4){0.f, 0.f, 0.f, 0.f};

    const int srow = lane >> 2, schk = lane & 3;
    const int wr = w >> 1, wc = w & 1;
    const int row16 = lane & 15;
    const uint koffB = (uint)(lane >> 4) * 16u;
    const uint aoff0 = (uint)(wr * 64 + row16) * 64u + koffB;
    const uint boff0 = 8192u + (uint)(wc * 64 + row16) * 64u + koffB;

    const int NT = NPASS * 16;
    auto Asel = [&](int t) -> const ushort* { return (t < 16) ? A0 : ((t < 32) ? A1p : A2p); };
    auto Wsel = [&](int t) -> const ushort* { return (t < 16) ? W0 : ((t < 32) ? W1p : W2p); };

    auto stage = [&](int buf, int t) {
        const ushort* __restrict__ A  = Asel(t);
        const ushort* __restrict__ Wt = Wsel(t);
        const int kt = (t & 15) * 32;
        char* base = smem + buf * 16384;
#pragma unroll
        for (int c = 0; c < 2; ++c) {
            const int rb = c * 64 + w * 16;   // wave-uniform LDS row base
            async_copy16(A  + (size_t)(m0 + rb + srow) * 512 + kt + schk * 8, base + rb * 64);
            async_copy16(Wt + (size_t)(n0 + rb + srow) * 512 + kt + schk * 8, base + 8192 + rb * 64);
        }
    };
    auto compute = [&](int buf) {
        const char* base = smem + buf * 16384;
        bf16x8 af[4], bfr[4];
#pragma unroll
        for (int i = 0; i < 4; ++i) af[i] = *(const bf16x8*)(base + aoff0 + i * 1024);
#pragma unroll
        for (int j = 0; j < 4; ++j) bfr[j] = *(const bf16x8*)(base + boff0 + j * 1024);
#pragma unroll
        for (int i = 0; i < 4; ++i)
#pragma unroll
            for (int j = 0; j < 4; ++j)
                acc[i][j] = __builtin_amdgcn_mfma_f32_16x16x32_bf16(af[i], bfr[j], acc[i][j], 0, 0, 0);
    };

    // 2-phase pipeline: stage(t+1) in flight while computing tile t (T3+T4).
    stage(0, 0);
    for (int t = 0; t < NT - 1; ++t) {
        stage((t + 1) & 1, t + 1);
        asm volatile("s_waitcnt vmcnt(4)" ::: "memory");  // tile t landed (own loads)
        __builtin_amdgcn_s_barrier();                     // all waves' tile t landed
        compute(t & 1);
        __builtin_amdgcn_s_barrier();                     // all waves done reading buf t&1
    }
    asm volatile("s_waitcnt vmcnt(0)" ::: "memory");
    __builtin_amdgcn_s_barrier();
    compute((NT - 1) & 1);

    // ---- epilogue ----  C/D layout: col = lane&15, row = (lane>>4)*4 + q
#pragma unroll
    for (int i = 0; i < 4; ++i) {
        const int r0 = m0 + wr * 64 + i * 16 + (lane >> 4) * 4;
#pragma unroll
        for (int j = 0; j < 4; ++j) {
            const int c = n0 + wc * 64 + j * 16 + row16;
            const float bj = (EPI == 5) ? 0.f : bias[c];
#pragma unroll
            for (int q = 0; q < 4; ++q) {
                const int r = r0 + q;
                float v = acc[i][j][q] + bj;
                if (EPI == 0) {
                    if (RELU) v = fmaxf(v, 0.f);
                    ((ushort*)out0)[(size_t)r * Ncols + c] = f2bf(v);
                } else if (EPI == 4) {
                    const ushort hi = f2bf(v);
                    const ushort lo = f2bf(v - bf2f(hi));
                    ((ushort*)out0)[(size_t)r * Ncols + c] = hi;
                    ((ushort*)out1)[(size_t)r * Ncols + c] = lo;
                } else if (EPI == 5) {
                    ((float*)out0)[(size_t)r * Ncols + c] = v;
                } else {
                    if (r < N_NODES) {
                        const float wrow = wcol[(size_t)r * 4];
                        if (EPI == 3) ((float*)out0)[(size_t)r * Ncols + c] = wrow * v;
                        else          ((float*)out0)[(size_t)r * Ncols + c] += wrow * v;
                    }
                }
            }
        }
    }
}

// t1 = relu(x[:,4:10] @ enc_W1 + enc_b1), split into bf16 hi+lo; zero pad rows
__global__ void encoder1_kernel(const float* __restrict__ x, const float* __restrict__ W1,
                                const float* __restrict__ b1,
                                ushort* __restrict__ t1hi, ushort* __restrict__ t1lo)
{
    const int idx = blockIdx.x * blockDim.x + threadIdx.x;
    if (idx >= P_ROWS * H_DIM) return;
    const int i = idx / H_DIM, j = idx - i * H_DIM;
    float v = 0.f;
    if (i < N_NODES) {
        const float* xr = &x[i * 16 + 4];
        v = b1[j];
#pragma unroll
        for (int k = 0; k < 6; ++k) v = fmaf(xr[k], W1[k * H_DIM + j], v);
        v = fmaxf(v, 0.f);
    }
    const ushort hi = f2bf(v);
    t1hi[idx] = hi;
    t1lo[idx] = f2bf(v - bf2f(hi));
}

__global__ void zero_ints_kernel(int* __restrict__ p, int n)
{
    const int idx = blockIdx.x * blockDim.x + threadIdx.x;
    if (idx < n) p[idx] = 0;
}

// 65 binary searches on sorted batch -> graph start offsets (no atomics)
__global__ void graph_bounds_kernel(const int* __restrict__ batch, int* __restrict__ gstart)
{
    const int g = threadIdx.x;
    if (g > G_GRAPHS) return;
    int lo = 0, hi = N_NODES;
    while (lo < hi) {
        const int mid = (lo + hi) >> 1;
        if (batch[mid] < g) lo = mid + 1; else hi = mid;
    }
    gstart[g] = lo;
}

// per-block LDS histogram of edge graphs + in-degree atomics (spread addresses)
__global__ __launch_bounds__(256)
void edge_hist_kernel(const int* __restrict__ src, const int* __restrict__ dst,
                      const int* __restrict__ batch,
                      int* __restrict__ part, int* __restrict__ deg)
{
    __shared__ int hist[G_GRAPHS];
    const int tid = threadIdx.x;
    if (tid < G_GRAPHS) hist[tid] = 0;
    __syncthreads();
    for (int e = blockIdx.x * 256 + tid; e < N_EDGES; e += EH_BLOCKS * 256) {
        atomicAdd(&deg[dst[e]], 1);
        atomicAdd(&hist[batch[src[e]]], 1);
    }
    __syncthreads();
    if (tid < G_GRAPHS) part[blockIdx.x * G_GRAPHS + tid] = hist[tid];
}

// 64 threads (one wave): reduce partials, log/normalize per-graph features
__global__ void stats_finalize_kernel(const int* __restrict__ gstart, const int* __restrict__ part,
                                      float* __restrict__ f_norm, float* __restrict__ size_norm)
{
    const int g = threadIdx.x;  // exactly 64
    const float nn = fmaxf((float)(gstart[g + 1] - gstart[g]), 1.0f);
    int ec = 0;
#pragma unroll 8
    for (int b = 0; b < EH_BLOCKS; ++b) ec += part[b * G_GRAPHS + g];
    const float ee = (float)ec;
    const float ln = logf(nn);
    const float le = log1pf(ee);
    float s0 = ln, s1 = le;
#pragma unroll
    for (int o = 32; o > 0; o >>= 1) { s0 += __shfl_xor(s0, o); s1 += __shfl_xor(s1, o); }
    const float m0 = s0 / 64.f, m1 = s1 / 64.f;
    const float d0 = ln - m0, d1 = le - m1;
    float v0 = d0 * d0, v1 = d1 * d1;
#pragma unroll
    for (int o = 32; o > 0; o >>= 1) { v0 += __shfl_xor(v0, o); v1 += __shfl_xor(v1, o); }
    const float sd0 = sqrtf(v0 / 64.f), sd1 = sqrtf(v1 / 64.f);
    float mn = ln, mx = ln;
#pragma unroll
    for (int o = 32; o > 0; o >>= 1) {
        mn = fminf(mn, __shfl_xor(mn, o));
        mx = fmaxf(mx, __shfl_xor(mx, o));
    }
    f_norm[g * 2 + 0] = d0 / (sd0 + 1e-6f);
    f_norm[g * 2 + 1] = d1 / (sd1 + 1e-6f);
    size_norm[g] = (ln - mn) / (mx - mn + 1e-6f);
}

// single-block shuffle-based exclusive scan of deg -> row_ptr (+copy to cursor)
__global__ void scan_kernel(const int* __restrict__ in, int* __restrict__ row_ptr,
                            int* __restrict__ cursor, int n)
{
    __shared__ int wsum[16];
    __shared__ int carry_s;
    const int tid = threadIdx.x;
    const int lane = tid & 63, wv = tid >> 6;
    if (tid == 0) carry_s = 0;
    __syncthreads();
    for (int base = 0; base < n; base += 1024) {
        const int idx = base + tid;
        const int v = (idx < n) ? in[idx] : 0;
        int x = v;
#pragma unroll
        for (int o = 1; o < 64; o <<= 1) { const int t = __shfl_up(x, o); if (lane >= o) x += t; }
        if (lane == 63) wsum[wv] = x;
        __syncthreads();
        const int carry = carry_s;
        if (wv == 0) {
            int y = (lane < 16) ? wsum[lane] : 0;
#pragma unroll
            for (int o = 1; o < 16; o <<= 1) { const int t = __shfl_up(y, o); if (lane >= o) y += t; }
            if (lane < 16) wsum[lane] = y;
        }
        __syncthreads();
        const int woff = (wv > 0) ? wsum[wv - 1] : 0;
        const int excl = x - v + woff + carry;
        if (idx < n) { row_ptr[idx] = excl; cursor[idx] = excl; }
        __syncthreads();
        if (tid == 0) carry_s = carry + wsum[15];
        __syncthreads();
    }
    if (tid == 0) row_ptr[n] = carry_s;
}

__global__ void scatter_kernel(const int* __restrict__ src, const int* __restrict__ dst,
                               int* __restrict__ cursor, int* __restrict__ csr_col)
{
    const int e = blockIdx.x * blockDim.x + threadIdx.x;
    if (e >= N_EDGES) return;
    const int d = dst[e];
    const int slot = atomicAdd(&cursor[d], 1);
    csr_col[slot] = src[e];
}

__global__ void sort_adj_kernel(const int* __restrict__ row_ptr, int* __restrict__ csr_col)
{
    const int i = blockIdx.x * blockDim.x + threadIdx.x;
    if (i >= N_NODES) return;
    const int b = row_ptr[i], e = row_ptr[i + 1];
    for (int p = b + 1; p < e; ++p) {
        const int key = csr_col[p];
        int q = p - 1;
        while (q >= b && csr_col[q] > key) { csr_col[q + 1] = csr_col[q]; --q; }
        csr_col[q + 1] = key;
    }
}

// agg[i,:] = sum over in-edges of z[src,:]  (bf16 in/out, fp32 accumulate, 4-wide ILP)
__global__ __launch_bounds__(256)
void aggregate_bf16(const uint* __restrict__ z2, const int* __restrict__ row_ptr,
                    const int* __restrict__ csr_col, uint* __restrict__ agg2)
{
    const int i = blockIdx.x;
    const int t = threadIdx.x;   // 2 cols per thread
    const int b = row_ptr[i], e = row_ptr[i + 1];
    float ax = 0.f, ay = 0.f;
    int p = b;
    for (; p + 4 <= e; p += 4) {
        const int s0 = csr_col[p + 0], s1 = csr_col[p + 1];
        const int s2 = csr_col[p + 2], s3 = csr_col[p + 3];
        const uint v0 = z2[(size_t)s0 * 256 + t];
        const uint v1 = z2[(size_t)s1 * 256 + t];
        const uint v2 = z2[(size_t)s2 * 256 + t];
        const uint v3 = z2[(size_t)s3 * 256 + t];
        ax += bf2f((ushort)(v0 & 0xffffu)) + bf2f((ushort)(v1 & 0xffffu))
            + bf2f((ushort)(v2 & 0xffffu)) + bf2f((ushort)(v3 & 0xffffu));
        ay += bf2f((ushort)(v0 >> 16)) + bf2f((ushort)(v1 >> 16))
            + bf2f((ushort)(v2 >> 16)) + bf2f((ushort)(v3 >> 16));
    }
    for (; p < e; ++p) {
        const uint v = z2[(size_t)csr_col[p] * 256 + t];
        ax += bf2f((ushort)(v & 0xffffu));
        ay += bf2f((ushort)(v >> 16));
    }
    agg2[(size_t)i * 256 + t] = (uint)f2bf(ax) | ((uint)f2bf(ay) << 16);
}

// one 512x512 matrix per blockIdx.z: Wt[n][k] = bf16(W[k][n])   (experts, hi only)
__global__ __launch_bounds__(256)
void transpose_f32_to_bf16(const float* __restrict__ W, ushort* __restrict__ Wt)
{
    __shared__ float tile[32][33];
    const float* Wm = W + (size_t)blockIdx.z * 512 * 512;
    ushort* Wtm = Wt + (size_t)blockIdx.z * 512 * 512;
    const int c0 = blockIdx.x * 32, r0 = blockIdx.y * 32;
    const int tc = threadIdx.x & 31, tr = threadIdx.x >> 5;
#pragma unroll
    for (int it = 0; it < 4; ++it)
        tile[tr + it * 8][tc] = Wm[(size_t)(r0 + tr + it * 8) * 512 + c0 + tc];
    __syncthreads();
#pragma unroll
    for (int it = 0; it < 4; ++it) {
        const int cr = tr + it * 8;
        Wtm[(size_t)(c0 + cr) * 512 + r0 + tc] = f2bf(tile[tc][cr]);
    }
}

// W [512][Nin] fp32 -> Wt hi/lo [Nin][512] bf16 (k-stride 512)
__global__ __launch_bounds__(256)
void transpose_split_kernel(const float* __restrict__ W, ushort* __restrict__ Whi,
                            ushort* __restrict__ Wlo, int Nin)
{
    __shared__ float tile[32][33];
    const int c0 = blockIdx.x * 32;   // col in W = row of Wt
    const int r0 = blockIdx.y * 32;   // k
    const int tc = threadIdx.x & 31, tr = threadIdx.x >> 5;
#pragma unroll
    for (int it = 0; it < 4; ++it)
        tile[tr + it * 8][tc] = W[(size_t)(r0 + tr + it * 8) * Nin + c0 + tc];
    __syncthreads();
#pragma unroll
    for (int it = 0; it < 4; ++it) {
        const int cr = tr + it * 8;
        const float v = tile[tc][cr];
        const ushort hi = f2bf(v);
        Whi[(size_t)(c0 + cr) * 512 + r0 + tc] = hi;
        Wlo[(size_t)(c0 + cr) * 512 + r0 + tc] = f2bf(v - bf2f(hi));
    }
}

// router tail (fp32)
__global__ __launch_bounds__(128)
void router_kernel(const float* __restrict__ rtmp, const int* __restrict__ batch,
                   const float* __restrict__ rW1, const float* __restrict__ rb1,
                   const float* __restrict__ lng, const float* __restrict__ lnb,
                   const float* __restrict__ rW2, const float* __restrict__ rb2,
                   const float* __restrict__ centers,
                   const float* __restrict__ f_norm, const float* __restrict__ size_norm,
                   float* __restrict__ weights)
{
    const int i = blockIdx.x;
    const int j = threadIdx.x;
    const int g = batch[i];
    const float f0 = f_norm[g * 2], f1 = f_norm[g * 2 + 1];
    float r = rtmp[(size_t)i * RH_DIM + j]
            + f0 * rW1[512 * RH_DIM + j] + f1 * rW1[513 * RH_DIM + j] + rb1[j];

    __shared__ float part[2];
    __shared__ float rbuf[RH_DIM];
    __shared__ float lbuf[4];
    const int lane = j & 63, wv = j >> 6;

    float s = r;
#pragma unroll
    for (int o = 32; o > 0; o >>= 1) s += __shfl_xor(s, o);
    if (lane == 0) part[wv] = s;
    __syncthreads();
    const float mean = (part[0] + part[1]) / 128.f;
    __syncthreads();
    const float d = r - mean;
    float v = d * d;
#pragma unroll
    for (int o = 32; o > 0; o >>= 1) v += __shfl_xor(v, o);
    if (lane == 0) part[wv] = v;
    __syncthreads();
    const float var = (part[0] + part[1]) / 128.f;
    const float rn = d / sqrtf(var + 1e-5f) * lng[j] + lnb[j];
    rbuf[j] = fmaxf(rn, 0.f);
    __syncthreads();

    if (j < 4) {
        float acc = rb2[j];
        for (int t = 0; t < RH_DIM; ++t) acc = fmaf(rbuf[t], rW2[t * 4 + j], acc);
        const float sn = size_norm[g];
        const float dd = sn - centers[j];
        lbuf[j] = 0.7f * acc + 0.3f * (-(dd * dd));
    }
    __syncthreads();
    if (j == 0) {
        float p[4];
        const float mx = fmaxf(fmaxf(lbuf[0], lbuf[1]), fmaxf(lbuf[2], lbuf[3]));
#pragma unroll
        for (int c = 0; c < 4; ++c) p[c] = expf(lbuf[c] - mx);
        const float ssum = p[0] + p[1] + p[2] + p[3];
#pragma unroll
        for (int c = 0; c < 4; ++c) p[c] /= ssum;
        int i1 = 0;
#pragma unroll
        for (int c = 1; c < 4; ++c) if (p[c] > p[i1]) i1 = c;
        int i2 = -1;
#pragma unroll
        for (int c = 0; c < 4; ++c) {
            if (c == i1) continue;
            if (i2 < 0 || p[c] > p[i2]) i2 = c;
        }
        const float vs = p[i1] + p[i2] + 1e-8f;
        float wout[4] = {0.f, 0.f, 0.f, 0.f};
        wout[i1] = p[i1] / vs;
        wout[i2] = p[i2] / vs;
#pragma unroll
        for (int c = 0; c < 4; ++c) weights[(size_t)i * 4 + c] = wout[c];
    }
}

extern "C" void kernel_launch(void* const* d_in, const int* in_sizes, int n_in,
                              void* d_out, int out_size, void* d_ws, size_t ws_size,
                              hipStream_t stream)
{
    const float* x       = (const float*)d_in[0];
    const int*   ei      = (const int*)d_in[1];
    const int*   batch   = (const int*)d_in[2];
    const float* enc_W1  = (const float*)d_in[4];
    const float* enc_b1  = (const float*)d_in[5];
    const float* enc_W2  = (const float*)d_in[6];
    const float* enc_b2  = (const float*)d_in[7];
    const float* r_W1    = (const float*)d_in[8];
    const float* r_b1    = (const float*)d_in[9];
    const float* ln_g    = (const float*)d_in[10];
    const float* ln_b    = (const float*)d_in[11];
    const float* r_W2    = (const float*)d_in[12];
    const float* r_b2    = (const float*)d_in[13];
    const float* centers = (const float*)d_in[14];
    const float* W_rel   = (const float*)d_in[15];
    const float* b_rel   = (const float*)d_in[16];
    const float* W_root  = (const float*)d_in[17];
    const int* src = ei;
    const int* dst = ei + N_EDGES;
    float* out = (float*)d_out;

    // ---- workspace layout (~135 MB) ----
    char* wsp = (char*)d_ws;
    size_t off = 0;
    auto alloc = [&](size_t bytes) -> char* {
        char* p = wsp + off;
        off = (off + bytes + 255) & ~(size_t)255;
        return p;
    };
    const size_t PF = (size_t)P_ROWS * H_DIM;
    // region1: t1hi|t1lo  -> later zA16|zB16 ; rtmp aliases first half (transient)
    char* region1 = alloc(PF * 4);
    ushort* t1hi = (ushort*)region1;
    ushort* t1lo = (ushort*)(region1 + PF * 2);
    ushort* zA16 = (ushort*)region1;
    ushort* zB16 = (ushort*)(region1 + PF * 2);
    float*  rtmp = (float*)region1;                 // P_ROWS*128*4 = 10.3MB
    // region2: h_hi | h_lo ; agg16 aliases h_lo after router GEMM
    char* region2 = alloc(PF * 4);
    ushort* h_hi  = (ushort*)region2;
    ushort* h_lo  = (ushort*)(region2 + PF * 2);
    ushort* agg16 = (ushort*)(region2 + PF * 2);
    ushort* aggH16 = (ushort*)alloc(PF * 2);
    ushort* Wt_rel16  = (ushort*)alloc((size_t)12 * 512 * 512 * 2);
    ushort* Wt_root16 = (ushort*)alloc((size_t)12 * 512 * 512 * 2);
    ushort* W2t_hi = (ushort*)alloc((size_t)512 * 512 * 2);
    ushort* W2t_lo = (ushort*)alloc((size_t)512 * 512 * 2);
    ushort* rW1t_hi = (ushort*)alloc((size_t)128 * 512 * 2);
    ushort* rW1t_lo = (ushort*)alloc((size_t)128 * 512 * 2);
    float*  weights   = (float*)alloc((size_t)P_ROWS * 4 * 4);
    int* deg     = (int*)alloc((size_t)N_NODES * 4);
    int* gstart  = (int*)alloc((size_t)(G_GRAPHS + 1) * 4);
    int* part    = (int*)alloc((size_t)EH_BLOCKS * G_GRAPHS * 4);
    int* row_ptr = (int*)alloc((size_t)(N_NODES + 1) * 4);
    int* cursor  = (int*)alloc((size_t)N_NODES * 4);
    int* csr_col = (int*)alloc((size_t)N_EDGES * 4);
    float* f_norm    = (float*)alloc((size_t)G_GRAPHS * 2 * 4);
    float* size_norm = (float*)alloc((size_t)G_GRAPHS * 4);
    (void)ws_size; (void)in_sizes; (void)n_in; (void)out_size;

    const dim3 mfma_grid(4, P_ROWS / 128);     // Ncols=512
    const dim3 mfma_grid_r(1, P_ROWS / 128);   // Ncols=128
    const dim3 tr_grid(16, 16, 12);

    // 0) zero deg + one-time weight transposes/splits
    zero_ints_kernel<<<(N_NODES + 255) / 256, 256, 0, stream>>>(deg, N_NODES);
    transpose_f32_to_bf16<<<tr_grid, 256, 0, stream>>>(W_rel, Wt_rel16);
    transpose_f32_to_bf16<<<tr_grid, 256, 0, stream>>>(W_root, Wt_root16);
    transpose_split_kernel<<<dim3(16, 16), 256, 0, stream>>>(enc_W2, W2t_hi, W2t_lo, 512);
    transpose_split_kernel<<<dim3(4, 16), 256, 0, stream>>>(r_W1, rW1t_hi, rW1t_lo, 128);
    // 1) graph stats (contention-free)
    graph_bounds_kernel<<<1, 128, 0, stream>>>(batch, gstart);
    edge_hist_kernel<<<EH_BLOCKS, 256, 0, stream>>>(src, dst, batch, part, deg);
    stats_finalize_kernel<<<1, 64, 0, stream>>>(gstart, part, f_norm, size_norm);
    // 2) encoder: t1 (split) then h = t1@W2 via bf16x3 -> h_hi/h_lo
    encoder1_kernel<<<(P_ROWS * H_DIM + 255) / 256, 256, 0, stream>>>(x, enc_W1, enc_b1, t1hi, t1lo);
    gemm_mfma<3, false, 4><<<mfma_grid, 256, 0, stream>>>(
        t1hi, W2t_hi, t1hi, W2t_lo, t1lo, W2t_hi, enc_b2, nullptr, h_hi, h_lo, 512);
    // 3) router: rtmp = h@rW1 via bf16x3 (t1 region reusable now)
    gemm_mfma<3, false, 5><<<mfma_grid_r, 256, 0, stream>>>(
        h_hi, rW1t_hi, h_hi, rW1t_lo, h_lo, rW1t_hi, nullptr, nullptr, rtmp, nullptr, 128);
    router_kernel<<<N_NODES, 128, 0, stream>>>(rtmp, batch, r_W1, r_b1, ln_g, ln_b,
                                               r_W2, r_b2, centers, f_norm, size_norm, weights);
    // 4) CSR build (deterministic: sorted adjacency)
    scan_kernel<<<1, 1024, 0, stream>>>(deg, row_ptr, cursor, N_NODES);
    scatter_kernel<<<(N_EDGES + 255) / 256, 256, 0, stream>>>(src, dst, cursor, csr_col);
    sort_adj_kernel<<<(N_NODES + 255) / 256, 256, 0, stream>>>(row_ptr, csr_col);
    // 5) shared layer-0 aggregation (identical for all experts)
    aggregate_bf16<<<N_NODES, 256, 0, stream>>>((const uint*)h_hi, row_ptr, csr_col, (uint*)aggH16);

    // 6) experts (bf16 MFMA dual, 2-phase pipelined)
    for (int e = 0; e < NE_EXP; ++e) {
        const ushort* Wr0 = Wt_rel16  + (size_t)(e * 3 + 0) * 512 * 512;
        const ushort* Wr1 = Wt_rel16  + (size_t)(e * 3 + 1) * 512 * 512;
        const ushort* Wr2 = Wt_rel16  + (size_t)(e * 3 + 2) * 512 * 512;
        const ushort* Wo0 = Wt_root16 + (size_t)(e * 3 + 0) * 512 * 512;
        const ushort* Wo1 = Wt_root16 + (size_t)(e * 3 + 1) * 512 * 512;
        const ushort* Wo2 = Wt_root16 + (size_t)(e * 3 + 2) * 512 * 512;
        const float* br0 = b_rel + (size_t)(e * 3 + 0) * H_DIM;
        const float* br1 = b_rel + (size_t)(e * 3 + 1) * H_DIM;
        const float* br2 = b_rel + (size_t)(e * 3 + 2) * H_DIM;

        gemm_mfma<2, true, 0><<<mfma_grid, 256, 0, stream>>>(
            aggH16, Wr0, h_hi, Wo0, nullptr, nullptr, br0, nullptr, zA16, nullptr, 512);

        aggregate_bf16<<<N_NODES, 256, 0, stream>>>((const uint*)zA16, row_ptr, csr_col, (uint*)agg16);
        gemm_mfma<2, true, 0><<<mfma_grid, 256, 0, stream>>>(
            agg16, Wr1, zA16, Wo1, nullptr, nullptr, br1, nullptr, zB16, nullptr, 512);

        aggregate_bf16<<<N_NODES, 256, 0, stream>>>((const uint*)zB16, row_ptr, csr_col, (uint*)agg16);
        if (e == 0) {
            gemm_mfma<2, false, 3><<<mfma_grid, 256, 0, stream>>>(
                agg16, Wr2, zB16, Wo2, nullptr, nullptr, br2, weights + e, out, nullptr, 512);
        } else {
            gemm_mfma<2, false, 2><<<mfma_grid, 256, 0, stream>>>(
                agg16, Wr2, zB16, Wo2, nullptr, nullptr, br2, weights + e, out, nullptr, 512);
        }
    }
}

// Round 5
// 931.951 us; speedup vs baseline: 4.8585x; 1.0457x over previous
//
#include <hip/hip_runtime.h>
#include <math.h>

// ---------------- problem constants (match reference) ----------------
#define N_NODES 20000
#define N_EDGES 160000
#define G_GRAPHS 64
#define H_DIM 512
#define RH_DIM 128
#define NE_EXP 4
#define P_ROWS 20096   // 157 * 128, padded row count for GEMM tiles
#define EH_BLOCKS 64   // edge-histogram partial blocks

// ================= bf16 helpers =================
typedef __attribute__((ext_vector_type(8))) short bf16x8;
typedef __attribute__((ext_vector_type(4))) float f32x4;

__device__ __forceinline__ ushort f2bf(float f) {
    uint u = __float_as_uint(f);
    return (ushort)((u + 0x7FFFu + ((u >> 16) & 1u)) >> 16);  // round-to-nearest-even
}
__device__ __forceinline__ float bf2f(ushort h) {
    return __uint_as_float(((uint)h) << 16);
}

__device__ __forceinline__ void async_copy16(const void* g, void* l) {
    __builtin_amdgcn_global_load_lds(
        (__attribute__((address_space(1))) void*)g,
        (__attribute__((address_space(3))) void*)l, 16, 0, 0);
}

// ================= unified bf16 MFMA GEMM, 2-phase pipelined =================
// C = sum_p A[p] @ W[p]^T (+ bias)   (W stored n-major: W[n][k], k-stride 512)
// A rows: P_ROWS, row stride 512. Output row stride = Ncols (128 or 512).
// Grid: 1D, NBM*NBN blocks, bijective XCD-chunk swizzle (T1, m204):
// each XCD gets a contiguous wgid chunk, n fastest -> A-panel stays in one L2.
// EPI 0: out0[r][c] = bf16(relu?(v+bias))
// EPI 2: out0[r][c] += wcol[r*4]*(v+bias)  fp32, rows < N_NODES
// EPI 3: out0[r][c]  = wcol[r*4]*(v+bias)  fp32, rows < N_NODES
// EPI 4: hi/lo bf16 split -> out0/out1 (no relu)
// EPI 5: out0[r][c] = v  fp32
template<int NPASS, bool RELU, int EPI, int NBN>
__global__ __launch_bounds__(256)
void gemm_mfma(const ushort* __restrict__ A0, const ushort* __restrict__ W0,
               const ushort* __restrict__ A1p, const ushort* __restrict__ W1p,
               const ushort* __restrict__ A2p, const ushort* __restrict__ W2p,
               const float* __restrict__ bias, const float* __restrict__ wcol,
               void* __restrict__ out0, void* __restrict__ out1, int Ncols)
{
    __shared__ char smem[32768];   // 2 bufs x (A 8KB | B 8KB)
    const int tid = threadIdx.x;
    const int w = tid >> 6, lane = tid & 63;

    // ---- T1 bijective XCD swizzle (m204) ----
    const int nwg = gridDim.x;
    const int orig = blockIdx.x;
    const int q = nwg >> 3, r = nwg & 7;
    const int xcd = orig & 7, sid = orig >> 3;
    const int wgid = (xcd < r ? xcd * (q + 1) : r * (q + 1) + (xcd - r) * q) + sid;
    const int m0 = (wgid / NBN) * 128;
    const int n0 = (wgid % NBN) * 128;

    f32x4 acc[4][4];
#pragma unroll
    for (int i = 0; i < 4; ++i)
#pragma unroll
        for (int j = 0; j < 4; ++j) acc[i][j] = (f32x4){0.f, 0.f, 0.f, 0.f};

    const int srow = lane >> 2, schk = lane & 3;
    const int wr = w >> 1, wc = w & 1;
    const int row16 = lane & 15;
    const uint koffB = (uint)(lane >> 4) * 16u;
    const uint aoff0 = (uint)(wr * 64 + row16) * 64u + koffB;
    const uint boff0 = 8192u + (uint)(wc * 64 + row16) * 64u + koffB;

    const int NT = NPASS * 16;
    auto Asel = [&](int t) -> const ushort* { return (t < 16) ? A0 : ((t < 32) ? A1p : A2p); };
    auto Wsel = [&](int t) -> const ushort* { return (t < 16) ? W0 : ((t < 32) ? W1p : W2p); };

    auto stage = [&](int buf, int t) {
        const ushort* __restrict__ A  = Asel(t);
        const ushort* __restrict__ Wt = Wsel(t);
        const int kt = (t & 15) * 32;
        char* base = smem + buf * 16384;
#pragma unroll
        for (int c = 0; c < 2; ++c) {
            const int rb = c * 64 + w * 16;   // wave-uniform LDS row base
            async_copy16(A  + (size_t)(m0 + rb + srow) * 512 + kt + schk * 8, base + rb * 64);
            async_copy16(Wt + (size_t)(n0 + rb + srow) * 512 + kt + schk * 8, base + 8192 + rb * 64);
        }
    };
    auto compute = [&](int buf) {
        const char* base = smem + buf * 16384;
        bf16x8 af[4], bfr[4];
#pragma unroll
        for (int i = 0; i < 4; ++i) af[i] = *(const bf16x8*)(base + aoff0 + i * 1024);
#pragma unroll
        for (int j = 0; j < 4; ++j) bfr[j] = *(const bf16x8*)(base + boff0 + j * 1024);
#pragma unroll
        for (int i = 0; i < 4; ++i)
#pragma unroll
            for (int j = 0; j < 4; ++j)
                acc[i][j] = __builtin_amdgcn_mfma_f32_16x16x32_bf16(af[i], bfr[j], acc[i][j], 0, 0, 0);
    };

    // 2-phase pipeline: stage(t+1) in flight while computing tile t (T3+T4).
    stage(0, 0);
    for (int t = 0; t < NT - 1; ++t) {
        stage((t + 1) & 1, t + 1);
        asm volatile("s_waitcnt vmcnt(4)" ::: "memory");  // tile t landed (own loads)
        __builtin_amdgcn_s_barrier();                     // all waves' tile t landed
        compute(t & 1);
        __builtin_amdgcn_s_barrier();                     // all waves done reading buf t&1
    }
    asm volatile("s_waitcnt vmcnt(0)" ::: "memory");
    __builtin_amdgcn_s_barrier();
    compute((NT - 1) & 1);

    // ---- epilogue ----  C/D layout: col = lane&15, row = (lane>>4)*4 + q
#pragma unroll
    for (int i = 0; i < 4; ++i) {
        const int r0 = m0 + wr * 64 + i * 16 + (lane >> 4) * 4;
#pragma unroll
        for (int j = 0; j < 4; ++j) {
            const int c = n0 + wc * 64 + j * 16 + row16;
            const float bj = (EPI == 5) ? 0.f : bias[c];
#pragma unroll
            for (int q2 = 0; q2 < 4; ++q2) {
                const int r = r0 + q2;
                float v = acc[i][j][q2] + bj;
                if (EPI == 0) {
                    if (RELU) v = fmaxf(v, 0.f);
                    ((ushort*)out0)[(size_t)r * Ncols + c] = f2bf(v);
                } else if (EPI == 4) {
                    const ushort hi = f2bf(v);
                    const ushort lo = f2bf(v - bf2f(hi));
                    ((ushort*)out0)[(size_t)r * Ncols + c] = hi;
                    ((ushort*)out1)[(size_t)r * Ncols + c] = lo;
                } else if (EPI == 5) {
                    ((float*)out0)[(size_t)r * Ncols + c] = v;
                } else {
                    if (r < N_NODES) {
                        const float wrow = wcol[(size_t)r * 4];
                        if (EPI == 3) ((float*)out0)[(size_t)r * Ncols + c] = wrow * v;
                        else          ((float*)out0)[(size_t)r * Ncols + c] += wrow * v;
                    }
                }
            }
        }
    }
}

// t1 = relu(x[:,4:10] @ enc_W1 + enc_b1), split into bf16 hi+lo; zero pad rows
__global__ void encoder1_kernel(const float* __restrict__ x, const float* __restrict__ W1,
                                const float* __restrict__ b1,
                                ushort* __restrict__ t1hi, ushort* __restrict__ t1lo)
{
    const int idx = blockIdx.x * blockDim.x + threadIdx.x;
    if (idx >= P_ROWS * H_DIM) return;
    const int i = idx / H_DIM, j = idx - i * H_DIM;
    float v = 0.f;
    if (i < N_NODES) {
        const float* xr = &x[i * 16 + 4];
        v = b1[j];
#pragma unroll
        for (int k = 0; k < 6; ++k) v = fmaf(xr[k], W1[k * H_DIM + j], v);
        v = fmaxf(v, 0.f);
    }
    const ushort hi = f2bf(v);
    t1hi[idx] = hi;
    t1lo[idx] = f2bf(v - bf2f(hi));
}

__global__ void zero_ints_kernel(int* __restrict__ p, int n)
{
    const int idx = blockIdx.x * blockDim.x + threadIdx.x;
    if (idx < n) p[idx] = 0;
}

// 65 binary searches on sorted batch -> graph start offsets (no atomics)
__global__ void graph_bounds_kernel(const int* __restrict__ batch, int* __restrict__ gstart)
{
    const int g = threadIdx.x;
    if (g > G_GRAPHS) return;
    int lo = 0, hi = N_NODES;
    while (lo < hi) {
        const int mid = (lo + hi) >> 1;
        if (batch[mid] < g) lo = mid + 1; else hi = mid;
    }
    gstart[g] = lo;
}

// per-block LDS histogram of edge graphs + in-degree atomics (spread addresses)
__global__ __launch_bounds__(256)
void edge_hist_kernel(const int* __restrict__ src, const int* __restrict__ dst,
                      const int* __restrict__ batch,
                      int* __restrict__ part, int* __restrict__ deg)
{
    __shared__ int hist[G_GRAPHS];
    const int tid = threadIdx.x;
    if (tid < G_GRAPHS) hist[tid] = 0;
    __syncthreads();
    for (int e = blockIdx.x * 256 + tid; e < N_EDGES; e += EH_BLOCKS * 256) {
        atomicAdd(&deg[dst[e]], 1);
        atomicAdd(&hist[batch[src[e]]], 1);
    }
    __syncthreads();
    if (tid < G_GRAPHS) part[blockIdx.x * G_GRAPHS + tid] = hist[tid];
}

// 64 threads (one wave): reduce partials, log/normalize per-graph features
__global__ void stats_finalize_kernel(const int* __restrict__ gstart, const int* __restrict__ part,
                                      float* __restrict__ f_norm, float* __restrict__ size_norm)
{
    const int g = threadIdx.x;  // exactly 64
    const float nn = fmaxf((float)(gstart[g + 1] - gstart[g]), 1.0f);
    int ec = 0;
#pragma unroll 8
    for (int b = 0; b < EH_BLOCKS; ++b) ec += part[b * G_GRAPHS + g];
    const float ee = (float)ec;
    const float ln = logf(nn);
    const float le = log1pf(ee);
    float s0 = ln, s1 = le;
#pragma unroll
    for (int o = 32; o > 0; o >>= 1) { s0 += __shfl_xor(s0, o); s1 += __shfl_xor(s1, o); }
    const float m0 = s0 / 64.f, m1 = s1 / 64.f;
    const float d0 = ln - m0, d1 = le - m1;
    float v0 = d0 * d0, v1 = d1 * d1;
#pragma unroll
    for (int o = 32; o > 0; o >>= 1) { v0 += __shfl_xor(v0, o); v1 += __shfl_xor(v1, o); }
    const float sd0 = sqrtf(v0 / 64.f), sd1 = sqrtf(v1 / 64.f);
    float mn = ln, mx = ln;
#pragma unroll
    for (int o = 32; o > 0; o >>= 1) {
        mn = fminf(mn, __shfl_xor(mn, o));
        mx = fmaxf(mx, __shfl_xor(mx, o));
    }
    f_norm[g * 2 + 0] = d0 / (sd0 + 1e-6f);
    f_norm[g * 2 + 1] = d1 / (sd1 + 1e-6f);
    size_norm[g] = (ln - mn) / (mx - mn + 1e-6f);
}

// single-block shuffle-based exclusive scan of deg -> row_ptr (+copy to cursor)
__global__ void scan_kernel(const int* __restrict__ in, int* __restrict__ row_ptr,
                            int* __restrict__ cursor, int n)
{
    __shared__ int wsum[16];
    __shared__ int carry_s;
    const int tid = threadIdx.x;
    const int lane = tid & 63, wv = tid >> 6;
    if (tid == 0) carry_s = 0;
    __syncthreads();
    for (int base = 0; base < n; base += 1024) {
        const int idx = base + tid;
        const int v = (idx < n) ? in[idx] : 0;
        int x = v;
#pragma unroll
        for (int o = 1; o < 64; o <<= 1) { const int t = __shfl_up(x, o); if (lane >= o) x += t; }
        if (lane == 63) wsum[wv] = x;
        __syncthreads();
        const int carry = carry_s;
        if (wv == 0) {
            int y = (lane < 16) ? wsum[lane] : 0;
#pragma unroll
            for (int o = 1; o < 16; o <<= 1) { const int t = __shfl_up(y, o); if (lane >= o) y += t; }
            if (lane < 16) wsum[lane] = y;
        }
        __syncthreads();
        const int woff = (wv > 0) ? wsum[wv - 1] : 0;
        const int excl = x - v + woff + carry;
        if (idx < n) { row_ptr[idx] = excl; cursor[idx] = excl; }
        __syncthreads();
        if (tid == 0) carry_s = carry + wsum[15];
        __syncthreads();
    }
    if (tid == 0) row_ptr[n] = carry_s;
}

__global__ void scatter_kernel(const int* __restrict__ src, const int* __restrict__ dst,
                               int* __restrict__ cursor, int* __restrict__ csr_col)
{
    const int e = blockIdx.x * blockDim.x + threadIdx.x;
    if (e >= N_EDGES) return;
    const int d = dst[e];
    const int slot = atomicAdd(&cursor[d], 1);
    csr_col[slot] = src[e];
}

__global__ void sort_adj_kernel(const int* __restrict__ row_ptr, int* __restrict__ csr_col)
{
    const int i = blockIdx.x * blockDim.x + threadIdx.x;
    if (i >= N_NODES) return;
    const int b = row_ptr[i], e = row_ptr[i + 1];
    for (int p = b + 1; p < e; ++p) {
        const int key = csr_col[p];
        int q = p - 1;
        while (q >= b && csr_col[q] > key) { csr_col[q + 1] = csr_col[q]; --q; }
        csr_col[q + 1] = key;
    }
}

// agg[i,:] = sum over in-edges of z[src,:]  (bf16 in/out, fp32 accumulate, 4-wide ILP)
__global__ __launch_bounds__(256)
void aggregate_bf16(const uint* __restrict__ z2, const int* __restrict__ row_ptr,
                    const int* __restrict__ csr_col, uint* __restrict__ agg2)
{
    const int i = blockIdx.x;
    const int t = threadIdx.x;   // 2 cols per thread
    const int b = row_ptr[i], e = row_ptr[i + 1];
    float ax = 0.f, ay = 0.f;
    int p = b;
    for (; p + 4 <= e; p += 4) {
        const int s0 = csr_col[p + 0], s1 = csr_col[p + 1];
        const int s2 = csr_col[p + 2], s3 = csr_col[p + 3];
        const uint v0 = z2[(size_t)s0 * 256 + t];
        const uint v1 = z2[(size_t)s1 * 256 + t];
        const uint v2 = z2[(size_t)s2 * 256 + t];
        const uint v3 = z2[(size_t)s3 * 256 + t];
        ax += bf2f((ushort)(v0 & 0xffffu)) + bf2f((ushort)(v1 & 0xffffu))
            + bf2f((ushort)(v2 & 0xffffu)) + bf2f((ushort)(v3 & 0xffffu));
        ay += bf2f((ushort)(v0 >> 16)) + bf2f((ushort)(v1 >> 16))
            + bf2f((ushort)(v2 >> 16)) + bf2f((ushort)(v3 >> 16));
    }
    for (; p < e; ++p) {
        const uint v = z2[(size_t)csr_col[p] * 256 + t];
        ax += bf2f((ushort)(v & 0xffffu));
        ay += bf2f((ushort)(v >> 16));
    }
    agg2[(size_t)i * 256 + t] = (uint)f2bf(ax) | ((uint)f2bf(ay) << 16);
}

// one 512x512 matrix per blockIdx.z: Wt[n][k] = bf16(W[k][n])   (experts, hi only)
__global__ __launch_bounds__(256)
void transpose_f32_to_bf16(const float* __restrict__ W, ushort* __restrict__ Wt)
{
    __shared__ float tile[32][33];
    const float* Wm = W + (size_t)blockIdx.z * 512 * 512;
    ushort* Wtm = Wt + (size_t)blockIdx.z * 512 * 512;
    const int c0 = blockIdx.x * 32, r0 = blockIdx.y * 32;
    const int tc = threadIdx.x & 31, tr = threadIdx.x >> 5;
#pragma unroll
    for (int it = 0; it < 4; ++it)
        tile[tr + it * 8][tc] = Wm[(size_t)(r0 + tr + it * 8) * 512 + c0 + tc];
    __syncthreads();
#pragma unroll
    for (int it = 0; it < 4; ++it) {
        const int cr = tr + it * 8;
        Wtm[(size_t)(c0 + cr) * 512 + r0 + tc] = f2bf(tile[tc][cr]);
    }
}

// W [512][Nin] fp32 -> Wt hi/lo [Nin][512] bf16 (k-stride 512)
__global__ __launch_bounds__(256)
void transpose_split_kernel(const float* __restrict__ W, ushort* __restrict__ Whi,
                            ushort* __restrict__ Wlo, int Nin)
{
    __shared__ float tile[32][33];
    const int c0 = blockIdx.x * 32;   // col in W = row of Wt
    const int r0 = blockIdx.y * 32;   // k
    const int tc = threadIdx.x & 31, tr = threadIdx.x >> 5;
#pragma unroll
    for (int it = 0; it < 4; ++it)
        tile[tr + it * 8][tc] = W[(size_t)(r0 + tr + it * 8) * Nin + c0 + tc];
    __syncthreads();
#pragma unroll
    for (int it = 0; it < 4; ++it) {
        const int cr = tr + it * 8;
        const float v = tile[tc][cr];
        const ushort hi = f2bf(v);
        Whi[(size_t)(c0 + cr) * 512 + r0 + tc] = hi;
        Wlo[(size_t)(c0 + cr) * 512 + r0 + tc] = f2bf(v - bf2f(hi));
    }
}

// router tail (fp32)
__global__ __launch_bounds__(128)
void router_kernel(const float* __restrict__ rtmp, const int* __restrict__ batch,
                   const float* __restrict__ rW1, const float* __restrict__ rb1,
                   const float* __restrict__ lng, const float* __restrict__ lnb,
                   const float* __restrict__ rW2, const float* __restrict__ rb2,
                   const float* __restrict__ centers,
                   const float* __restrict__ f_norm, const float* __restrict__ size_norm,
                   float* __restrict__ weights)
{
    const int i = blockIdx.x;
    const int j = threadIdx.x;
    const int g = batch[i];
    const float f0 = f_norm[g * 2], f1 = f_norm[g * 2 + 1];
    float r = rtmp[(size_t)i * RH_DIM + j]
            + f0 * rW1[512 * RH_DIM + j] + f1 * rW1[513 * RH_DIM + j] + rb1[j];

    __shared__ float part[2];
    __shared__ float rbuf[RH_DIM];
    __shared__ float lbuf[4];
    const int lane = j & 63, wv = j >> 6;

    float s = r;
#pragma unroll
    for (int o = 32; o > 0; o >>= 1) s += __shfl_xor(s, o);
    if (lane == 0) part[wv] = s;
    __syncthreads();
    const float mean = (part[0] + part[1]) / 128.f;
    __syncthreads();
    const float d = r - mean;
    float v = d * d;
#pragma unroll
    for (int o = 32; o > 0; o >>= 1) v += __shfl_xor(v, o);
    if (lane == 0) part[wv] = v;
    __syncthreads();
    const float var = (part[0] + part[1]) / 128.f;
    const float rn = d / sqrtf(var + 1e-5f) * lng[j] + lnb[j];
    rbuf[j] = fmaxf(rn, 0.f);
    __syncthreads();

    if (j < 4) {
        float acc = rb2[j];
        for (int t = 0; t < RH_DIM; ++t) acc = fmaf(rbuf[t], rW2[t * 4 + j], acc);
        const float sn = size_norm[g];
        const float dd = sn - centers[j];
        lbuf[j] = 0.7f * acc + 0.3f * (-(dd * dd));
    }
    __syncthreads();
    if (j == 0) {
        float p[4];
        const float mx = fmaxf(fmaxf(lbuf[0], lbuf[1]), fmaxf(lbuf[2], lbuf[3]));
#pragma unroll
        for (int c = 0; c < 4; ++c) p[c] = expf(lbuf[c] - mx);
        const float ssum = p[0] + p[1] + p[2] + p[3];
#pragma unroll
        for (int c = 0; c < 4; ++c) p[c] /= ssum;
        int i1 = 0;
#pragma unroll
        for (int c = 1; c < 4; ++c) if (p[c] > p[i1]) i1 = c;
        int i2 = -1;
#pragma unroll
        for (int c = 0; c < 4; ++c) {
            if (c == i1) continue;
            if (i2 < 0 || p[c] > p[i2]) i2 = c;
        }
        const float vs = p[i1] + p[i2] + 1e-8f;
        float wout[4] = {0.f, 0.f, 0.f, 0.f};
        wout[i1] = p[i1] / vs;
        wout[i2] = p[i2] / vs;
#pragma unroll
        for (int c = 0; c < 4; ++c) weights[(size_t)i * 4 + c] = wout[c];
    }
}

extern "C" void kernel_launch(void* const* d_in, const int* in_sizes, int n_in,
                              void* d_out, int out_size, void* d_ws, size_t ws_size,
                              hipStream_t stream)
{
    const float* x       = (const float*)d_in[0];
    const int*   ei      = (const int*)d_in[1];
    const int*   batch   = (const int*)d_in[2];
    const float* enc_W1  = (const float*)d_in[4];
    const float* enc_b1  = (const float*)d_in[5];
    const float* enc_W2  = (const float*)d_in[6];
    const float* enc_b2  = (const float*)d_in[7];
    const float* r_W1    = (const float*)d_in[8];
    const float* r_b1    = (const float*)d_in[9];
    const float* ln_g    = (const float*)d_in[10];
    const float* ln_b    = (const float*)d_in[11];
    const float* r_W2    = (const float*)d_in[12];
    const float* r_b2    = (const float*)d_in[13];
    const float* centers = (const float*)d_in[14];
    const float* W_rel   = (const float*)d_in[15];
    const float* b_rel   = (const float*)d_in[16];
    const float* W_root  = (const float*)d_in[17];
    const int* src = ei;
    const int* dst = ei + N_EDGES;
    float* out = (float*)d_out;

    // ---- workspace layout (~135 MB) ----
    char* wsp = (char*)d_ws;
    size_t off = 0;
    auto alloc = [&](size_t bytes) -> char* {
        char* p = wsp + off;
        off = (off + bytes + 255) & ~(size_t)255;
        return p;
    };
    const size_t PF = (size_t)P_ROWS * H_DIM;
    // region1: t1hi|t1lo  -> later zA16|zB16 ; rtmp aliases first half (transient)
    char* region1 = alloc(PF * 4);
    ushort* t1hi = (ushort*)region1;
    ushort* t1lo = (ushort*)(region1 + PF * 2);
    ushort* zA16 = (ushort*)region1;
    ushort* zB16 = (ushort*)(region1 + PF * 2);
    float*  rtmp = (float*)region1;                 // P_ROWS*128*4 = 10.3MB
    // region2: h_hi | h_lo ; agg16 aliases h_lo after router GEMM
    char* region2 = alloc(PF * 4);
    ushort* h_hi  = (ushort*)region2;
    ushort* h_lo  = (ushort*)(region2 + PF * 2);
    ushort* agg16 = (ushort*)(region2 + PF * 2);
    ushort* aggH16 = (ushort*)alloc(PF * 2);
    ushort* Wt_rel16  = (ushort*)alloc((size_t)12 * 512 * 512 * 2);
    ushort* Wt_root16 = (ushort*)alloc((size_t)12 * 512 * 512 * 2);
    ushort* W2t_hi = (ushort*)alloc((size_t)512 * 512 * 2);
    ushort* W2t_lo = (ushort*)alloc((size_t)512 * 512 * 2);
    ushort* rW1t_hi = (ushort*)alloc((size_t)128 * 512 * 2);
    ushort* rW1t_lo = (ushort*)alloc((size_t)128 * 512 * 2);
    float*  weights   = (float*)alloc((size_t)P_ROWS * 4 * 4);
    int* deg     = (int*)alloc((size_t)N_NODES * 4);
    int* gstart  = (int*)alloc((size_t)(G_GRAPHS + 1) * 4);
    int* part    = (int*)alloc((size_t)EH_BLOCKS * G_GRAPHS * 4);
    int* row_ptr = (int*)alloc((size_t)(N_NODES + 1) * 4);
    int* cursor  = (int*)alloc((size_t)N_NODES * 4);
    int* csr_col = (int*)alloc((size_t)N_EDGES * 4);
    float* f_norm    = (float*)alloc((size_t)G_GRAPHS * 2 * 4);
    float* size_norm = (float*)alloc((size_t)G_GRAPHS * 4);
    (void)ws_size; (void)in_sizes; (void)n_in; (void)out_size;

    const int mfma_nwg   = 4 * (P_ROWS / 128);   // 628: NBN=4 (Ncols=512)
    const int mfma_nwg_r = 1 * (P_ROWS / 128);   // 157: NBN=1 (Ncols=128)
    const dim3 tr_grid(16, 16, 12);

    // 0) zero deg + one-time weight transposes/splits
    zero_ints_kernel<<<(N_NODES + 255) / 256, 256, 0, stream>>>(deg, N_NODES);
    transpose_f32_to_bf16<<<tr_grid, 256, 0, stream>>>(W_rel, Wt_rel16);
    transpose_f32_to_bf16<<<tr_grid, 256, 0, stream>>>(W_root, Wt_root16);
    transpose_split_kernel<<<dim3(16, 16), 256, 0, stream>>>(enc_W2, W2t_hi, W2t_lo, 512);
    transpose_split_kernel<<<dim3(4, 16), 256, 0, stream>>>(r_W1, rW1t_hi, rW1t_lo, 128);
    // 1) graph stats (contention-free)
    graph_bounds_kernel<<<1, 128, 0, stream>>>(batch, gstart);
    edge_hist_kernel<<<EH_BLOCKS, 256, 0, stream>>>(src, dst, batch, part, deg);
    stats_finalize_kernel<<<1, 64, 0, stream>>>(gstart, part, f_norm, size_norm);
    // 2) encoder: t1 (split) then h = t1@W2 via bf16x3 -> h_hi/h_lo
    encoder1_kernel<<<(P_ROWS * H_DIM + 255) / 256, 256, 0, stream>>>(x, enc_W1, enc_b1, t1hi, t1lo);
    gemm_mfma<3, false, 4, 4><<<mfma_nwg, 256, 0, stream>>>(
        t1hi, W2t_hi, t1hi, W2t_lo, t1lo, W2t_hi, enc_b2, nullptr, h_hi, h_lo, 512);
    // 3) router: rtmp = h@rW1 via bf16x3 (t1 region reusable now)
    gemm_mfma<3, false, 5, 1><<<mfma_nwg_r, 256, 0, stream>>>(
        h_hi, rW1t_hi, h_hi, rW1t_lo, h_lo, rW1t_hi, nullptr, nullptr, rtmp, nullptr, 128);
    router_kernel<<<N_NODES, 128, 0, stream>>>(rtmp, batch, r_W1, r_b1, ln_g, ln_b,
                                               r_W2, r_b2, centers, f_norm, size_norm, weights);
    // 4) CSR build (deterministic: sorted adjacency)
    scan_kernel<<<1, 1024, 0, stream>>>(deg, row_ptr, cursor, N_NODES);
    scatter_kernel<<<(N_EDGES + 255) / 256, 256, 0, stream>>>(src, dst, cursor, csr_col);
    sort_adj_kernel<<<(N_NODES + 255) / 256, 256, 0, stream>>>(row_ptr, csr_col);
    // 5) shared layer-0 aggregation (identical for all experts)
    aggregate_bf16<<<N_NODES, 256, 0, stream>>>((const uint*)h_hi, row_ptr, csr_col, (uint*)aggH16);

    // 6) experts (bf16 MFMA dual, 2-phase pipelined, XCD-swizzled)
    for (int e = 0; e < NE_EXP; ++e) {
        const ushort* Wr0 = Wt_rel16  + (size_t)(e * 3 + 0) * 512 * 512;
        const ushort* Wr1 = Wt_rel16  + (size_t)(e * 3 + 1) * 512 * 512;
        const ushort* Wr2 = Wt_rel16  + (size_t)(e * 3 + 2) * 512 * 512;
        const ushort* Wo0 = Wt_root16 + (size_t)(e * 3 + 0) * 512 * 512;
        const ushort* Wo1 = Wt_root16 + (size_t)(e * 3 + 1) * 512 * 512;
        const ushort* Wo2 = Wt_root16 + (size_t)(e * 3 + 2) * 512 * 512;
        const float* br0 = b_rel + (size_t)(e * 3 + 0) * H_DIM;
        const float* br1 = b_rel + (size_t)(e * 3 + 1) * H_DIM;
        const float* br2 = b_rel + (size_t)(e * 3 + 2) * H_DIM;

        gemm_mfma<2, true, 0, 4><<<mfma_nwg, 256, 0, stream>>>(
            aggH16, Wr0, h_hi, Wo0, nullptr, nullptr, br0, nullptr, zA16, nullptr, 512);

        aggregate_bf16<<<N_NODES, 256, 0, stream>>>((const uint*)zA16, row_ptr, csr_col, (uint*)agg16);
        gemm_mfma<2, true, 0, 4><<<mfma_nwg, 256, 0, stream>>>(
            agg16, Wr1, zA16, Wo1, nullptr, nullptr, br1, nullptr, zB16, nullptr, 512);

        aggregate_bf16<<<N_NODES, 256, 0, stream>>>((const uint*)zB16, row_ptr, csr_col, (uint*)agg16);
        if (e == 0) {
            gemm_mfma<2, false, 3, 4><<<mfma_nwg, 256, 0, stream>>>(
                agg16, Wr2, zB16, Wo2, nullptr, nullptr, br2, weights + e, out, nullptr, 512);
        } else {
            gemm_mfma<2, false, 2, 4><<<mfma_nwg, 256, 0, stream>>>(
                agg16, Wr2, zB16, Wo2, nullptr, nullptr, br2, weights + e, out, nullptr, 512);
        }
    }
}

// Round 6
// 863.031 us; speedup vs baseline: 5.2465x; 1.0799x over previous
//
#include <hip/hip_runtime.h>
#include <math.h>

// ---------------- problem constants (match reference) ----------------
#define N_NODES 20000
#define N_EDGES 160000
#define G_GRAPHS 64
#define H_DIM 512
#define RH_DIM 128
#define NE_EXP 4
#define P_ROWS 20096   // 157 * 128, padded row count for GEMM tiles
#define EH_BLOCKS 64   // edge-histogram partial blocks
#define WSZ (512 * 512)

// ================= bf16 helpers =================
typedef __attribute__((ext_vector_type(8))) short bf16x8;
typedef __attribute__((ext_vector_type(4))) float f32x4;

__device__ __forceinline__ ushort f2bf(float f) {
    uint u = __float_as_uint(f);
    return (ushort)((u + 0x7FFFu + ((u >> 16) & 1u)) >> 16);  // round-to-nearest-even
}
__device__ __forceinline__ float bf2f(ushort h) {
    return __uint_as_float(((uint)h) << 16);
}

__device__ __forceinline__ void async_copy16(const void* g, void* l) {
    __builtin_amdgcn_global_load_lds(
        (__attribute__((address_space(1))) void*)g,
        (__attribute__((address_space(3))) void*)l, 16, 0, 0);
}

// ---- T1 bijective XCD swizzle (m204) ----
__device__ __forceinline__ int xcd_swizzle(int orig, int nwg) {
    const int q = nwg >> 3, r = nwg & 7;
    const int xcd = orig & 7, sid = orig >> 3;
    return (xcd < r ? xcd * (q + 1) : r * (q + 1) + (xcd - r) * q) + sid;
}

// ================= grouped expert GEMM (pair of experts per launch) =========
// Per block: one (m, n, e) tile of C_e = A1_e@W1_e^T + A2_e@W2_e^T + bias_e.
// Grid = 157*4*2 = 1256 (m-major after swizzle -> same-m blocks share an XCD L2).
// EPI 0: out bf16(relu?(v+bias))
// EPI 6: out bf16((v+bias) * wcol[r*4+e])   (weighted expert output, pad rows 0)
template<bool RELU, int EPI>
__global__ __launch_bounds__(256)
void gemm_grp(const ushort* __restrict__ A1, size_t a1es,
              const ushort* __restrict__ W1, size_t w1es,
              const ushort* __restrict__ A2, size_t a2es,
              const ushort* __restrict__ W2, size_t w2es,
              const float* __restrict__ bias, size_t bes,
              const float* __restrict__ wcol,
              ushort* __restrict__ out0, size_t oes)
{
    __shared__ char smem[32768];   // 2 bufs x (A 8KB | B 8KB)
    const int tid = threadIdx.x;
    const int w = tid >> 6, lane = tid & 63;

    const int wgid = xcd_swizzle(blockIdx.x, gridDim.x);
    const int m0 = (wgid >> 3) * 128;
    const int rem = wgid & 7;
    const int n0 = (rem >> 1) * 128;
    const int e  = rem & 1;

    const ushort* __restrict__ A1e = A1 + (size_t)e * a1es;
    const ushort* __restrict__ W1e = W1 + (size_t)e * w1es;
    const ushort* __restrict__ A2e = A2 + (size_t)e * a2es;
    const ushort* __restrict__ W2e = W2 + (size_t)e * w2es;
    const float*  __restrict__ be  = bias + (size_t)e * bes;
    ushort* __restrict__ oe = out0 + (size_t)e * oes;

    f32x4 acc[4][4];
#pragma unroll
    for (int i = 0; i < 4; ++i)
#pragma unroll
        for (int j = 0; j < 4; ++j) acc[i][j] = (f32x4){0.f, 0.f, 0.f, 0.f};

    const int srow = lane >> 2, schk = lane & 3;
    const int wr = w >> 1, wc = w & 1;
    const int row16 = lane & 15;
    const uint koffB = (uint)(lane >> 4) * 16u;
    const uint aoff0 = (uint)(wr * 64 + row16) * 64u + koffB;
    const uint boff0 = 8192u + (uint)(wc * 64 + row16) * 64u + koffB;

    auto stage = [&](int buf, int t) {
        const ushort* __restrict__ A  = (t < 16) ? A1e : A2e;
        const ushort* __restrict__ Wt = (t < 16) ? W1e : W2e;
        const int kt = (t & 15) * 32;
        char* base = smem + buf * 16384;
#pragma unroll
        for (int c = 0; c < 2; ++c) {
            const int rb = c * 64 + w * 16;   // wave-uniform LDS row base
            async_copy16(A  + (size_t)(m0 + rb + srow) * 512 + kt + schk * 8, base + rb * 64);
            async_copy16(Wt + (size_t)(n0 + rb + srow) * 512 + kt + schk * 8, base + 8192 + rb * 64);
        }
    };
    auto compute = [&](int buf) {
        const char* base = smem + buf * 16384;
        bf16x8 af[4], bfr[4];
#pragma unroll
        for (int i = 0; i < 4; ++i) af[i] = *(const bf16x8*)(base + aoff0 + i * 1024);
#pragma unroll
        for (int j = 0; j < 4; ++j) bfr[j] = *(const bf16x8*)(base + boff0 + j * 1024);
#pragma unroll
        for (int i = 0; i < 4; ++i)
#pragma unroll
            for (int j = 0; j < 4; ++j)
                acc[i][j] = __builtin_amdgcn_mfma_f32_16x16x32_bf16(af[i], bfr[j], acc[i][j], 0, 0, 0);
    };

    // 2-phase pipeline (T3 minimum + T4 counted vmcnt)
    stage(0, 0);
    for (int t = 0; t < 31; ++t) {
        stage((t + 1) & 1, t + 1);
        asm volatile("s_waitcnt vmcnt(4)" ::: "memory");
        __builtin_amdgcn_s_barrier();
        compute(t & 1);
        __builtin_amdgcn_s_barrier();
    }
    asm volatile("s_waitcnt vmcnt(0)" ::: "memory");
    __builtin_amdgcn_s_barrier();
    compute(1);

    // epilogue: C/D layout col = lane&15, row = (lane>>4)*4 + q
#pragma unroll
    for (int i = 0; i < 4; ++i) {
        const int r0 = m0 + wr * 64 + i * 16 + (lane >> 4) * 4;
#pragma unroll
        for (int j = 0; j < 4; ++j) {
            const int c = n0 + wc * 64 + j * 16 + row16;
            const float bj = be[c];
#pragma unroll
            for (int q2 = 0; q2 < 4; ++q2) {
                const int r = r0 + q2;
                float v = acc[i][j][q2] + bj;
                if (EPI == 0) {
                    if (RELU) v = fmaxf(v, 0.f);
                    oe[(size_t)r * 512 + c] = f2bf(v);
                } else {  // EPI 6
                    const float wrow = (r < N_NODES) ? wcol[(size_t)r * 4 + e] : 0.f;
                    oe[(size_t)r * 512 + c] = f2bf(v * wrow);
                }
            }
        }
    }
}

// ================= encoder/router bf16x3 GEMM (2-phase, unchanged) ==========
// EPI 4: hi/lo bf16 split -> out0/out1 ; EPI 5: out0 fp32
template<int NPASS, int EPI, int NBN>
__global__ __launch_bounds__(256)
void gemm_mfma(const ushort* __restrict__ A0, const ushort* __restrict__ W0,
               const ushort* __restrict__ A1p, const ushort* __restrict__ W1p,
               const ushort* __restrict__ A2p, const ushort* __restrict__ W2p,
               const float* __restrict__ bias,
               void* __restrict__ out0, void* __restrict__ out1, int Ncols)
{
    __shared__ char smem[32768];
    const int tid = threadIdx.x;
    const int w = tid >> 6, lane = tid & 63;

    const int wgid = xcd_swizzle(blockIdx.x, gridDim.x);
    const int m0 = (wgid / NBN) * 128;
    const int n0 = (wgid % NBN) * 128;

    f32x4 acc[4][4];
#pragma unroll
    for (int i = 0; i < 4; ++i)
#pragma unroll
        for (int j = 0; j < 4; ++j) acc[i][j] = (f32x4){0.f, 0.f, 0.f, 0.f};

    const int srow = lane >> 2, schk = lane & 3;
    const int wr = w >> 1, wc = w & 1;
    const int row16 = lane & 15;
    const uint koffB = (uint)(lane >> 4) * 16u;
    const uint aoff0 = (uint)(wr * 64 + row16) * 64u + koffB;
    const uint boff0 = 8192u + (uint)(wc * 64 + row16) * 64u + koffB;

    const int NT = NPASS * 16;
    auto Asel = [&](int t) -> const ushort* { return (t < 16) ? A0 : ((t < 32) ? A1p : A2p); };
    auto Wsel = [&](int t) -> const ushort* { return (t < 16) ? W0 : ((t < 32) ? W1p : W2p); };

    auto stage = [&](int buf, int t) {
        const ushort* __restrict__ A  = Asel(t);
        const ushort* __restrict__ Wt = Wsel(t);
        const int kt = (t & 15) * 32;
        char* base = smem + buf * 16384;
#pragma unroll
        for (int c = 0; c < 2; ++c) {
            const int rb = c * 64 + w * 16;
            async_copy16(A  + (size_t)(m0 + rb + srow) * 512 + kt + schk * 8, base + rb * 64);
            async_copy16(Wt + (size_t)(n0 + rb + srow) * 512 + kt + schk * 8, base + 8192 + rb * 64);
        }
    };
    auto compute = [&](int buf) {
        const char* base = smem + buf * 16384;
        bf16x8 af[4], bfr[4];
#pragma unroll
        for (int i = 0; i < 4; ++i) af[i] = *(const bf16x8*)(base + aoff0 + i * 1024);
#pragma unroll
        for (int j = 0; j < 4; ++j) bfr[j] = *(const bf16x8*)(base + boff0 + j * 1024);
#pragma unroll
        for (int i = 0; i < 4; ++i)
#pragma unroll
            for (int j = 0; j < 4; ++j)
                acc[i][j] = __builtin_amdgcn_mfma_f32_16x16x32_bf16(af[i], bfr[j], acc[i][j], 0, 0, 0);
    };

    stage(0, 0);
    for (int t = 0; t < NT - 1; ++t) {
        stage((t + 1) & 1, t + 1);
        asm volatile("s_waitcnt vmcnt(4)" ::: "memory");
        __builtin_amdgcn_s_barrier();
        compute(t & 1);
        __builtin_amdgcn_s_barrier();
    }
    asm volatile("s_waitcnt vmcnt(0)" ::: "memory");
    __builtin_amdgcn_s_barrier();
    compute((NT - 1) & 1);

#pragma unroll
    for (int i = 0; i < 4; ++i) {
        const int r0 = m0 + wr * 64 + i * 16 + (lane >> 4) * 4;
#pragma unroll
        for (int j = 0; j < 4; ++j) {
            const int c = n0 + wc * 64 + j * 16 + row16;
            const float bj = (EPI == 5) ? 0.f : bias[c];
#pragma unroll
            for (int q2 = 0; q2 < 4; ++q2) {
                const int r = r0 + q2;
                float v = acc[i][j][q2] + bj;
                if (EPI == 4) {
                    const ushort hi = f2bf(v);
                    const ushort lo = f2bf(v - bf2f(hi));
                    ((ushort*)out0)[(size_t)r * Ncols + c] = hi;
                    ((ushort*)out1)[(size_t)r * Ncols + c] = lo;
                } else {
                    ((float*)out0)[(size_t)r * Ncols + c] = v;
                }
            }
        }
    }
}

// out[r,c] = sum_e bf2f(wz[e][r,c])  (2 cols/thread)
__global__ __launch_bounds__(256)
void reduce_wz_kernel(const uint* __restrict__ wz01, const uint* __restrict__ wz23,
                      float2* __restrict__ out)
{
    const size_t idx = (size_t)blockIdx.x * 256 + threadIdx.x;  // < N_NODES*256
    const size_t es = (size_t)P_ROWS * 256;  // uints per expert
    const uint a = wz01[idx], b = wz01[idx + es];
    const uint c = wz23[idx], d = wz23[idx + es];
    float lo = bf2f((ushort)(a & 0xffffu)) + bf2f((ushort)(b & 0xffffu))
             + bf2f((ushort)(c & 0xffffu)) + bf2f((ushort)(d & 0xffffu));
    float hi = bf2f((ushort)(a >> 16)) + bf2f((ushort)(b >> 16))
             + bf2f((ushort)(c >> 16)) + bf2f((ushort)(d >> 16));
    out[idx] = make_float2(lo, hi);
}

// t1 = relu(x[:,4:10] @ enc_W1 + enc_b1), split into bf16 hi+lo; zero pad rows
__global__ void encoder1_kernel(const float* __restrict__ x, const float* __restrict__ W1,
                                const float* __restrict__ b1,
                                ushort* __restrict__ t1hi, ushort* __restrict__ t1lo)
{
    const int idx = blockIdx.x * blockDim.x + threadIdx.x;
    if (idx >= P_ROWS * H_DIM) return;
    const int i = idx / H_DIM, j = idx - i * H_DIM;
    float v = 0.f;
    if (i < N_NODES) {
        const float* xr = &x[i * 16 + 4];
        v = b1[j];
#pragma unroll
        for (int k = 0; k < 6; ++k) v = fmaf(xr[k], W1[k * H_DIM + j], v);
        v = fmaxf(v, 0.f);
    }
    const ushort hi = f2bf(v);
    t1hi[idx] = hi;
    t1lo[idx] = f2bf(v - bf2f(hi));
}

__global__ void zero_ints_kernel(int* __restrict__ p, int n)
{
    const int idx = blockIdx.x * blockDim.x + threadIdx.x;
    if (idx < n) p[idx] = 0;
}

__global__ void graph_bounds_kernel(const int* __restrict__ batch, int* __restrict__ gstart)
{
    const int g = threadIdx.x;
    if (g > G_GRAPHS) return;
    int lo = 0, hi = N_NODES;
    while (lo < hi) {
        const int mid = (lo + hi) >> 1;
        if (batch[mid] < g) lo = mid + 1; else hi = mid;
    }
    gstart[g] = lo;
}

__global__ __launch_bounds__(256)
void edge_hist_kernel(const int* __restrict__ src, const int* __restrict__ dst,
                      const int* __restrict__ batch,
                      int* __restrict__ part, int* __restrict__ deg)
{
    __shared__ int hist[G_GRAPHS];
    const int tid = threadIdx.x;
    if (tid < G_GRAPHS) hist[tid] = 0;
    __syncthreads();
    for (int e = blockIdx.x * 256 + tid; e < N_EDGES; e += EH_BLOCKS * 256) {
        atomicAdd(&deg[dst[e]], 1);
        atomicAdd(&hist[batch[src[e]]], 1);
    }
    __syncthreads();
    if (tid < G_GRAPHS) part[blockIdx.x * G_GRAPHS + tid] = hist[tid];
}

__global__ void stats_finalize_kernel(const int* __restrict__ gstart, const int* __restrict__ part,
                                      float* __restrict__ f_norm, float* __restrict__ size_norm)
{
    const int g = threadIdx.x;  // exactly 64
    const float nn = fmaxf((float)(gstart[g + 1] - gstart[g]), 1.0f);
    int ec = 0;
#pragma unroll 8
    for (int b = 0; b < EH_BLOCKS; ++b) ec += part[b * G_GRAPHS + g];
    const float ee = (float)ec;
    const float ln = logf(nn);
    const float le = log1pf(ee);
    float s0 = ln, s1 = le;
#pragma unroll
    for (int o = 32; o > 0; o >>= 1) { s0 += __shfl_xor(s0, o); s1 += __shfl_xor(s1, o); }
    const float m0 = s0 / 64.f, m1 = s1 / 64.f;
    const float d0 = ln - m0, d1 = le - m1;
    float v0 = d0 * d0, v1 = d1 * d1;
#pragma unroll
    for (int o = 32; o > 0; o >>= 1) { v0 += __shfl_xor(v0, o); v1 += __shfl_xor(v1, o); }
    const float sd0 = sqrtf(v0 / 64.f), sd1 = sqrtf(v1 / 64.f);
    float mn = ln, mx = ln;
#pragma unroll
    for (int o = 32; o > 0; o >>= 1) {
        mn = fminf(mn, __shfl_xor(mn, o));
        mx = fmaxf(mx, __shfl_xor(mx, o));
    }
    f_norm[g * 2 + 0] = d0 / (sd0 + 1e-6f);
    f_norm[g * 2 + 1] = d1 / (sd1 + 1e-6f);
    size_norm[g] = (ln - mn) / (mx - mn + 1e-6f);
}

__global__ void scan_kernel(const int* __restrict__ in, int* __restrict__ row_ptr,
                            int* __restrict__ cursor, int n)
{
    __shared__ int wsum[16];
    __shared__ int carry_s;
    const int tid = threadIdx.x;
    const int lane = tid & 63, wv = tid >> 6;
    if (tid == 0) carry_s = 0;
    __syncthreads();
    for (int base = 0; base < n; base += 1024) {
        const int idx = base + tid;
        const int v = (idx < n) ? in[idx] : 0;
        int x = v;
#pragma unroll
        for (int o = 1; o < 64; o <<= 1) { const int t = __shfl_up(x, o); if (lane >= o) x += t; }
        if (lane == 63) wsum[wv] = x;
        __syncthreads();
        const int carry = carry_s;
        if (wv == 0) {
            int y = (lane < 16) ? wsum[lane] : 0;
#pragma unroll
            for (int o = 1; o < 16; o <<= 1) { const int t = __shfl_up(y, o); if (lane >= o) y += t; }
            if (lane < 16) wsum[lane] = y;
        }
        __syncthreads();
        const int woff = (wv > 0) ? wsum[wv - 1] : 0;
        const int excl = x - v + woff + carry;
        if (idx < n) { row_ptr[idx] = excl; cursor[idx] = excl; }
        __syncthreads();
        if (tid == 0) carry_s = carry + wsum[15];
        __syncthreads();
    }
    if (tid == 0) row_ptr[n] = carry_s;
}

__global__ void scatter_kernel(const int* __restrict__ src, const int* __restrict__ dst,
                               int* __restrict__ cursor, int* __restrict__ csr_col)
{
    const int e = blockIdx.x * blockDim.x + threadIdx.x;
    if (e >= N_EDGES) return;
    const int d = dst[e];
    const int slot = atomicAdd(&cursor[d], 1);
    csr_col[slot] = src[e];
}

__global__ void sort_adj_kernel(const int* __restrict__ row_ptr, int* __restrict__ csr_col)
{
    const int i = blockIdx.x * blockDim.x + threadIdx.x;
    if (i >= N_NODES) return;
    const int b = row_ptr[i], e = row_ptr[i + 1];
    for (int p = b + 1; p < e; ++p) {
        const int key = csr_col[p];
        int q = p - 1;
        while (q >= b && csr_col[q] > key) { csr_col[q + 1] = csr_col[q]; --q; }
        csr_col[q + 1] = key;
    }
}

// agg[e][i,:] = sum over in-edges of z[e][src,:]  (expert = blockIdx.y)
__global__ __launch_bounds__(256)
void aggregate_bf16(const uint* __restrict__ z2, const int* __restrict__ row_ptr,
                    const int* __restrict__ csr_col, uint* __restrict__ agg2)
{
    const size_t es = (size_t)blockIdx.y * P_ROWS * 256;
    const uint* __restrict__ zz = z2 + es;
    uint* __restrict__ aa = agg2 + es;
    const int i = blockIdx.x;
    const int t = threadIdx.x;
    const int b = row_ptr[i], e = row_ptr[i + 1];
    float ax = 0.f, ay = 0.f;
    int p = b;
    for (; p + 4 <= e; p += 4) {
        const int s0 = csr_col[p + 0], s1 = csr_col[p + 1];
        const int s2 = csr_col[p + 2], s3 = csr_col[p + 3];
        const uint v0 = zz[(size_t)s0 * 256 + t];
        const uint v1 = zz[(size_t)s1 * 256 + t];
        const uint v2 = zz[(size_t)s2 * 256 + t];
        const uint v3 = zz[(size_t)s3 * 256 + t];
        ax += bf2f((ushort)(v0 & 0xffffu)) + bf2f((ushort)(v1 & 0xffffu))
            + bf2f((ushort)(v2 & 0xffffu)) + bf2f((ushort)(v3 & 0xffffu));
        ay += bf2f((ushort)(v0 >> 16)) + bf2f((ushort)(v1 >> 16))
            + bf2f((ushort)(v2 >> 16)) + bf2f((ushort)(v3 >> 16));
    }
    for (; p < e; ++p) {
        const uint v = zz[(size_t)csr_col[p] * 256 + t];
        ax += bf2f((ushort)(v & 0xffffu));
        ay += bf2f((ushort)(v >> 16));
    }
    aa[(size_t)i * 256 + t] = (uint)f2bf(ax) | ((uint)f2bf(ay) << 16);
}

// one 512x512 matrix per blockIdx.z: Wt[n][k] = bf16(W[k][n])
__global__ __launch_bounds__(256)
void transpose_f32_to_bf16(const float* __restrict__ W, ushort* __restrict__ Wt)
{
    __shared__ float tile[32][33];
    const float* Wm = W + (size_t)blockIdx.z * WSZ;
    ushort* Wtm = Wt + (size_t)blockIdx.z * WSZ;
    const int c0 = blockIdx.x * 32, r0 = blockIdx.y * 32;
    const int tc = threadIdx.x & 31, tr = threadIdx.x >> 5;
#pragma unroll
    for (int it = 0; it < 4; ++it)
        tile[tr + it * 8][tc] = Wm[(size_t)(r0 + tr + it * 8) * 512 + c0 + tc];
    __syncthreads();
#pragma unroll
    for (int it = 0; it < 4; ++it) {
        const int cr = tr + it * 8;
        Wtm[(size_t)(c0 + cr) * 512 + r0 + tc] = f2bf(tile[tc][cr]);
    }
}

// W [512][Nin] fp32 -> Wt hi/lo [Nin][512] bf16 (k-stride 512)
__global__ __launch_bounds__(256)
void transpose_split_kernel(const float* __restrict__ W, ushort* __restrict__ Whi,
                            ushort* __restrict__ Wlo, int Nin)
{
    __shared__ float tile[32][33];
    const int c0 = blockIdx.x * 32;
    const int r0 = blockIdx.y * 32;
    const int tc = threadIdx.x & 31, tr = threadIdx.x >> 5;
#pragma unroll
    for (int it = 0; it < 4; ++it)
        tile[tr + it * 8][tc] = W[(size_t)(r0 + tr + it * 8) * Nin + c0 + tc];
    __syncthreads();
#pragma unroll
    for (int it = 0; it < 4; ++it) {
        const int cr = tr + it * 8;
        const float v = tile[tc][cr];
        const ushort hi = f2bf(v);
        Whi[(size_t)(c0 + cr) * 512 + r0 + tc] = hi;
        Wlo[(size_t)(c0 + cr) * 512 + r0 + tc] = f2bf(v - bf2f(hi));
    }
}

// router tail (fp32)
__global__ __launch_bounds__(128)
void router_kernel(const float* __restrict__ rtmp, const int* __restrict__ batch,
                   const float* __restrict__ rW1, const float* __restrict__ rb1,
                   const float* __restrict__ lng, const float* __restrict__ lnb,
                   const float* __restrict__ rW2, const float* __restrict__ rb2,
                   const float* __restrict__ centers,
                   const float* __restrict__ f_norm, const float* __restrict__ size_norm,
                   float* __restrict__ weights)
{
    const int i = blockIdx.x;
    const int j = threadIdx.x;
    const int g = batch[i];
    const float f0 = f_norm[g * 2], f1 = f_norm[g * 2 + 1];
    float r = rtmp[(size_t)i * RH_DIM + j]
            + f0 * rW1[512 * RH_DIM + j] + f1 * rW1[513 * RH_DIM + j] + rb1[j];

    __shared__ float part[2];
    __shared__ float rbuf[RH_DIM];
    __shared__ float lbuf[4];
    const int lane = j & 63, wv = j >> 6;

    float s = r;
#pragma unroll
    for (int o = 32; o > 0; o >>= 1) s += __shfl_xor(s, o);
    if (lane == 0) part[wv] = s;
    __syncthreads();
    const float mean = (part[0] + part[1]) / 128.f;
    __syncthreads();
    const float d = r - mean;
    float v = d * d;
#pragma unroll
    for (int o = 32; o > 0; o >>= 1) v += __shfl_xor(v, o);
    if (lane == 0) part[wv] = v;
    __syncthreads();
    const float var = (part[0] + part[1]) / 128.f;
    const float rn = d / sqrtf(var + 1e-5f) * lng[j] + lnb[j];
    rbuf[j] = fmaxf(rn, 0.f);
    __syncthreads();

    if (j < 4) {
        float acc = rb2[j];
        for (int t = 0; t < RH_DIM; ++t) acc = fmaf(rbuf[t], rW2[t * 4 + j], acc);
        const float sn = size_norm[g];
        const float dd = sn - centers[j];
        lbuf[j] = 0.7f * acc + 0.3f * (-(dd * dd));
    }
    __syncthreads();
    if (j == 0) {
        float p[4];
        const float mx = fmaxf(fmaxf(lbuf[0], lbuf[1]), fmaxf(lbuf[2], lbuf[3]));
#pragma unroll
        for (int c = 0; c < 4; ++c) p[c] = expf(lbuf[c] - mx);
        const float ssum = p[0] + p[1] + p[2] + p[3];
#pragma unroll
        for (int c = 0; c < 4; ++c) p[c] /= ssum;
        int i1 = 0;
#pragma unroll
        for (int c = 1; c < 4; ++c) if (p[c] > p[i1]) i1 = c;
        int i2 = -1;
#pragma unroll
        for (int c = 0; c < 4; ++c) {
            if (c == i1) continue;
            if (i2 < 0 || p[c] > p[i2]) i2 = c;
        }
        const float vs = p[i1] + p[i2] + 1e-8f;
        float wout[4] = {0.f, 0.f, 0.f, 0.f};
        wout[i1] = p[i1] / vs;
        wout[i2] = p[i2] / vs;
#pragma unroll
        for (int c = 0; c < 4; ++c) weights[(size_t)i * 4 + c] = wout[c];
    }
}

extern "C" void kernel_launch(void* const* d_in, const int* in_sizes, int n_in,
                              void* d_out, int out_size, void* d_ws, size_t ws_size,
                              hipStream_t stream)
{
    const float* x       = (const float*)d_in[0];
    const int*   ei      = (const int*)d_in[1];
    const int*   batch   = (const int*)d_in[2];
    const float* enc_W1  = (const float*)d_in[4];
    const float* enc_b1  = (const float*)d_in[5];
    const float* enc_W2  = (const float*)d_in[6];
    const float* enc_b2  = (const float*)d_in[7];
    const float* r_W1    = (const float*)d_in[8];
    const float* r_b1    = (const float*)d_in[9];
    const float* ln_g    = (const float*)d_in[10];
    const float* ln_b    = (const float*)d_in[11];
    const float* r_W2    = (const float*)d_in[12];
    const float* r_b2    = (const float*)d_in[13];
    const float* centers = (const float*)d_in[14];
    const float* W_rel   = (const float*)d_in[15];
    const float* b_rel   = (const float*)d_in[16];
    const float* W_root  = (const float*)d_in[17];
    const int* src = ei;
    const int* dst = ei + N_EDGES;
    float* out = (float*)d_out;

    // ---- workspace layout (~280 MB) ----
    char* wsp = (char*)d_ws;
    size_t off = 0;
    auto alloc = [&](size_t bytes) -> char* {
        char* p = wsp + off;
        off = (off + bytes + 255) & ~(size_t)255;
        return p;
    };
    const size_t PF = (size_t)P_ROWS * H_DIM;
    // B_t1: t1hi|t1lo -> later wz[0]|wz[1] (pair0 L2 output)
    char* B_t1 = alloc(PF * 4);
    ushort* t1hi = (ushort*)B_t1;
    ushort* t1lo = (ushort*)(B_t1 + PF * 2);
    ushort* wz01 = (ushort*)B_t1;
    // B_h: h_hi|h_lo -> later wz[2]|wz[3] (pair1 L2 output, after pair1 L0 consumed h_hi)
    char* B_h = alloc(PF * 4);
    ushort* h_hi = (ushort*)B_h;
    ushort* h_lo = (ushort*)(B_h + PF * 2);
    ushort* wz23 = (ushort*)B_h;
    // B_zA: zA pair (e-major); rtmp (fp32, 10.3MB) aliases start (dead before pair0 L0)
    char* B_zA = alloc(PF * 4);
    ushort* zA2 = (ushort*)B_zA;
    float*  rtmp = (float*)B_zA;
    char* B_zB = alloc(PF * 4);
    ushort* zB2 = (ushort*)B_zB;
    char* B_ag = alloc(PF * 4);
    ushort* agg2 = (ushort*)B_ag;
    ushort* aggH16 = (ushort*)alloc(PF * 2);
    ushort* Wt_rel16  = (ushort*)alloc((size_t)12 * WSZ * 2);
    ushort* Wt_root16 = (ushort*)alloc((size_t)12 * WSZ * 2);
    ushort* W2t_hi = (ushort*)alloc((size_t)WSZ * 2);
    ushort* W2t_lo = (ushort*)alloc((size_t)WSZ * 2);
    ushort* rW1t_hi = (ushort*)alloc((size_t)128 * 512 * 2);
    ushort* rW1t_lo = (ushort*)alloc((size_t)128 * 512 * 2);
    float*  weights = (float*)alloc((size_t)P_ROWS * 4 * 4);
    int* deg     = (int*)alloc((size_t)N_NODES * 4);
    int* gstart  = (int*)alloc((size_t)(G_GRAPHS + 1) * 4);
    int* part    = (int*)alloc((size_t)EH_BLOCKS * G_GRAPHS * 4);
    int* row_ptr = (int*)alloc((size_t)(N_NODES + 1) * 4);
    int* cursor  = (int*)alloc((size_t)N_NODES * 4);
    int* csr_col = (int*)alloc((size_t)N_EDGES * 4);
    float* f_norm    = (float*)alloc((size_t)G_GRAPHS * 2 * 4);
    float* size_norm = (float*)alloc((size_t)G_GRAPHS * 4);
    (void)ws_size; (void)in_sizes; (void)n_in; (void)out_size;

    const int enc_nwg = 4 * (P_ROWS / 128);   // 628
    const int rtr_nwg = 1 * (P_ROWS / 128);   // 157
    const int grp_nwg = 8 * (P_ROWS / 128);   // 1256 (4 n-blocks x 2 experts)
    const dim3 tr_grid(16, 16, 12);
    const dim3 agg_grid1(N_NODES, 1), agg_grid2(N_NODES, 2);

    // 0) zero deg + one-time weight transposes/splits
    zero_ints_kernel<<<(N_NODES + 255) / 256, 256, 0, stream>>>(deg, N_NODES);
    transpose_f32_to_bf16<<<tr_grid, 256, 0, stream>>>(W_rel, Wt_rel16);
    transpose_f32_to_bf16<<<tr_grid, 256, 0, stream>>>(W_root, Wt_root16);
    transpose_split_kernel<<<dim3(16, 16), 256, 0, stream>>>(enc_W2, W2t_hi, W2t_lo, 512);
    transpose_split_kernel<<<dim3(4, 16), 256, 0, stream>>>(r_W1, rW1t_hi, rW1t_lo, 128);
    // 1) graph stats (contention-free)
    graph_bounds_kernel<<<1, 128, 0, stream>>>(batch, gstart);
    edge_hist_kernel<<<EH_BLOCKS, 256, 0, stream>>>(src, dst, batch, part, deg);
    stats_finalize_kernel<<<1, 64, 0, stream>>>(gstart, part, f_norm, size_norm);
    // 2) encoder: t1 (split) then h = t1@W2 via bf16x3 -> h_hi/h_lo
    encoder1_kernel<<<(P_ROWS * H_DIM + 255) / 256, 256, 0, stream>>>(x, enc_W1, enc_b1, t1hi, t1lo);
    gemm_mfma<3, 4, 4><<<enc_nwg, 256, 0, stream>>>(
        t1hi, W2t_hi, t1hi, W2t_lo, t1lo, W2t_hi, enc_b2, h_hi, h_lo, 512);
    // 3) router: rtmp = h@rW1 via bf16x3 (t1 region dead now)
    gemm_mfma<3, 5, 1><<<rtr_nwg, 256, 0, stream>>>(
        h_hi, rW1t_hi, h_hi, rW1t_lo, h_lo, rW1t_hi, nullptr, rtmp, nullptr, 128);
    router_kernel<<<N_NODES, 128, 0, stream>>>(rtmp, batch, r_W1, r_b1, ln_g, ln_b,
                                               r_W2, r_b2, centers, f_norm, size_norm, weights);
    // 4) CSR build (deterministic: sorted adjacency)
    scan_kernel<<<1, 1024, 0, stream>>>(deg, row_ptr, cursor, N_NODES);
    scatter_kernel<<<(N_EDGES + 255) / 256, 256, 0, stream>>>(src, dst, cursor, csr_col);
    sort_adj_kernel<<<(N_NODES + 255) / 256, 256, 0, stream>>>(row_ptr, csr_col);
    // 5) shared layer-0 aggregation (identical for all experts)
    aggregate_bf16<<<agg_grid1, 256, 0, stream>>>((const uint*)h_hi, row_ptr, csr_col, (uint*)aggH16);

    // 6) experts, pair-grouped (2 experts per launch, grid 1256 ~= LDS occupancy cap)
    const size_t WES = (size_t)3 * WSZ;   // expert stride in Wt buffers
    const size_t BES = (size_t)3 * 512;   // expert stride in b_rel
    for (int p = 0; p < 2; ++p) {
        const size_t eb = (size_t)(p * 2);
        const ushort* WrP = Wt_rel16  + eb * WES;
        const ushort* WoP = Wt_root16 + eb * WES;
        const float*  brP = b_rel + eb * BES;
        ushort* wzP = (p == 0) ? wz01 : wz23;

        // L0: zA_e = relu(aggH@Wr0_e + h@Wo0_e + br0_e)   (shared A operands)
        gemm_grp<true, 0><<<grp_nwg, 256, 0, stream>>>(
            aggH16, 0, WrP, WES, h_hi, 0, WoP, WES, brP, BES, nullptr, zA2, PF);
        aggregate_bf16<<<agg_grid2, 256, 0, stream>>>((const uint*)zA2, row_ptr, csr_col, (uint*)agg2);
        // L1
        gemm_grp<true, 0><<<grp_nwg, 256, 0, stream>>>(
            agg2, PF, WrP + WSZ, WES, zA2, PF, WoP + WSZ, WES, brP + 512, BES, nullptr, zB2, PF);
        aggregate_bf16<<<agg_grid2, 256, 0, stream>>>((const uint*)zB2, row_ptr, csr_col, (uint*)agg2);
        // L2: wz_e = bf16(w[:,e] * (agg@Wr2_e + zB@Wo2_e + br2_e))
        gemm_grp<false, 6><<<grp_nwg, 256, 0, stream>>>(
            agg2, PF, WrP + 2 * WSZ, WES, zB2, PF, WoP + 2 * WSZ, WES, brP + 1024, BES,
            weights + eb, wzP, PF);
    }
    // 7) out = sum_e wz[e]
    reduce_wz_kernel<<<N_NODES, 256, 0, stream>>>((const uint*)wz01, (const uint*)wz23,
                                                  (float2*)out);
}

// Round 8
// 859.923 us; speedup vs baseline: 5.2654x; 1.0036x over previous
//
#include <hip/hip_runtime.h>
#include <math.h>

// ---------------- problem constants (match reference) ----------------
#define N_NODES 20000
#define N_EDGES 160000
#define G_GRAPHS 64
#define H_DIM 512
#define RH_DIM 128
#define NE_EXP 4
#define P_ROWS 20096   // 157 * 128, padded row count for GEMM tiles
#define EH_BLOCKS 64   // edge-histogram partial blocks
#define WSZ (512 * 512)

// ================= bf16 helpers =================
typedef __attribute__((ext_vector_type(8))) short bf16x8;
typedef __attribute__((ext_vector_type(4))) float f32x4;

__device__ __forceinline__ ushort f2bf(float f) {
    uint u = __float_as_uint(f);
    return (ushort)((u + 0x7FFFu + ((u >> 16) & 1u)) >> 16);  // round-to-nearest-even
}
__device__ __forceinline__ float bf2f(ushort h) {
    return __uint_as_float(((uint)h) << 16);
}

__device__ __forceinline__ void async_copy16(const void* g, void* l) {
    __builtin_amdgcn_global_load_lds(
        (__attribute__((address_space(1))) void*)g,
        (__attribute__((address_space(3))) void*)l, 16, 0, 0);
}

// ---- T1 bijective XCD swizzle (m204) ----
__device__ __forceinline__ int xcd_swizzle(int orig, int nwg) {
    const int q = nwg >> 3, r = nwg & 7;
    const int xcd = orig & 7, sid = orig >> 3;
    return (xcd < r ? xcd * (q + 1) : r * (q + 1) + (xcd - r) * q) + sid;
}

// ================= grouped expert GEMM (NE2 experts per launch) =============
// Per block: one (m, n, e) tile of C_e = A1_e@W1_e^T + A2_e@W2_e^T + bias_e.
// PROVEN 2-phase pipeline (R4-R6): double buffer, vmcnt(4), 32KB LDS.
// EPI 0: out bf16(relu?(v+bias))
// EPI 6: out bf16((v+bias) * wcol[r*4+e])
template<bool RELU, int EPI, int NE2>
__global__ __launch_bounds__(256)
void gemm_grp(const ushort* __restrict__ A1, size_t a1es,
              const ushort* __restrict__ W1, size_t w1es,
              const ushort* __restrict__ A2, size_t a2es,
              const ushort* __restrict__ W2, size_t w2es,
              const float* __restrict__ bias, size_t bes,
              const float* __restrict__ wcol,
              ushort* __restrict__ out0, size_t oes)
{
    __shared__ char smem[32768];   // 2 bufs x (A 8KB | B 8KB)
    const int tid = threadIdx.x;
    const int w = tid >> 6, lane = tid & 63;

    const int wgid = xcd_swizzle(blockIdx.x, gridDim.x);
    const int m0 = (wgid / (4 * NE2)) * 128;
    const int rem = wgid % (4 * NE2);
    const int e  = rem % NE2;
    const int n0 = (rem / NE2) * 128;

    const ushort* __restrict__ A1e = A1 + (size_t)e * a1es;
    const ushort* __restrict__ W1e = W1 + (size_t)e * w1es;
    const ushort* __restrict__ A2e = A2 + (size_t)e * a2es;
    const ushort* __restrict__ W2e = W2 + (size_t)e * w2es;
    const float*  __restrict__ be  = bias + (size_t)e * bes;
    ushort* __restrict__ oe = out0 + (size_t)e * oes;

    f32x4 acc[4][4];
#pragma unroll
    for (int i = 0; i < 4; ++i)
#pragma unroll
        for (int j = 0; j < 4; ++j) acc[i][j] = (f32x4){0.f, 0.f, 0.f, 0.f};

    const int srow = lane >> 2, schk = lane & 3;
    const int wr = w >> 1, wc = w & 1;
    const int row16 = lane & 15;
    const uint koffB = (uint)(lane >> 4) * 16u;
    const uint aoff0 = (uint)(wr * 64 + row16) * 64u + koffB;
    const uint boff0 = 8192u + (uint)(wc * 64 + row16) * 64u + koffB;

    auto stage = [&](int buf, int t) {
        const ushort* __restrict__ A  = (t < 16) ? A1e : A2e;
        const ushort* __restrict__ Wt = (t < 16) ? W1e : W2e;
        const int kt = (t & 15) * 32;
        char* base = smem + buf * 16384;
#pragma unroll
        for (int c = 0; c < 2; ++c) {
            const int rb = c * 64 + w * 16;   // wave-uniform LDS row base
            async_copy16(A  + (size_t)(m0 + rb + srow) * 512 + kt + schk * 8, base + rb * 64);
            async_copy16(Wt + (size_t)(n0 + rb + srow) * 512 + kt + schk * 8, base + 8192 + rb * 64);
        }
    };
    auto compute = [&](int buf) {
        const char* base = smem + buf * 16384;
        bf16x8 af[4], bfr[4];
#pragma unroll
        for (int i = 0; i < 4; ++i) af[i] = *(const bf16x8*)(base + aoff0 + i * 1024);
#pragma unroll
        for (int j = 0; j < 4; ++j) bfr[j] = *(const bf16x8*)(base + boff0 + j * 1024);
#pragma unroll
        for (int i = 0; i < 4; ++i)
#pragma unroll
            for (int j = 0; j < 4; ++j)
                acc[i][j] = __builtin_amdgcn_mfma_f32_16x16x32_bf16(af[i], bfr[j], acc[i][j], 0, 0, 0);
    };

    // 2-phase pipeline (T3 minimum + T4 counted vmcnt) — proven R4-R6
    stage(0, 0);
    for (int t = 0; t < 31; ++t) {
        stage((t + 1) & 1, t + 1);
        asm volatile("s_waitcnt vmcnt(4)" ::: "memory");
        __builtin_amdgcn_s_barrier();
        compute(t & 1);
        __builtin_amdgcn_s_barrier();
    }
    asm volatile("s_waitcnt vmcnt(0)" ::: "memory");
    __builtin_amdgcn_s_barrier();
    compute(1);

    // epilogue: C/D layout col = lane&15, row = (lane>>4)*4 + q
#pragma unroll
    for (int i = 0; i < 4; ++i) {
        const int r0 = m0 + wr * 64 + i * 16 + (lane >> 4) * 4;
#pragma unroll
        for (int j = 0; j < 4; ++j) {
            const int c = n0 + wc * 64 + j * 16 + row16;
            const float bj = be[c];
#pragma unroll
            for (int q2 = 0; q2 < 4; ++q2) {
                const int r = r0 + q2;
                float v = acc[i][j][q2] + bj;
                if (EPI == 0) {
                    if (RELU) v = fmaxf(v, 0.f);
                    oe[(size_t)r * 512 + c] = f2bf(v);
                } else {  // EPI 6
                    const float wrow = (r < N_NODES) ? wcol[(size_t)r * 4 + e] : 0.f;
                    oe[(size_t)r * 512 + c] = f2bf(v * wrow);
                }
            }
        }
    }
}

// ================= encoder/router bf16x3 GEMM (2-phase, proven) =============
// EPI 4: hi/lo bf16 split -> out0/out1 ; EPI 5: out0 fp32
template<int NPASS, int EPI, int NBN>
__global__ __launch_bounds__(256)
void gemm_mfma(const ushort* __restrict__ A0, const ushort* __restrict__ W0,
               const ushort* __restrict__ A1p, const ushort* __restrict__ W1p,
               const ushort* __restrict__ A2p, const ushort* __restrict__ W2p,
               const float* __restrict__ bias,
               void* __restrict__ out0, void* __restrict__ out1, int Ncols)
{
    __shared__ char smem[32768];
    const int tid = threadIdx.x;
    const int w = tid >> 6, lane = tid & 63;

    const int wgid = xcd_swizzle(blockIdx.x, gridDim.x);
    const int m0 = (wgid / NBN) * 128;
    const int n0 = (wgid % NBN) * 128;

    f32x4 acc[4][4];
#pragma unroll
    for (int i = 0; i < 4; ++i)
#pragma unroll
        for (int j = 0; j < 4; ++j) acc[i][j] = (f32x4){0.f, 0.f, 0.f, 0.f};

    const int srow = lane >> 2, schk = lane & 3;
    const int wr = w >> 1, wc = w & 1;
    const int row16 = lane & 15;
    const uint koffB = (uint)(lane >> 4) * 16u;
    const uint aoff0 = (uint)(wr * 64 + row16) * 64u + koffB;
    const uint boff0 = 8192u + (uint)(wc * 64 + row16) * 64u + koffB;

    const int NT = NPASS * 16;
    auto Asel = [&](int t) -> const ushort* { return (t < 16) ? A0 : ((t < 32) ? A1p : A2p); };
    auto Wsel = [&](int t) -> const ushort* { return (t < 16) ? W0 : ((t < 32) ? W1p : W2p); };

    auto stage = [&](int buf, int t) {
        const ushort* __restrict__ A  = Asel(t);
        const ushort* __restrict__ Wt = Wsel(t);
        const int kt = (t & 15) * 32;
        char* base = smem + buf * 16384;
#pragma unroll
        for (int c = 0; c < 2; ++c) {
            const int rb = c * 64 + w * 16;
            async_copy16(A  + (size_t)(m0 + rb + srow) * 512 + kt + schk * 8, base + rb * 64);
            async_copy16(Wt + (size_t)(n0 + rb + srow) * 512 + kt + schk * 8, base + 8192 + rb * 64);
        }
    };
    auto compute = [&](int buf) {
        const char* base = smem + buf * 16384;
        bf16x8 af[4], bfr[4];
#pragma unroll
        for (int i = 0; i < 4; ++i) af[i] = *(const bf16x8*)(base + aoff0 + i * 1024);
#pragma unroll
        for (int j = 0; j < 4; ++j) bfr[j] = *(const bf16x8*)(base + boff0 + j * 1024);
#pragma unroll
        for (int i = 0; i < 4; ++i)
#pragma unroll
            for (int j = 0; j < 4; ++j)
                acc[i][j] = __builtin_amdgcn_mfma_f32_16x16x32_bf16(af[i], bfr[j], acc[i][j], 0, 0, 0);
    };

    stage(0, 0);
    for (int t = 0; t < NT - 1; ++t) {
        stage((t + 1) & 1, t + 1);
        asm volatile("s_waitcnt vmcnt(4)" ::: "memory");
        __builtin_amdgcn_s_barrier();
        compute(t & 1);
        __builtin_amdgcn_s_barrier();
    }
    asm volatile("s_waitcnt vmcnt(0)" ::: "memory");
    __builtin_amdgcn_s_barrier();
    compute((NT - 1) & 1);

#pragma unroll
    for (int i = 0; i < 4; ++i) {
        const int r0 = m0 + wr * 64 + i * 16 + (lane >> 4) * 4;
#pragma unroll
        for (int j = 0; j < 4; ++j) {
            const int c = n0 + wc * 64 + j * 16 + row16;
            const float bj = (EPI == 5) ? 0.f : bias[c];
#pragma unroll
            for (int q2 = 0; q2 < 4; ++q2) {
                const int r = r0 + q2;
                float v = acc[i][j][q2] + bj;
                if (EPI == 4) {
                    const ushort hi = f2bf(v);
                    const ushort lo = f2bf(v - bf2f(hi));
                    ((ushort*)out0)[(size_t)r * Ncols + c] = hi;
                    ((ushort*)out1)[(size_t)r * Ncols + c] = lo;
                } else {
                    ((float*)out0)[(size_t)r * Ncols + c] = v;
                }
            }
        }
    }
}

// out[r,c] = sum_e bf2f(wz[e][r,c])  (wz 4 experts contiguous, 2 cols/thread)
__global__ __launch_bounds__(256)
void reduce_wz_kernel(const uint* __restrict__ wz4, float2* __restrict__ out)
{
    const size_t idx = (size_t)blockIdx.x * 256 + threadIdx.x;  // < N_NODES*256
    const size_t es = (size_t)P_ROWS * 256;  // uints per expert
    const uint a = wz4[idx], b = wz4[idx + es];
    const uint c = wz4[idx + 2 * es], d = wz4[idx + 3 * es];
    float lo = bf2f((ushort)(a & 0xffffu)) + bf2f((ushort)(b & 0xffffu))
             + bf2f((ushort)(c & 0xffffu)) + bf2f((ushort)(d & 0xffffu));
    float hi = bf2f((ushort)(a >> 16)) + bf2f((ushort)(b >> 16))
             + bf2f((ushort)(c >> 16)) + bf2f((ushort)(d >> 16));
    out[idx] = make_float2(lo, hi);
}

// t1 = relu(x[:,4:10] @ enc_W1 + enc_b1), split into bf16 hi+lo; zero pad rows
__global__ void encoder1_kernel(const float* __restrict__ x, const float* __restrict__ W1,
                                const float* __restrict__ b1,
                                ushort* __restrict__ t1hi, ushort* __restrict__ t1lo)
{
    const int idx = blockIdx.x * blockDim.x + threadIdx.x;
    if (idx >= P_ROWS * H_DIM) return;
    const int i = idx / H_DIM, j = idx - i * H_DIM;
    float v = 0.f;
    if (i < N_NODES) {
        const float* xr = &x[i * 16 + 4];
        v = b1[j];
#pragma unroll
        for (int k = 0; k < 6; ++k) v = fmaf(xr[k], W1[k * H_DIM + j], v);
        v = fmaxf(v, 0.f);
    }
    const ushort hi = f2bf(v);
    t1hi[idx] = hi;
    t1lo[idx] = f2bf(v - bf2f(hi));
}

__global__ void zero_ints_kernel(int* __restrict__ p, int n)
{
    const int idx = blockIdx.x * blockDim.x + threadIdx.x;
    if (idx < n) p[idx] = 0;
}

__global__ void graph_bounds_kernel(const int* __restrict__ batch, int* __restrict__ gstart)
{
    const int g = threadIdx.x;
    if (g > G_GRAPHS) return;
    int lo = 0, hi = N_NODES;
    while (lo < hi) {
        const int mid = (lo + hi) >> 1;
        if (batch[mid] < g) lo = mid + 1; else hi = mid;
    }
    gstart[g] = lo;
}

__global__ __launch_bounds__(256)
void edge_hist_kernel(const int* __restrict__ src, const int* __restrict__ dst,
                      const int* __restrict__ batch,
                      int* __restrict__ part, int* __restrict__ deg)
{
    __shared__ int hist[G_GRAPHS];
    const int tid = threadIdx.x;
    if (tid < G_GRAPHS) hist[tid] = 0;
    __syncthreads();
    for (int e = blockIdx.x * 256 + tid; e < N_EDGES; e += EH_BLOCKS * 256) {
        atomicAdd(&deg[dst[e]], 1);
        atomicAdd(&hist[batch[src[e]]], 1);
    }
    __syncthreads();
    if (tid < G_GRAPHS) part[blockIdx.x * G_GRAPHS + tid] = hist[tid];
}

__global__ void stats_finalize_kernel(const int* __restrict__ gstart, const int* __restrict__ part,
                                      float* __restrict__ f_norm, float* __restrict__ size_norm)
{
    const int g = threadIdx.x;  // exactly 64
    const float nn = fmaxf((float)(gstart[g + 1] - gstart[g]), 1.0f);
    int ec = 0;
#pragma unroll 8
    for (int b = 0; b < EH_BLOCKS; ++b) ec += part[b * G_GRAPHS + g];
    const float ee = (float)ec;
    const float ln = logf(nn);
    const float le = log1pf(ee);
    float s0 = ln, s1 = le;
#pragma unroll
    for (int o = 32; o > 0; o >>= 1) { s0 += __shfl_xor(s0, o); s1 += __shfl_xor(s1, o); }
    const float m0 = s0 / 64.f, m1 = s1 / 64.f;
    const float d0 = ln - m0, d1 = le - m1;
    float v0 = d0 * d0, v1 = d1 * d1;
#pragma unroll
    for (int o = 32; o > 0; o >>= 1) { v0 += __shfl_xor(v0, o); v1 += __shfl_xor(v1, o); }
    const float sd0 = sqrtf(v0 / 64.f), sd1 = sqrtf(v1 / 64.f);
    float mn = ln, mx = ln;
#pragma unroll
    for (int o = 32; o > 0; o >>= 1) {
        mn = fminf(mn, __shfl_xor(mn, o));
        mx = fmaxf(mx, __shfl_xor(mx, o));
    }
    f_norm[g * 2 + 0] = d0 / (sd0 + 1e-6f);
    f_norm[g * 2 + 1] = d1 / (sd1 + 1e-6f);
    size_norm[g] = (ln - mn) / (mx - mn + 1e-6f);
}

__global__ void scan_kernel(const int* __restrict__ in, int* __restrict__ row_ptr,
                            int* __restrict__ cursor, int n)
{
    __shared__ int wsum[16];
    __shared__ int carry_s;
    const int tid = threadIdx.x;
    const int lane = tid & 63, wv = tid >> 6;
    if (tid == 0) carry_s = 0;
    __syncthreads();
    for (int base = 0; base < n; base += 1024) {
        const int idx = base + tid;
        const int v = (idx < n) ? in[idx] : 0;
        int x = v;
#pragma unroll
        for (int o = 1; o < 64; o <<= 1) { const int t = __shfl_up(x, o); if (lane >= o) x += t; }
        if (lane == 63) wsum[wv] = x;
        __syncthreads();
        const int carry = carry_s;
        if (wv == 0) {
            int y = (lane < 16) ? wsum[lane] : 0;
#pragma unroll
            for (int o = 1; o < 16; o <<= 1) { const int t = __shfl_up(y, o); if (lane >= o) y += t; }
            if (lane < 16) wsum[lane] = y;
        }
        __syncthreads();
        const int woff = (wv > 0) ? wsum[wv - 1] : 0;
        const int excl = x - v + woff + carry;
        if (idx < n) { row_ptr[idx] = excl; cursor[idx] = excl; }
        __syncthreads();
        if (tid == 0) carry_s = carry + wsum[15];
        __syncthreads();
    }
    if (tid == 0) row_ptr[n] = carry_s;
}

__global__ void scatter_kernel(const int* __restrict__ src, const int* __restrict__ dst,
                               int* __restrict__ cursor, int* __restrict__ csr_col)
{
    const int e = blockIdx.x * blockDim.x + threadIdx.x;
    if (e >= N_EDGES) return;
    const int d = dst[e];
    const int slot = atomicAdd(&cursor[d], 1);
    csr_col[slot] = src[e];
}

__global__ void sort_adj_kernel(const int* __restrict__ row_ptr, int* __restrict__ csr_col)
{
    const int i = blockIdx.x * blockDim.x + threadIdx.x;
    if (i >= N_NODES) return;
    const int b = row_ptr[i], e = row_ptr[i + 1];
    for (int p = b + 1; p < e; ++p) {
        const int key = csr_col[p];
        int q = p - 1;
        while (q >= b && csr_col[q] > key) { csr_col[q + 1] = csr_col[q]; --q; }
        csr_col[q + 1] = key;
    }
}

// agg[e][i,:] = sum over in-edges of z[e][src,:]  (expert = blockIdx.y)
__global__ __launch_bounds__(256)
void aggregate_bf16(const uint* __restrict__ z2, const int* __restrict__ row_ptr,
                    const int* __restrict__ csr_col, uint* __restrict__ agg2)
{
    const size_t es = (size_t)blockIdx.y * P_ROWS * 256;
    const uint* __restrict__ zz = z2 + es;
    uint* __restrict__ aa = agg2 + es;
    const int i = blockIdx.x;
    const int t = threadIdx.x;
    const int b = row_ptr[i], e = row_ptr[i + 1];
    float ax = 0.f, ay = 0.f;
    int p = b;
    for (; p + 4 <= e; p += 4) {
        const int s0 = csr_col[p + 0], s1 = csr_col[p + 1];
        const int s2 = csr_col[p + 2], s3 = csr_col[p + 3];
        const uint v0 = zz[(size_t)s0 * 256 + t];
        const uint v1 = zz[(size_t)s1 * 256 + t];
        const uint v2 = zz[(size_t)s2 * 256 + t];
        const uint v3 = zz[(size_t)s3 * 256 + t];
        ax += bf2f((ushort)(v0 & 0xffffu)) + bf2f((ushort)(v1 & 0xffffu))
            + bf2f((ushort)(v2 & 0xffffu)) + bf2f((ushort)(v3 & 0xffffu));
        ay += bf2f((ushort)(v0 >> 16)) + bf2f((ushort)(v1 >> 16))
            + bf2f((ushort)(v2 >> 16)) + bf2f((ushort)(v3 >> 16));
    }
    for (; p < e; ++p) {
        const uint v = zz[(size_t)csr_col[p] * 256 + t];
        ax += bf2f((ushort)(v & 0xffffu));
        ay += bf2f((ushort)(v >> 16));
    }
    aa[(size_t)i * 256 + t] = (uint)f2bf(ax) | ((uint)f2bf(ay) << 16);
}

// one 512x512 matrix per blockIdx.z: Wt[n][k] = bf16(W[k][n])
__global__ __launch_bounds__(256)
void transpose_f32_to_bf16(const float* __restrict__ W, ushort* __restrict__ Wt)
{
    __shared__ float tile[32][33];
    const float* Wm = W + (size_t)blockIdx.z * WSZ;
    ushort* Wtm = Wt + (size_t)blockIdx.z * WSZ;
    const int c0 = blockIdx.x * 32, r0 = blockIdx.y * 32;
    const int tc = threadIdx.x & 31, tr = threadIdx.x >> 5;
#pragma unroll
    for (int it = 0; it < 4; ++it)
        tile[tr + it * 8][tc] = Wm[(size_t)(r0 + tr + it * 8) * 512 + c0 + tc];
    __syncthreads();
#pragma unroll
    for (int it = 0; it < 4; ++it) {
        const int cr = tr + it * 8;
        Wtm[(size_t)(c0 + cr) * 512 + r0 + tc] = f2bf(tile[tc][cr]);
    }
}

// W [512][Nin] fp32 -> Wt hi/lo [Nin][512] bf16 (k-stride 512)
__global__ __launch_bounds__(256)
void transpose_split_kernel(const float* __restrict__ W, ushort* __restrict__ Whi,
                            ushort* __restrict__ Wlo, int Nin)
{
    __shared__ float tile[32][33];
    const int c0 = blockIdx.x * 32;
    const int r0 = blockIdx.y * 32;
    const int tc = threadIdx.x & 31, tr = threadIdx.x >> 5;
#pragma unroll
    for (int it = 0; it < 4; ++it)
        tile[tr + it * 8][tc] = W[(size_t)(r0 + tr + it * 8) * Nin + c0 + tc];
    __syncthreads();
#pragma unroll
    for (int it = 0; it < 4; ++it) {
        const int cr = tr + it * 8;
        const float v = tile[tc][cr];
        const ushort hi = f2bf(v);
        Whi[(size_t)(c0 + cr) * 512 + r0 + tc] = hi;
        Wlo[(size_t)(c0 + cr) * 512 + r0 + tc] = f2bf(v - bf2f(hi));
    }
}

// router tail (fp32)
__global__ __launch_bounds__(128)
void router_kernel(const float* __restrict__ rtmp, const int* __restrict__ batch,
                   const float* __restrict__ rW1, const float* __restrict__ rb1,
                   const float* __restrict__ lng, const float* __restrict__ lnb,
                   const float* __restrict__ rW2, const float* __restrict__ rb2,
                   const float* __restrict__ centers,
                   const float* __restrict__ f_norm, const float* __restrict__ size_norm,
                   float* __restrict__ weights)
{
    const int i = blockIdx.x;
    const int j = threadIdx.x;
    const int g = batch[i];
    const float f0 = f_norm[g * 2], f1 = f_norm[g * 2 + 1];
    float r = rtmp[(size_t)i * RH_DIM + j]
            + f0 * rW1[512 * RH_DIM + j] + f1 * rW1[513 * RH_DIM + j] + rb1[j];

    __shared__ float part[2];
    __shared__ float rbuf[RH_DIM];
    __shared__ float lbuf[4];
    const int lane = j & 63, wv = j >> 6;

    float s = r;
#pragma unroll
    for (int o = 32; o > 0; o >>= 1) s += __shfl_xor(s, o);
    if (lane == 0) part[wv] = s;
    __syncthreads();
    const float mean = (part[0] + part[1]) / 128.f;
    __syncthreads();
    const float d = r - mean;
    float v = d * d;
#pragma unroll
    for (int o = 32; o > 0; o >>= 1) v += __shfl_xor(v, o);
    if (lane == 0) part[wv] = v;
    __syncthreads();
    const float var = (part[0] + part[1]) / 128.f;
    const float rn = d / sqrtf(var + 1e-5f) * lng[j] + lnb[j];
    rbuf[j] = fmaxf(rn, 0.f);
    __syncthreads();

    if (j < 4) {
        float acc = rb2[j];
        for (int t = 0; t < RH_DIM; ++t) acc = fmaf(rbuf[t], rW2[t * 4 + j], acc);
        const float sn = size_norm[g];
        const float dd = sn - centers[j];
        lbuf[j] = 0.7f * acc + 0.3f * (-(dd * dd));
    }
    __syncthreads();
    if (j == 0) {
        float p[4];
        const float mx = fmaxf(fmaxf(lbuf[0], lbuf[1]), fmaxf(lbuf[2], lbuf[3]));
#pragma unroll
        for (int c = 0; c < 4; ++c) p[c] = expf(lbuf[c] - mx);
        const float ssum = p[0] + p[1] + p[2] + p[3];
#pragma unroll
        for (int c = 0; c < 4; ++c) p[c] /= ssum;
        int i1 = 0;
#pragma unroll
        for (int c = 1; c < 4; ++c) if (p[c] > p[i1]) i1 = c;
        int i2 = -1;
#pragma unroll
        for (int c = 0; c < 4; ++c) {
            if (c == i1) continue;
            if (i2 < 0 || p[c] > p[i2]) i2 = c;
        }
        const float vs = p[i1] + p[i2] + 1e-8f;
        float wout[4] = {0.f, 0.f, 0.f, 0.f};
        wout[i1] = p[i1] / vs;
        wout[i2] = p[i2] / vs;
#pragma unroll
        for (int c = 0; c < 4; ++c) weights[(size_t)i * 4 + c] = wout[c];
    }
}

extern "C" void kernel_launch(void* const* d_in, const int* in_sizes, int n_in,
                              void* d_out, int out_size, void* d_ws, size_t ws_size,
                              hipStream_t stream)
{
    const float* x       = (const float*)d_in[0];
    const int*   ei      = (const int*)d_in[1];
    const int*   batch   = (const int*)d_in[2];
    const float* enc_W1  = (const float*)d_in[4];
    const float* enc_b1  = (const float*)d_in[5];
    const float* enc_W2  = (const float*)d_in[6];
    const float* enc_b2  = (const float*)d_in[7];
    const float* r_W1    = (const float*)d_in[8];
    const float* r_b1    = (const float*)d_in[9];
    const float* ln_g    = (const float*)d_in[10];
    const float* ln_b    = (const float*)d_in[11];
    const float* r_W2    = (const float*)d_in[12];
    const float* r_b2    = (const float*)d_in[13];
    const float* centers = (const float*)d_in[14];
    const float* W_rel   = (const float*)d_in[15];
    const float* b_rel   = (const float*)d_in[16];
    const float* W_root  = (const float*)d_in[17];
    const int* src = ei;
    const int* dst = ei + N_EDGES;
    float* out = (float*)d_out;

    const size_t PF = (size_t)P_ROWS * H_DIM;
    // choose 4-expert-merged path if workspace allows (deterministic: ws_size fixed)
    const size_t need4 = PF * 34 + (size_t)40 * 1024 * 1024;
    const bool path4 = (ws_size >= need4);
    const int NEPD = path4 ? 4 : 2;           // experts per dispatch
    const size_t ZBYTES = PF * 2 * NEPD;      // z/agg buffer bytes per stage

    char* wsp = (char*)d_ws;
    size_t off = 0;
    auto alloc = [&](size_t bytes) -> char* {
        char* p = wsp + off;
        off = (off + bytes + 255) & ~(size_t)255;
        return p;
    };
    // region1+region2 contiguous: t1hi|t1lo , h_hi|h_lo -> later wz4 (4 x PF bf16)
    char* region1 = alloc(PF * 4);
    ushort* t1hi = (ushort*)region1;
    ushort* t1lo = (ushort*)(region1 + PF * 2);
    ushort* wz4  = (ushort*)region1;           // spans region1+region2
    char* region2 = alloc(PF * 4);
    ushort* h_hi = (ushort*)region2;
    ushort* h_lo = (ushort*)(region2 + PF * 2);
    // z/agg buffers (NEPD-wide); rtmp fp32 aliases zA start (dead before expert L0)
    char* B_zA = alloc(ZBYTES);
    ushort* zAe = (ushort*)B_zA;
    float*  rtmp = (float*)B_zA;
    char* B_zB = alloc(ZBYTES);
    ushort* zBe = (ushort*)B_zB;
    char* B_ag = alloc(ZBYTES);
    ushort* agge = (ushort*)B_ag;
    ushort* aggH16 = (ushort*)alloc(PF * 2);
    ushort* Wt_rel16  = (ushort*)alloc((size_t)12 * WSZ * 2);
    ushort* Wt_root16 = (ushort*)alloc((size_t)12 * WSZ * 2);
    ushort* W2t_hi = (ushort*)alloc((size_t)WSZ * 2);
    ushort* W2t_lo = (ushort*)alloc((size_t)WSZ * 2);
    ushort* rW1t_hi = (ushort*)alloc((size_t)128 * 512 * 2);
    ushort* rW1t_lo = (ushort*)alloc((size_t)128 * 512 * 2);
    float*  weights = (float*)alloc((size_t)P_ROWS * 4 * 4);
    int* deg     = (int*)alloc((size_t)N_NODES * 4);
    int* gstart  = (int*)alloc((size_t)(G_GRAPHS + 1) * 4);
    int* part    = (int*)alloc((size_t)EH_BLOCKS * G_GRAPHS * 4);
    int* row_ptr = (int*)alloc((size_t)(N_NODES + 1) * 4);
    int* cursor  = (int*)alloc((size_t)N_NODES * 4);
    int* csr_col = (int*)alloc((size_t)N_EDGES * 4);
    float* f_norm    = (float*)alloc((size_t)G_GRAPHS * 2 * 4);
    float* size_norm = (float*)alloc((size_t)G_GRAPHS * 4);
    (void)in_sizes; (void)n_in; (void)out_size;

    const int enc_nwg = 4 * (P_ROWS / 128);               // 628
    const int rtr_nwg = 1 * (P_ROWS / 128);               // 157
    const int grp_nwg = 4 * NEPD * (P_ROWS / 128);        // 2512 or 1256
    const dim3 tr_grid(16, 16, 12);
    const dim3 agg_grid1(N_NODES, 1), agg_gridE(N_NODES, NEPD);

    // 0) zero deg + one-time weight transposes/splits
    zero_ints_kernel<<<(N_NODES + 255) / 256, 256, 0, stream>>>(deg, N_NODES);
    transpose_f32_to_bf16<<<tr_grid, 256, 0, stream>>>(W_rel, Wt_rel16);
    transpose_f32_to_bf16<<<tr_grid, 256, 0, stream>>>(W_root, Wt_root16);
    transpose_split_kernel<<<dim3(16, 16), 256, 0, stream>>>(enc_W2, W2t_hi, W2t_lo, 512);
    transpose_split_kernel<<<dim3(4, 16), 256, 0, stream>>>(r_W1, rW1t_hi, rW1t_lo, 128);
    // 1) graph stats (contention-free)
    graph_bounds_kernel<<<1, 128, 0, stream>>>(batch, gstart);
    edge_hist_kernel<<<EH_BLOCKS, 256, 0, stream>>>(src, dst, batch, part, deg);
    stats_finalize_kernel<<<1, 64, 0, stream>>>(gstart, part, f_norm, size_norm);
    // 2) encoder: t1 (split) then h = t1@W2 via bf16x3 -> h_hi/h_lo
    encoder1_kernel<<<(P_ROWS * H_DIM + 255) / 256, 256, 0, stream>>>(x, enc_W1, enc_b1, t1hi, t1lo);
    gemm_mfma<3, 4, 4><<<enc_nwg, 256, 0, stream>>>(
        t1hi, W2t_hi, t1hi, W2t_lo, t1lo, W2t_hi, enc_b2, h_hi, h_lo, 512);
    // 3) router: rtmp = h@rW1 via bf16x3 (t1 region dead now)
    gemm_mfma<3, 5, 1><<<rtr_nwg, 256, 0, stream>>>(
        h_hi, rW1t_hi, h_hi, rW1t_lo, h_lo, rW1t_hi, nullptr, rtmp, nullptr, 128);
    router_kernel<<<N_NODES, 128, 0, stream>>>(rtmp, batch, r_W1, r_b1, ln_g, ln_b,
                                               r_W2, r_b2, centers, f_norm, size_norm, weights);
    // 4) CSR build (deterministic: sorted adjacency)
    scan_kernel<<<1, 1024, 0, stream>>>(deg, row_ptr, cursor, N_NODES);
    scatter_kernel<<<(N_EDGES + 255) / 256, 256, 0, stream>>>(src, dst, cursor, csr_col);
    sort_adj_kernel<<<(N_NODES + 255) / 256, 256, 0, stream>>>(row_ptr, csr_col);
    // 5) shared layer-0 aggregation
    aggregate_bf16<<<agg_grid1, 256, 0, stream>>>((const uint*)h_hi, row_ptr, csr_col, (uint*)aggH16);

    // 6) experts
    const size_t WES = (size_t)3 * WSZ;   // expert stride in Wt buffers
    const size_t BES = (size_t)3 * 512;   // expert stride in b_rel
    if (path4) {
        // all 4 experts per dispatch
        gemm_grp<true, 0, 4><<<grp_nwg, 256, 0, stream>>>(
            aggH16, 0, Wt_rel16, WES, h_hi, 0, Wt_root16, WES, b_rel, BES, nullptr, zAe, PF);
        aggregate_bf16<<<agg_gridE, 256, 0, stream>>>((const uint*)zAe, row_ptr, csr_col, (uint*)agge);
        gemm_grp<true, 0, 4><<<grp_nwg, 256, 0, stream>>>(
            agge, PF, Wt_rel16 + WSZ, WES, zAe, PF, Wt_root16 + WSZ, WES, b_rel + 512, BES,
            nullptr, zBe, PF);
        aggregate_bf16<<<agg_gridE, 256, 0, stream>>>((const uint*)zBe, row_ptr, csr_col, (uint*)agge);
        gemm_grp<false, 6, 4><<<grp_nwg, 256, 0, stream>>>(
            agge, PF, Wt_rel16 + 2 * WSZ, WES, zBe, PF, Wt_root16 + 2 * WSZ, WES, b_rel + 1024, BES,
            weights, wz4, PF);
    } else {
        // pair path (2 experts per dispatch)
        for (int p = 0; p < 2; ++p) {
            const size_t eb = (size_t)(p * 2);
            const ushort* WrP = Wt_rel16  + eb * WES;
            const ushort* WoP = Wt_root16 + eb * WES;
            const float*  brP = b_rel + eb * BES;
            ushort* wzP = wz4 + eb * PF;
            gemm_grp<true, 0, 2><<<grp_nwg, 256, 0, stream>>>(
                aggH16, 0, WrP, WES, h_hi, 0, WoP, WES, brP, BES, nullptr, zAe, PF);
            aggregate_bf16<<<agg_gridE, 256, 0, stream>>>((const uint*)zAe, row_ptr, csr_col, (uint*)agge);
            gemm_grp<true, 0, 2><<<grp_nwg, 256, 0, stream>>>(
                agge, PF, WrP + WSZ, WES, zAe, PF, WoP + WSZ, WES, brP + 512, BES, nullptr, zBe, PF);
            aggregate_bf16<<<agg_gridE, 256, 0, stream>>>((const uint*)zBe, row_ptr, csr_col, (uint*)agge);
            gemm_grp<false, 6, 2><<<grp_nwg, 256, 0, stream>>>(
                agge, PF, WrP + 2 * WSZ, WES, zBe, PF, WoP + 2 * WSZ, WES, brP + 1024, BES,
                weights + eb, wzP, PF);
        }
    }
    // 7) out = sum_e wz[e]
    reduce_wz_kernel<<<N_NODES, 256, 0, stream>>>((const uint*)wz4, (float2*)out);
}

// Round 9
// 848.730 us; speedup vs baseline: 5.3349x; 1.0132x over previous
//
#include <hip/hip_runtime.h>
#include <math.h>

// ---------------- problem constants (match reference) ----------------
#define N_NODES 20000
#define N_EDGES 160000
#define G_GRAPHS 64
#define H_DIM 512
#define RH_DIM 128
#define NE_EXP 4
#define P_ROWS 20096   // 157 * 128, padded row count for GEMM tiles
#define EH_BLOCKS 64   // edge-histogram partial blocks
#define WSZ (512 * 512)

// ================= bf16 helpers =================
typedef __attribute__((ext_vector_type(8))) short bf16x8;
typedef __attribute__((ext_vector_type(4))) float f32x4;

__device__ __forceinline__ ushort f2bf(float f) {
    uint u = __float_as_uint(f);
    return (ushort)((u + 0x7FFFu + ((u >> 16) & 1u)) >> 16);  // round-to-nearest-even
}
__device__ __forceinline__ float bf2f(ushort h) {
    return __uint_as_float(((uint)h) << 16);
}

__device__ __forceinline__ void async_copy16(const void* g, void* l) {
    __builtin_amdgcn_global_load_lds(
        (__attribute__((address_space(1))) void*)g,
        (__attribute__((address_space(3))) void*)l, 16, 0, 0);
}

// ---- T1 bijective XCD swizzle (m204) ----
__device__ __forceinline__ int xcd_swizzle(int orig, int nwg) {
    const int q = nwg >> 3, r = nwg & 7;
    const int xcd = orig & 7, sid = orig >> 3;
    return (xcd < r ? xcd * (q + 1) : r * (q + 1) + (xcd - r) * q) + sid;
}

// ================= grouped expert GEMM, 128x256 tile, 4x8 frags =============
// Per block: one (m, n, e) 128x256 tile of C_e = A1_e@W1_e^T + A2_e@W2_e^T + b.
// 4 waves (2x2), each 64x128 output (acc 4x8). LDS/K-tile: A 8KB + B 16KB.
// Sync skeleton = PROVEN R4-R6 2-phase: stage(t+1); vmcnt(one-stage=6);
// barrier; compute(t); barrier. No structural sync change.
// EPI 0: out bf16(relu?(v+bias)) ; EPI 6: out bf16((v+bias)*wcol[r*4+e])
template<bool RELU, int EPI, int NE2>
__global__ __launch_bounds__(256, 2)
void gemm_grp(const ushort* __restrict__ A1, size_t a1es,
              const ushort* __restrict__ W1, size_t w1es,
              const ushort* __restrict__ A2, size_t a2es,
              const ushort* __restrict__ W2, size_t w2es,
              const float* __restrict__ bias, size_t bes,
              const float* __restrict__ wcol,
              ushort* __restrict__ out0, size_t oes)
{
    __shared__ char smem[49152];   // 2 bufs x (A 8KB | B 16KB)
    const int tid = threadIdx.x;
    const int w = tid >> 6, lane = tid & 63;

    const int wgid = xcd_swizzle(blockIdx.x, gridDim.x);
    const int m0 = (wgid / (2 * NE2)) * 128;
    const int rem = wgid % (2 * NE2);
    const int e  = rem % NE2;
    const int n0 = (rem / NE2) * 256;

    const ushort* __restrict__ A1e = A1 + (size_t)e * a1es;
    const ushort* __restrict__ W1e = W1 + (size_t)e * w1es;
    const ushort* __restrict__ A2e = A2 + (size_t)e * a2es;
    const ushort* __restrict__ W2e = W2 + (size_t)e * w2es;
    const float*  __restrict__ be  = bias + (size_t)e * bes;
    ushort* __restrict__ oe = out0 + (size_t)e * oes;

    f32x4 acc[4][8];
#pragma unroll
    for (int i = 0; i < 4; ++i)
#pragma unroll
        for (int j = 0; j < 8; ++j) acc[i][j] = (f32x4){0.f, 0.f, 0.f, 0.f};

    const int srow = lane >> 2, schk = lane & 3;
    const int wr = w >> 1, wc = w & 1;          // wave grid 2x2: 64-row x 128-col
    const int row16 = lane & 15;
    const uint koffB = (uint)(lane >> 4) * 16u;
    const uint aoff0 = (uint)(wr * 64 + row16) * 64u + koffB;
    const uint boff0 = 8192u + (uint)(wc * 128 + row16) * 64u + koffB;

    auto stage = [&](int buf, int t) {
        const ushort* __restrict__ A  = (t < 16) ? A1e : A2e;
        const ushort* __restrict__ Wt = (t < 16) ? W1e : W2e;
        const int kt = (t & 15) * 32;
        char* base = smem + buf * 24576;
        // A: 128 rows (2 row-groups of 64)
#pragma unroll
        for (int c = 0; c < 2; ++c) {
            const int rb = c * 64 + w * 16;   // wave-uniform LDS row base
            async_copy16(A + (size_t)(m0 + rb + srow) * 512 + kt + schk * 8, base + rb * 64);
        }
        // B: 256 rows (4 row-groups of 64)
#pragma unroll
        for (int c = 0; c < 4; ++c) {
            const int rb = c * 64 + w * 16;
            async_copy16(Wt + (size_t)(n0 + rb + srow) * 512 + kt + schk * 8,
                         base + 8192 + rb * 64);
        }
    };
    auto compute = [&](int buf) {
        const char* base = smem + buf * 24576;
        bf16x8 af[4], bfr[8];
#pragma unroll
        for (int i = 0; i < 4; ++i) af[i] = *(const bf16x8*)(base + aoff0 + i * 1024);
#pragma unroll
        for (int j = 0; j < 8; ++j) bfr[j] = *(const bf16x8*)(base + boff0 + j * 1024);
#pragma unroll
        for (int i = 0; i < 4; ++i)
#pragma unroll
            for (int j = 0; j < 8; ++j)
                acc[i][j] = __builtin_amdgcn_mfma_f32_16x16x32_bf16(af[i], bfr[j], acc[i][j], 0, 0, 0);
    };

    // 2-phase pipeline (proven skeleton; vmcnt(6) = one stage's load count)
    stage(0, 0);
    for (int t = 0; t < 31; ++t) {
        stage((t + 1) & 1, t + 1);
        asm volatile("s_waitcnt vmcnt(6)" ::: "memory");
        __builtin_amdgcn_s_barrier();
        compute(t & 1);
        __builtin_amdgcn_s_barrier();
    }
    asm volatile("s_waitcnt vmcnt(0)" ::: "memory");
    __builtin_amdgcn_s_barrier();
    compute(1);

    // epilogue: C/D layout col = lane&15, row = (lane>>4)*4 + q
#pragma unroll
    for (int i = 0; i < 4; ++i) {
        const int r0 = m0 + wr * 64 + i * 16 + (lane >> 4) * 4;
#pragma unroll
        for (int j = 0; j < 8; ++j) {
            const int c = n0 + wc * 128 + j * 16 + row16;
            const float bj = be[c];
#pragma unroll
            for (int q2 = 0; q2 < 4; ++q2) {
                const int r = r0 + q2;
                float v = acc[i][j][q2] + bj;
                if (EPI == 0) {
                    if (RELU) v = fmaxf(v, 0.f);
                    oe[(size_t)r * 512 + c] = f2bf(v);
                } else {  // EPI 6
                    const float wrow = (r < N_NODES) ? wcol[(size_t)r * 4 + e] : 0.f;
                    oe[(size_t)r * 512 + c] = f2bf(v * wrow);
                }
            }
        }
    }
}

// ================= encoder/router bf16x3 GEMM (2-phase, proven, unchanged) ==
// EPI 4: hi/lo bf16 split -> out0/out1 ; EPI 5: out0 fp32
template<int NPASS, int EPI, int NBN>
__global__ __launch_bounds__(256)
void gemm_mfma(const ushort* __restrict__ A0, const ushort* __restrict__ W0,
               const ushort* __restrict__ A1p, const ushort* __restrict__ W1p,
               const ushort* __restrict__ A2p, const ushort* __restrict__ W2p,
               const float* __restrict__ bias,
               void* __restrict__ out0, void* __restrict__ out1, int Ncols)
{
    __shared__ char smem[32768];
    const int tid = threadIdx.x;
    const int w = tid >> 6, lane = tid & 63;

    const int wgid = xcd_swizzle(blockIdx.x, gridDim.x);
    const int m0 = (wgid / NBN) * 128;
    const int n0 = (wgid % NBN) * 128;

    f32x4 acc[4][4];
#pragma unroll
    for (int i = 0; i < 4; ++i)
#pragma unroll
        for (int j = 0; j < 4; ++j) acc[i][j] = (f32x4){0.f, 0.f, 0.f, 0.f};

    const int srow = lane >> 2, schk = lane & 3;
    const int wr = w >> 1, wc = w & 1;
    const int row16 = lane & 15;
    const uint koffB = (uint)(lane >> 4) * 16u;
    const uint aoff0 = (uint)(wr * 64 + row16) * 64u + koffB;
    const uint boff0 = 8192u + (uint)(wc * 64 + row16) * 64u + koffB;

    const int NT = NPASS * 16;
    auto Asel = [&](int t) -> const ushort* { return (t < 16) ? A0 : ((t < 32) ? A1p : A2p); };
    auto Wsel = [&](int t) -> const ushort* { return (t < 16) ? W0 : ((t < 32) ? W1p : W2p); };

    auto stage = [&](int buf, int t) {
        const ushort* __restrict__ A  = Asel(t);
        const ushort* __restrict__ Wt = Wsel(t);
        const int kt = (t & 15) * 32;
        char* base = smem + buf * 16384;
#pragma unroll
        for (int c = 0; c < 2; ++c) {
            const int rb = c * 64 + w * 16;
            async_copy16(A  + (size_t)(m0 + rb + srow) * 512 + kt + schk * 8, base + rb * 64);
            async_copy16(Wt + (size_t)(n0 + rb + srow) * 512 + kt + schk * 8, base + 8192 + rb * 64);
        }
    };
    auto compute = [&](int buf) {
        const char* base = smem + buf * 16384;
        bf16x8 af[4], bfr[4];
#pragma unroll
        for (int i = 0; i < 4; ++i) af[i] = *(const bf16x8*)(base + aoff0 + i * 1024);
#pragma unroll
        for (int j = 0; j < 4; ++j) bfr[j] = *(const bf16x8*)(base + boff0 + j * 1024);
#pragma unroll
        for (int i = 0; i < 4; ++i)
#pragma unroll
            for (int j = 0; j < 4; ++j)
                acc[i][j] = __builtin_amdgcn_mfma_f32_16x16x32_bf16(af[i], bfr[j], acc[i][j], 0, 0, 0);
    };

    stage(0, 0);
    for (int t = 0; t < NT - 1; ++t) {
        stage((t + 1) & 1, t + 1);
        asm volatile("s_waitcnt vmcnt(4)" ::: "memory");
        __builtin_amdgcn_s_barrier();
        compute(t & 1);
        __builtin_amdgcn_s_barrier();
    }
    asm volatile("s_waitcnt vmcnt(0)" ::: "memory");
    __builtin_amdgcn_s_barrier();
    compute((NT - 1) & 1);

#pragma unroll
    for (int i = 0; i < 4; ++i) {
        const int r0 = m0 + wr * 64 + i * 16 + (lane >> 4) * 4;
#pragma unroll
        for (int j = 0; j < 4; ++j) {
            const int c = n0 + wc * 64 + j * 16 + row16;
            const float bj = (EPI == 5) ? 0.f : bias[c];
#pragma unroll
            for (int q2 = 0; q2 < 4; ++q2) {
                const int r = r0 + q2;
                float v = acc[i][j][q2] + bj;
                if (EPI == 4) {
                    const ushort hi = f2bf(v);
                    const ushort lo = f2bf(v - bf2f(hi));
                    ((ushort*)out0)[(size_t)r * Ncols + c] = hi;
                    ((ushort*)out1)[(size_t)r * Ncols + c] = lo;
                } else {
                    ((float*)out0)[(size_t)r * Ncols + c] = v;
                }
            }
        }
    }
}

// out[r,c] = sum_e bf2f(wz[e][r,c])  (wz 4 experts contiguous, 2 cols/thread)
__global__ __launch_bounds__(256)
void reduce_wz_kernel(const uint* __restrict__ wz4, float2* __restrict__ out)
{
    const size_t idx = (size_t)blockIdx.x * 256 + threadIdx.x;  // < N_NODES*256
    const size_t es = (size_t)P_ROWS * 256;  // uints per expert
    const uint a = wz4[idx], b = wz4[idx + es];
    const uint c = wz4[idx + 2 * es], d = wz4[idx + 3 * es];
    float lo = bf2f((ushort)(a & 0xffffu)) + bf2f((ushort)(b & 0xffffu))
             + bf2f((ushort)(c & 0xffffu)) + bf2f((ushort)(d & 0xffffu));
    float hi = bf2f((ushort)(a >> 16)) + bf2f((ushort)(b >> 16))
             + bf2f((ushort)(c >> 16)) + bf2f((ushort)(d >> 16));
    out[idx] = make_float2(lo, hi);
}

// t1 = relu(x[:,4:10] @ enc_W1 + enc_b1), split into bf16 hi+lo; zero pad rows
__global__ void encoder1_kernel(const float* __restrict__ x, const float* __restrict__ W1,
                                const float* __restrict__ b1,
                                ushort* __restrict__ t1hi, ushort* __restrict__ t1lo)
{
    const int idx = blockIdx.x * blockDim.x + threadIdx.x;
    if (idx >= P_ROWS * H_DIM) return;
    const int i = idx / H_DIM, j = idx - i * H_DIM;
    float v = 0.f;
    if (i < N_NODES) {
        const float* xr = &x[i * 16 + 4];
        v = b1[j];
#pragma unroll
        for (int k = 0; k < 6; ++k) v = fmaf(xr[k], W1[k * H_DIM + j], v);
        v = fmaxf(v, 0.f);
    }
    const ushort hi = f2bf(v);
    t1hi[idx] = hi;
    t1lo[idx] = f2bf(v - bf2f(hi));
}

__global__ void zero_ints_kernel(int* __restrict__ p, int n)
{
    const int idx = blockIdx.x * blockDim.x + threadIdx.x;
    if (idx < n) p[idx] = 0;
}

__global__ void graph_bounds_kernel(const int* __restrict__ batch, int* __restrict__ gstart)
{
    const int g = threadIdx.x;
    if (g > G_GRAPHS) return;
    int lo = 0, hi = N_NODES;
    while (lo < hi) {
        const int mid = (lo + hi) >> 1;
        if (batch[mid] < g) lo = mid + 1; else hi = mid;
    }
    gstart[g] = lo;
}

__global__ __launch_bounds__(256)
void edge_hist_kernel(const int* __restrict__ src, const int* __restrict__ dst,
                      const int* __restrict__ batch,
                      int* __restrict__ part, int* __restrict__ deg)
{
    __shared__ int hist[G_GRAPHS];
    const int tid = threadIdx.x;
    if (tid < G_GRAPHS) hist[tid] = 0;
    __syncthreads();
    for (int e = blockIdx.x * 256 + tid; e < N_EDGES; e += EH_BLOCKS * 256) {
        atomicAdd(&deg[dst[e]], 1);
        atomicAdd(&hist[batch[src[e]]], 1);
    }
    __syncthreads();
    if (tid < G_GRAPHS) part[blockIdx.x * G_GRAPHS + tid] = hist[tid];
}

__global__ void stats_finalize_kernel(const int* __restrict__ gstart, const int* __restrict__ part,
                                      float* __restrict__ f_norm, float* __restrict__ size_norm)
{
    const int g = threadIdx.x;  // exactly 64
    const float nn = fmaxf((float)(gstart[g + 1] - gstart[g]), 1.0f);
    int ec = 0;
#pragma unroll 8
    for (int b = 0; b < EH_BLOCKS; ++b) ec += part[b * G_GRAPHS + g];
    const float ee = (float)ec;
    const float ln = logf(nn);
    const float le = log1pf(ee);
    float s0 = ln, s1 = le;
#pragma unroll
    for (int o = 32; o > 0; o >>= 1) { s0 += __shfl_xor(s0, o); s1 += __shfl_xor(s1, o); }
    const float m0 = s0 / 64.f, m1 = s1 / 64.f;
    const float d0 = ln - m0, d1 = le - m1;
    float v0 = d0 * d0, v1 = d1 * d1;
#pragma unroll
    for (int o = 32; o > 0; o >>= 1) { v0 += __shfl_xor(v0, o); v1 += __shfl_xor(v1, o); }
    const float sd0 = sqrtf(v0 / 64.f), sd1 = sqrtf(v1 / 64.f);
    float mn = ln, mx = ln;
#pragma unroll
    for (int o = 32; o > 0; o >>= 1) {
        mn = fminf(mn, __shfl_xor(mn, o));
        mx = fmaxf(mx, __shfl_xor(mx, o));
    }
    f_norm[g * 2 + 0] = d0 / (sd0 + 1e-6f);
    f_norm[g * 2 + 1] = d1 / (sd1 + 1e-6f);
    size_norm[g] = (ln - mn) / (mx - mn + 1e-6f);
}

__global__ void scan_kernel(const int* __restrict__ in, int* __restrict__ row_ptr,
                            int* __restrict__ cursor, int n)
{
    __shared__ int wsum[16];
    __shared__ int carry_s;
    const int tid = threadIdx.x;
    const int lane = tid & 63, wv = tid >> 6;
    if (tid == 0) carry_s = 0;
    __syncthreads();
    for (int base = 0; base < n; base += 1024) {
        const int idx = base + tid;
        const int v = (idx < n) ? in[idx] : 0;
        int x = v;
#pragma unroll
        for (int o = 1; o < 64; o <<= 1) { const int t = __shfl_up(x, o); if (lane >= o) x += t; }
        if (lane == 63) wsum[wv] = x;
        __syncthreads();
        const int carry = carry_s;
        if (wv == 0) {
            int y = (lane < 16) ? wsum[lane] : 0;
#pragma unroll
            for (int o = 1; o < 16; o <<= 1) { const int t = __shfl_up(y, o); if (lane >= o) y += t; }
            if (lane < 16) wsum[lane] = y;
        }
        __syncthreads();
        const int woff = (wv > 0) ? wsum[wv - 1] : 0;
        const int excl = x - v + woff + carry;
        if (idx < n) { row_ptr[idx] = excl; cursor[idx] = excl; }
        __syncthreads();
        if (tid == 0) carry_s = carry + wsum[15];
        __syncthreads();
    }
    if (tid == 0) row_ptr[n] = carry_s;
}

__global__ void scatter_kernel(const int* __restrict__ src, const int* __restrict__ dst,
                               int* __restrict__ cursor, int* __restrict__ csr_col)
{
    const int e = blockIdx.x * blockDim.x + threadIdx.x;
    if (e >= N_EDGES) return;
    const int d = dst[e];
    const int slot = atomicAdd(&cursor[d], 1);
    csr_col[slot] = src[e];
}

__global__ void sort_adj_kernel(const int* __restrict__ row_ptr, int* __restrict__ csr_col)
{
    const int i = blockIdx.x * blockDim.x + threadIdx.x;
    if (i >= N_NODES) return;
    const int b = row_ptr[i], e = row_ptr[i + 1];
    for (int p = b + 1; p < e; ++p) {
        const int key = csr_col[p];
        int q = p - 1;
        while (q >= b && csr_col[q] > key) { csr_col[q + 1] = csr_col[q]; --q; }
        csr_col[q + 1] = key;
    }
}

// agg[e][i,:] = sum over in-edges of z[e][src,:]
// wave-per-node, uint4 (16B/lane) loads; 4 nodes per 256-thr block.
// Same ascending-CSR fp32 add order as before -> bit-identical result.
__global__ __launch_bounds__(256)
void aggregate_bf16(const uint4* __restrict__ z4, const int* __restrict__ row_ptr,
                    const int* __restrict__ csr_col, uint4* __restrict__ agg4)
{
    const size_t es = (size_t)blockIdx.y * P_ROWS * 64;   // uint4s per expert
    const uint4* __restrict__ zz = z4 + es;
    uint4* __restrict__ aa = agg4 + es;
    const int i = blockIdx.x * 4 + (threadIdx.x >> 6);     // node (grid 5000x4 exact)
    const int lane = threadIdx.x & 63;
    const int b = row_ptr[i], e = row_ptr[i + 1];
    float acc[8];
#pragma unroll
    for (int k = 0; k < 8; ++k) acc[k] = 0.f;
    auto add8 = [&](uint4 v) {
        acc[0] += bf2f((ushort)(v.x & 0xffffu)); acc[1] += bf2f((ushort)(v.x >> 16));
        acc[2] += bf2f((ushort)(v.y & 0xffffu)); acc[3] += bf2f((ushort)(v.y >> 16));
        acc[4] += bf2f((ushort)(v.z & 0xffffu)); acc[5] += bf2f((ushort)(v.z >> 16));
        acc[6] += bf2f((ushort)(v.w & 0xffffu)); acc[7] += bf2f((ushort)(v.w >> 16));
    };
    int p = b;
    for (; p + 2 <= e; p += 2) {
        const uint4 v0 = zz[(size_t)csr_col[p] * 64 + lane];
        const uint4 v1 = zz[(size_t)csr_col[p + 1] * 64 + lane];
        add8(v0);
        add8(v1);
    }
    if (p < e) add8(zz[(size_t)csr_col[p] * 64 + lane]);
    uint4 o;
    o.x = (uint)f2bf(acc[0]) | ((uint)f2bf(acc[1]) << 16);
    o.y = (uint)f2bf(acc[2]) | ((uint)f2bf(acc[3]) << 16);
    o.z = (uint)f2bf(acc[4]) | ((uint)f2bf(acc[5]) << 16);
    o.w = (uint)f2bf(acc[6]) | ((uint)f2bf(acc[7]) << 16);
    aa[(size_t)i * 64 + lane] = o;
}

// one 512x512 matrix per blockIdx.z: Wt[n][k] = bf16(W[k][n])
__global__ __launch_bounds__(256)
void transpose_f32_to_bf16(const float* __restrict__ W, ushort* __restrict__ Wt)
{
    __shared__ float tile[32][33];
    const float* Wm = W + (size_t)blockIdx.z * WSZ;
    ushort* Wtm = Wt + (size_t)blockIdx.z * WSZ;
    const int c0 = blockIdx.x * 32, r0 = blockIdx.y * 32;
    const int tc = threadIdx.x & 31, tr = threadIdx.x >> 5;
#pragma unroll
    for (int it = 0; it < 4; ++it)
        tile[tr + it * 8][tc] = Wm[(size_t)(r0 + tr + it * 8) * 512 + c0 + tc];
    __syncthreads();
#pragma unroll
    for (int it = 0; it < 4; ++it) {
        const int cr = tr + it * 8;
        Wtm[(size_t)(c0 + cr) * 512 + r0 + tc] = f2bf(tile[tc][cr]);
    }
}

// W [512][Nin] fp32 -> Wt hi/lo [Nin][512] bf16 (k-stride 512)
__global__ __launch_bounds__(256)
void transpose_split_kernel(const float* __restrict__ W, ushort* __restrict__ Whi,
                            ushort* __restrict__ Wlo, int Nin)
{
    __shared__ float tile[32][33];
    const int c0 = blockIdx.x * 32;
    const int r0 = blockIdx.y * 32;
    const int tc = threadIdx.x & 31, tr = threadIdx.x >> 5;
#pragma unroll
    for (int it = 0; it < 4; ++it)
        tile[tr + it * 8][tc] = W[(size_t)(r0 + tr + it * 8) * Nin + c0 + tc];
    __syncthreads();
#pragma unroll
    for (int it = 0; it < 4; ++it) {
        const int cr = tr + it * 8;
        const float v = tile[tc][cr];
        const ushort hi = f2bf(v);
        Whi[(size_t)(c0 + cr) * 512 + r0 + tc] = hi;
        Wlo[(size_t)(c0 + cr) * 512 + r0 + tc] = f2bf(v - bf2f(hi));
    }
}

// router tail (fp32)
__global__ __launch_bounds__(128)
void router_kernel(const float* __restrict__ rtmp, const int* __restrict__ batch,
                   const float* __restrict__ rW1, const float* __restrict__ rb1,
                   const float* __restrict__ lng, const float* __restrict__ lnb,
                   const float* __restrict__ rW2, const float* __restrict__ rb2,
                   const float* __restrict__ centers,
                   const float* __restrict__ f_norm, const float* __restrict__ size_norm,
                   float* __restrict__ weights)
{
    const int i = blockIdx.x;
    const int j = threadIdx.x;
    const int g = batch[i];
    const float f0 = f_norm[g * 2], f1 = f_norm[g * 2 + 1];
    float r = rtmp[(size_t)i * RH_DIM + j]
            + f0 * rW1[512 * RH_DIM + j] + f1 * rW1[513 * RH_DIM + j] + rb1[j];

    __shared__ float part[2];
    __shared__ float rbuf[RH_DIM];
    __shared__ float lbuf[4];
    const int lane = j & 63, wv = j >> 6;

    float s = r;
#pragma unroll
    for (int o = 32; o > 0; o >>= 1) s += __shfl_xor(s, o);
    if (lane == 0) part[wv] = s;
    __syncthreads();
    const float mean = (part[0] + part[1]) / 128.f;
    __syncthreads();
    const float d = r - mean;
    float v = d * d;
#pragma unroll
    for (int o = 32; o > 0; o >>= 1) v += __shfl_xor(v, o);
    if (lane == 0) part[wv] = v;
    __syncthreads();
    const float var = (part[0] + part[1]) / 128.f;
    const float rn = d / sqrtf(var + 1e-5f) * lng[j] + lnb[j];
    rbuf[j] = fmaxf(rn, 0.f);
    __syncthreads();

    if (j < 4) {
        float acc = rb2[j];
        for (int t = 0; t < RH_DIM; ++t) acc = fmaf(rbuf[t], rW2[t * 4 + j], acc);
        const float sn = size_norm[g];
        const float dd = sn - centers[j];
        lbuf[j] = 0.7f * acc + 0.3f * (-(dd * dd));
    }
    __syncthreads();
    if (j == 0) {
        float p[4];
        const float mx = fmaxf(fmaxf(lbuf[0], lbuf[1]), fmaxf(lbuf[2], lbuf[3]));
#pragma unroll
        for (int c = 0; c < 4; ++c) p[c] = expf(lbuf[c] - mx);
        const float ssum = p[0] + p[1] + p[2] + p[3];
#pragma unroll
        for (int c = 0; c < 4; ++c) p[c] /= ssum;
        int i1 = 0;
#pragma unroll
        for (int c = 1; c < 4; ++c) if (p[c] > p[i1]) i1 = c;
        int i2 = -1;
#pragma unroll
        for (int c = 0; c < 4; ++c) {
            if (c == i1) continue;
            if (i2 < 0 || p[c] > p[i2]) i2 = c;
        }
        const float vs = p[i1] + p[i2] + 1e-8f;
        float wout[4] = {0.f, 0.f, 0.f, 0.f};
        wout[i1] = p[i1] / vs;
        wout[i2] = p[i2] / vs;
#pragma unroll
        for (int c = 0; c < 4; ++c) weights[(size_t)i * 4 + c] = wout[c];
    }
}

extern "C" void kernel_launch(void* const* d_in, const int* in_sizes, int n_in,
                              void* d_out, int out_size, void* d_ws, size_t ws_size,
                              hipStream_t stream)
{
    const float* x       = (const float*)d_in[0];
    const int*   ei      = (const int*)d_in[1];
    const int*   batch   = (const int*)d_in[2];
    const float* enc_W1  = (const float*)d_in[4];
    const float* enc_b1  = (const float*)d_in[5];
    const float* enc_W2  = (const float*)d_in[6];
    const float* enc_b2  = (const float*)d_in[7];
    const float* r_W1    = (const float*)d_in[8];
    const float* r_b1    = (const float*)d_in[9];
    const float* ln_g    = (const float*)d_in[10];
    const float* ln_b    = (const float*)d_in[11];
    const float* r_W2    = (const float*)d_in[12];
    const float* r_b2    = (const float*)d_in[13];
    const float* centers = (const float*)d_in[14];
    const float* W_rel   = (const float*)d_in[15];
    const float* b_rel   = (const float*)d_in[16];
    const float* W_root  = (const float*)d_in[17];
    const int* src = ei;
    const int* dst = ei + N_EDGES;
    float* out = (float*)d_out;

    const size_t PF = (size_t)P_ROWS * H_DIM;
    // 4-expert-merged path if workspace allows (accurate threshold ~366MB)
    const size_t need4 = (size_t)372 * 1024 * 1024;
    const bool path4 = (ws_size >= need4);
    const int NEPD = path4 ? 4 : 2;           // experts per dispatch
    const size_t ZBYTES = PF * 2 * NEPD;      // z/agg buffer bytes per stage

    char* wsp = (char*)d_ws;
    size_t off = 0;
    auto alloc = [&](size_t bytes) -> char* {
        char* p = wsp + off;
        off = (off + bytes + 255) & ~(size_t)255;
        return p;
    };
    // region1+region2 contiguous: t1hi|t1lo , h_hi|h_lo -> later wz4 (4 x PF bf16)
    char* region1 = alloc(PF * 4);
    ushort* t1hi = (ushort*)region1;
    ushort* t1lo = (ushort*)(region1 + PF * 2);
    ushort* wz4  = (ushort*)region1;           // spans region1+region2
    char* region2 = alloc(PF * 4);
    ushort* h_hi = (ushort*)region2;
    ushort* h_lo = (ushort*)(region2 + PF * 2);
    // z/agg buffers (NEPD-wide); rtmp fp32 aliases zA start (dead before expert L0)
    char* B_zA = alloc(ZBYTES);
    ushort* zAe = (ushort*)B_zA;
    float*  rtmp = (float*)B_zA;
    char* B_zB = alloc(ZBYTES);
    ushort* zBe = (ushort*)B_zB;
    char* B_ag = alloc(ZBYTES);
    ushort* agge = (ushort*)B_ag;
    ushort* aggH16 = (ushort*)alloc(PF * 2);
    ushort* Wt_rel16  = (ushort*)alloc((size_t)12 * WSZ * 2);
    ushort* Wt_root16 = (ushort*)alloc((size_t)12 * WSZ * 2);
    ushort* W2t_hi = (ushort*)alloc((size_t)WSZ * 2);
    ushort* W2t_lo = (ushort*)alloc((size_t)WSZ * 2);
    ushort* rW1t_hi = (ushort*)alloc((size_t)128 * 512 * 2);
    ushort* rW1t_lo = (ushort*)alloc((size_t)128 * 512 * 2);
    float*  weights = (float*)alloc((size_t)P_ROWS * 4 * 4);
    int* deg     = (int*)alloc((size_t)N_NODES * 4);
    int* gstart  = (int*)alloc((size_t)(G_GRAPHS + 1) * 4);
    int* part    = (int*)alloc((size_t)EH_BLOCKS * G_GRAPHS * 4);
    int* row_ptr = (int*)alloc((size_t)(N_NODES + 1) * 4);
    int* cursor  = (int*)alloc((size_t)N_NODES * 4);
    int* csr_col = (int*)alloc((size_t)N_EDGES * 4);
    float* f_norm    = (float*)alloc((size_t)G_GRAPHS * 2 * 4);
    float* size_norm = (float*)alloc((size_t)G_GRAPHS * 4);
    (void)in_sizes; (void)n_in; (void)out_size;

    const int enc_nwg = 4 * (P_ROWS / 128);               // 628
    const int rtr_nwg = 1 * (P_ROWS / 128);               // 157
    const int grp_nwg = 2 * NEPD * (P_ROWS / 128);        // 1256 or 628 (256-col tiles)
    const dim3 tr_grid(16, 16, 12);
    const dim3 agg_grid1(N_NODES / 4, 1), agg_gridE(N_NODES / 4, NEPD);

    // 0) zero deg + one-time weight transposes/splits
    zero_ints_kernel<<<(N_NODES + 255) / 256, 256, 0, stream>>>(deg, N_NODES);
    transpose_f32_to_bf16<<<tr_grid, 256, 0, stream>>>(W_rel, Wt_rel16);
    transpose_f32_to_bf16<<<tr_grid, 256, 0, stream>>>(W_root, Wt_root16);
    transpose_split_kernel<<<dim3(16, 16), 256, 0, stream>>>(enc_W2, W2t_hi, W2t_lo, 512);
    transpose_split_kernel<<<dim3(4, 16), 256, 0, stream>>>(r_W1, rW1t_hi, rW1t_lo, 128);
    // 1) graph stats (contention-free)
    graph_bounds_kernel<<<1, 128, 0, stream>>>(batch, gstart);
    edge_hist_kernel<<<EH_BLOCKS, 256, 0, stream>>>(src, dst, batch, part, deg);
    stats_finalize_kernel<<<1, 64, 0, stream>>>(gstart, part, f_norm, size_norm);
    // 2) encoder: t1 (split) then h = t1@W2 via bf16x3 -> h_hi/h_lo
    encoder1_kernel<<<(P_ROWS * H_DIM + 255) / 256, 256, 0, stream>>>(x, enc_W1, enc_b1, t1hi, t1lo);
    gemm_mfma<3, 4, 4><<<enc_nwg, 256, 0, stream>>>(
        t1hi, W2t_hi, t1hi, W2t_lo, t1lo, W2t_hi, enc_b2, h_hi, h_lo, 512);
    // 3) router: rtmp = h@rW1 via bf16x3 (t1 region dead now)
    gemm_mfma<3, 5, 1><<<rtr_nwg, 256, 0, stream>>>(
        h_hi, rW1t_hi, h_hi, rW1t_lo, h_lo, rW1t_hi, nullptr, rtmp, nullptr, 128);
    router_kernel<<<N_NODES, 128, 0, stream>>>(rtmp, batch, r_W1, r_b1, ln_g, ln_b,
                                               r_W2, r_b2, centers, f_norm, size_norm, weights);
    // 4) CSR build (deterministic: sorted adjacency)
    scan_kernel<<<1, 1024, 0, stream>>>(deg, row_ptr, cursor, N_NODES);
    scatter_kernel<<<(N_EDGES + 255) / 256, 256, 0, stream>>>(src, dst, cursor, csr_col);
    sort_adj_kernel<<<(N_NODES + 255) / 256, 256, 0, stream>>>(row_ptr, csr_col);
    // 5) shared layer-0 aggregation
    aggregate_bf16<<<agg_grid1, 256, 0, stream>>>((const uint4*)h_hi, row_ptr, csr_col,
                                                  (uint4*)aggH16);

    // 6) experts (128x256-tile GEMM)
    const size_t WES = (size_t)3 * WSZ;   // expert stride in Wt buffers
    const size_t BES = (size_t)3 * 512;   // expert stride in b_rel
    if (path4) {
        gemm_grp<true, 0, 4><<<grp_nwg, 256, 0, stream>>>(
            aggH16, 0, Wt_rel16, WES, h_hi, 0, Wt_root16, WES, b_rel, BES, nullptr, zAe, PF);
        aggregate_bf16<<<agg_gridE, 256, 0, stream>>>((const uint4*)zAe, row_ptr, csr_col,
                                                      (uint4*)agge);
        gemm_grp<true, 0, 4><<<grp_nwg, 256, 0, stream>>>(
            agge, PF, Wt_rel16 + WSZ, WES, zAe, PF, Wt_root16 + WSZ, WES, b_rel + 512, BES,
            nullptr, zBe, PF);
        aggregate_bf16<<<agg_gridE, 256, 0, stream>>>((const uint4*)zBe, row_ptr, csr_col,
                                                      (uint4*)agge);
        gemm_grp<false, 6, 4><<<grp_nwg, 256, 0, stream>>>(
            agge, PF, Wt_rel16 + 2 * WSZ, WES, zBe, PF, Wt_root16 + 2 * WSZ, WES, b_rel + 1024, BES,
            weights, wz4, PF);
    } else {
        for (int p = 0; p < 2; ++p) {
            const size_t eb = (size_t)(p * 2);
            const ushort* WrP = Wt_rel16  + eb * WES;
            const ushort* WoP = Wt_root16 + eb * WES;
            const float*  brP = b_rel + eb * BES;
            ushort* wzP = wz4 + eb * PF;
            gemm_grp<true, 0, 2><<<grp_nwg, 256, 0, stream>>>(
                aggH16, 0, WrP, WES, h_hi, 0, WoP, WES, brP, BES, nullptr, zAe, PF);
            aggregate_bf16<<<agg_gridE, 256, 0, stream>>>((const uint4*)zAe, row_ptr, csr_col,
                                                          (uint4*)agge);
            gemm_grp<true, 0, 2><<<grp_nwg, 256, 0, stream>>>(
                agge, PF, WrP + WSZ, WES, zAe, PF, WoP + WSZ, WES, brP + 512, BES, nullptr, zBe, PF);
            aggregate_bf16<<<agg_gridE, 256, 0, stream>>>((const uint4*)zBe, row_ptr, csr_col,
                                                          (uint4*)agge);
            gemm_grp<false, 6, 2><<<grp_nwg, 256, 0, stream>>>(
                agge, PF, WrP + 2 * WSZ, WES, zBe, PF, WoP + 2 * WSZ, WES, brP + 1024, BES,
                weights + eb, wzP, PF);
        }
    }
    // 7) out = sum_e wz[e]
    reduce_wz_kernel<<<N_NODES, 256, 0, stream>>>((const uint*)wz4, (float2*)out);
}

// Round 10
// 836.662 us; speedup vs baseline: 5.4118x; 1.0144x over previous
//
#include <hip/hip_runtime.h>
#include <math.h>

// ---------------- problem constants (match reference) ----------------
#define N_NODES 20000
#define N_EDGES 160000
#define G_GRAPHS 64
#define H_DIM 512
#define RH_DIM 128
#define NE_EXP 4
#define P_ROWS 20096   // 157 * 128, padded row count for GEMM tiles
#define EH_BLOCKS 64   // edge-histogram partial blocks
#define WSZ (512 * 512)

// ================= bf16 helpers =================
typedef __attribute__((ext_vector_type(8))) short bf16x8;
typedef __attribute__((ext_vector_type(4))) float f32x4;

__device__ __forceinline__ ushort f2bf(float f) {
    uint u = __float_as_uint(f);
    return (ushort)((u + 0x7FFFu + ((u >> 16) & 1u)) >> 16);  // round-to-nearest-even
}
__device__ __forceinline__ float bf2f(ushort h) {
    return __uint_as_float(((uint)h) << 16);
}

__device__ __forceinline__ void async_copy16(const void* g, void* l) {
    __builtin_amdgcn_global_load_lds(
        (__attribute__((address_space(1))) void*)g,
        (__attribute__((address_space(3))) void*)l, 16, 0, 0);
}

// ---- T1 bijective XCD swizzle (m204) ----
__device__ __forceinline__ int xcd_swizzle(int orig, int nwg) {
    const int q = nwg >> 3, r = nwg & 7;
    const int xcd = orig & 7, sid = orig >> 3;
    return (xcd < r ? xcd * (q + 1) : r * (q + 1) + (xcd - r) * q) + sid;
}

// ================= grouped expert GEMM (NE2 experts per launch) =============
// PROVEN R6/R8 kernel: 128x128 tile, 2-phase pipeline, vmcnt(4), 32KB LDS.
// EPI 0: out bf16(relu?(v+bias)) ; EPI 6: out bf16((v+bias)*wcol[r*4+e])
template<bool RELU, int EPI, int NE2>
__global__ __launch_bounds__(256)
void gemm_grp(const ushort* __restrict__ A1, size_t a1es,
              const ushort* __restrict__ W1, size_t w1es,
              const ushort* __restrict__ A2, size_t a2es,
              const ushort* __restrict__ W2, size_t w2es,
              const float* __restrict__ bias, size_t bes,
              const float* __restrict__ wcol,
              ushort* __restrict__ out0, size_t oes)
{
    __shared__ char smem[32768];   // 2 bufs x (A 8KB | B 8KB)
    const int tid = threadIdx.x;
    const int w = tid >> 6, lane = tid & 63;

    const int wgid = xcd_swizzle(blockIdx.x, gridDim.x);
    const int m0 = (wgid / (4 * NE2)) * 128;
    const int rem = wgid % (4 * NE2);
    const int e  = rem % NE2;
    const int n0 = (rem / NE2) * 128;

    const ushort* __restrict__ A1e = A1 + (size_t)e * a1es;
    const ushort* __restrict__ W1e = W1 + (size_t)e * w1es;
    const ushort* __restrict__ A2e = A2 + (size_t)e * a2es;
    const ushort* __restrict__ W2e = W2 + (size_t)e * w2es;
    const float*  __restrict__ be  = bias + (size_t)e * bes;
    ushort* __restrict__ oe = out0 + (size_t)e * oes;

    f32x4 acc[4][4];
#pragma unroll
    for (int i = 0; i < 4; ++i)
#pragma unroll
        for (int j = 0; j < 4; ++j) acc[i][j] = (f32x4){0.f, 0.f, 0.f, 0.f};

    const int srow = lane >> 2, schk = lane & 3;
    const int wr = w >> 1, wc = w & 1;
    const int row16 = lane & 15;
    const uint koffB = (uint)(lane >> 4) * 16u;
    const uint aoff0 = (uint)(wr * 64 + row16) * 64u + koffB;
    const uint boff0 = 8192u + (uint)(wc * 64 + row16) * 64u + koffB;

    auto stage = [&](int buf, int t) {
        const ushort* __restrict__ A  = (t < 16) ? A1e : A2e;
        const ushort* __restrict__ Wt = (t < 16) ? W1e : W2e;
        const int kt = (t & 15) * 32;
        char* base = smem + buf * 16384;
#pragma unroll
        for (int c = 0; c < 2; ++c) {
            const int rb = c * 64 + w * 16;   // wave-uniform LDS row base
            async_copy16(A  + (size_t)(m0 + rb + srow) * 512 + kt + schk * 8, base + rb * 64);
            async_copy16(Wt + (size_t)(n0 + rb + srow) * 512 + kt + schk * 8, base + 8192 + rb * 64);
        }
    };
    auto compute = [&](int buf) {
        const char* base = smem + buf * 16384;
        bf16x8 af[4], bfr[4];
#pragma unroll
        for (int i = 0; i < 4; ++i) af[i] = *(const bf16x8*)(base + aoff0 + i * 1024);
#pragma unroll
        for (int j = 0; j < 4; ++j) bfr[j] = *(const bf16x8*)(base + boff0 + j * 1024);
#pragma unroll
        for (int i = 0; i < 4; ++i)
#pragma unroll
            for (int j = 0; j < 4; ++j)
                acc[i][j] = __builtin_amdgcn_mfma_f32_16x16x32_bf16(af[i], bfr[j], acc[i][j], 0, 0, 0);
    };

    // 2-phase pipeline (T3 minimum + T4 counted vmcnt) — proven R4-R8
    stage(0, 0);
    for (int t = 0; t < 31; ++t) {
        stage((t + 1) & 1, t + 1);
        asm volatile("s_waitcnt vmcnt(4)" ::: "memory");
        __builtin_amdgcn_s_barrier();
        compute(t & 1);
        __builtin_amdgcn_s_barrier();
    }
    asm volatile("s_waitcnt vmcnt(0)" ::: "memory");
    __builtin_amdgcn_s_barrier();
    compute(1);

    // epilogue: C/D layout col = lane&15, row = (lane>>4)*4 + q
#pragma unroll
    for (int i = 0; i < 4; ++i) {
        const int r0 = m0 + wr * 64 + i * 16 + (lane >> 4) * 4;
#pragma unroll
        for (int j = 0; j < 4; ++j) {
            const int c = n0 + wc * 64 + j * 16 + row16;
            const float bj = be[c];
#pragma unroll
            for (int q2 = 0; q2 < 4; ++q2) {
                const int r = r0 + q2;
                float v = acc[i][j][q2] + bj;
                if (EPI == 0) {
                    if (RELU) v = fmaxf(v, 0.f);
                    oe[(size_t)r * 512 + c] = f2bf(v);
                } else {  // EPI 6
                    const float wrow = (r < N_NODES) ? wcol[(size_t)r * 4 + e] : 0.f;
                    oe[(size_t)r * 512 + c] = f2bf(v * wrow);
                }
            }
        }
    }
}

// ================= encoder/router bf16x3 GEMM (2-phase, proven) =============
// EPI 4: hi/lo bf16 split -> out0/out1 ; EPI 5: out0 fp32
template<int NPASS, int EPI, int NBN>
__global__ __launch_bounds__(256)
void gemm_mfma(const ushort* __restrict__ A0, const ushort* __restrict__ W0,
               const ushort* __restrict__ A1p, const ushort* __restrict__ W1p,
               const ushort* __restrict__ A2p, const ushort* __restrict__ W2p,
               const float* __restrict__ bias,
               void* __restrict__ out0, void* __restrict__ out1, int Ncols)
{
    __shared__ char smem[32768];
    const int tid = threadIdx.x;
    const int w = tid >> 6, lane = tid & 63;

    const int wgid = xcd_swizzle(blockIdx.x, gridDim.x);
    const int m0 = (wgid / NBN) * 128;
    const int n0 = (wgid % NBN) * 128;

    f32x4 acc[4][4];
#pragma unroll
    for (int i = 0; i < 4; ++i)
#pragma unroll
        for (int j = 0; j < 4; ++j) acc[i][j] = (f32x4){0.f, 0.f, 0.f, 0.f};

    const int srow = lane >> 2, schk = lane & 3;
    const int wr = w >> 1, wc = w & 1;
    const int row16 = lane & 15;
    const uint koffB = (uint)(lane >> 4) * 16u;
    const uint aoff0 = (uint)(wr * 64 + row16) * 64u + koffB;
    const uint boff0 = 8192u + (uint)(wc * 64 + row16) * 64u + koffB;

    const int NT = NPASS * 16;
    auto Asel = [&](int t) -> const ushort* { return (t < 16) ? A0 : ((t < 32) ? A1p : A2p); };
    auto Wsel = [&](int t) -> const ushort* { return (t < 16) ? W0 : ((t < 32) ? W1p : W2p); };

    auto stage = [&](int buf, int t) {
        const ushort* __restrict__ A  = Asel(t);
        const ushort* __restrict__ Wt = Wsel(t);
        const int kt = (t & 15) * 32;
        char* base = smem + buf * 16384;
#pragma unroll
        for (int c = 0; c < 2; ++c) {
            const int rb = c * 64 + w * 16;
            async_copy16(A  + (size_t)(m0 + rb + srow) * 512 + kt + schk * 8, base + rb * 64);
            async_copy16(Wt + (size_t)(n0 + rb + srow) * 512 + kt + schk * 8, base + 8192 + rb * 64);
        }
    };
    auto compute = [&](int buf) {
        const char* base = smem + buf * 16384;
        bf16x8 af[4], bfr[4];
#pragma unroll
        for (int i = 0; i < 4; ++i) af[i] = *(const bf16x8*)(base + aoff0 + i * 1024);
#pragma unroll
        for (int j = 0; j < 4; ++j) bfr[j] = *(const bf16x8*)(base + boff0 + j * 1024);
#pragma unroll
        for (int i = 0; i < 4; ++i)
#pragma unroll
            for (int j = 0; j < 4; ++j)
                acc[i][j] = __builtin_amdgcn_mfma_f32_16x16x32_bf16(af[i], bfr[j], acc[i][j], 0, 0, 0);
    };

    stage(0, 0);
    for (int t = 0; t < NT - 1; ++t) {
        stage((t + 1) & 1, t + 1);
        asm volatile("s_waitcnt vmcnt(4)" ::: "memory");
        __builtin_amdgcn_s_barrier();
        compute(t & 1);
        __builtin_amdgcn_s_barrier();
    }
    asm volatile("s_waitcnt vmcnt(0)" ::: "memory");
    __builtin_amdgcn_s_barrier();
    compute((NT - 1) & 1);

#pragma unroll
    for (int i = 0; i < 4; ++i) {
        const int r0 = m0 + wr * 64 + i * 16 + (lane >> 4) * 4;
#pragma unroll
        for (int j = 0; j < 4; ++j) {
            const int c = n0 + wc * 64 + j * 16 + row16;
            const float bj = (EPI == 5) ? 0.f : bias[c];
#pragma unroll
            for (int q2 = 0; q2 < 4; ++q2) {
                const int r = r0 + q2;
                float v = acc[i][j][q2] + bj;
                if (EPI == 4) {
                    const ushort hi = f2bf(v);
                    const ushort lo = f2bf(v - bf2f(hi));
                    ((ushort*)out0)[(size_t)r * Ncols + c] = hi;
                    ((ushort*)out1)[(size_t)r * Ncols + c] = lo;
                } else {
                    ((float*)out0)[(size_t)r * Ncols + c] = v;
                }
            }
        }
    }
}

// out[r,c] = sum_e bf2f(wz[e][r,c])  (wz 4 experts contiguous, 2 cols/thread)
__global__ __launch_bounds__(256)
void reduce_wz_kernel(const uint* __restrict__ wz4, float2* __restrict__ out)
{
    const size_t idx = (size_t)blockIdx.x * 256 + threadIdx.x;  // < N_NODES*256
    const size_t es = (size_t)P_ROWS * 256;  // uints per expert
    const uint a = wz4[idx], b = wz4[idx + es];
    const uint c = wz4[idx + 2 * es], d = wz4[idx + 3 * es];
    float lo = bf2f((ushort)(a & 0xffffu)) + bf2f((ushort)(b & 0xffffu))
             + bf2f((ushort)(c & 0xffffu)) + bf2f((ushort)(d & 0xffffu));
    float hi = bf2f((ushort)(a >> 16)) + bf2f((ushort)(b >> 16))
             + bf2f((ushort)(c >> 16)) + bf2f((ushort)(d >> 16));
    out[idx] = make_float2(lo, hi);
}

// t1 = relu(x[:,4:10] @ enc_W1 + enc_b1), split into bf16 hi+lo; zero pad rows
__global__ void encoder1_kernel(const float* __restrict__ x, const float* __restrict__ W1,
                                const float* __restrict__ b1,
                                ushort* __restrict__ t1hi, ushort* __restrict__ t1lo)
{
    const int idx = blockIdx.x * blockDim.x + threadIdx.x;
    if (idx >= P_ROWS * H_DIM) return;
    const int i = idx / H_DIM, j = idx - i * H_DIM;
    float v = 0.f;
    if (i < N_NODES) {
        const float* xr = &x[i * 16 + 4];
        v = b1[j];
#pragma unroll
        for (int k = 0; k < 6; ++k) v = fmaf(xr[k], W1[k * H_DIM + j], v);
        v = fmaxf(v, 0.f);
    }
    const ushort hi = f2bf(v);
    t1hi[idx] = hi;
    t1lo[idx] = f2bf(v - bf2f(hi));
}

__global__ void zero_ints_kernel(int* __restrict__ p, int n)
{
    const int idx = blockIdx.x * blockDim.x + threadIdx.x;
    if (idx < n) p[idx] = 0;
}

__global__ void graph_bounds_kernel(const int* __restrict__ batch, int* __restrict__ gstart)
{
    const int g = threadIdx.x;
    if (g > G_GRAPHS) return;
    int lo = 0, hi = N_NODES;
    while (lo < hi) {
        const int mid = (lo + hi) >> 1;
        if (batch[mid] < g) lo = mid + 1; else hi = mid;
    }
    gstart[g] = lo;
}

__global__ __launch_bounds__(256)
void edge_hist_kernel(const int* __restrict__ src, const int* __restrict__ dst,
                      const int* __restrict__ batch,
                      int* __restrict__ part, int* __restrict__ deg)
{
    __shared__ int hist[G_GRAPHS];
    const int tid = threadIdx.x;
    if (tid < G_GRAPHS) hist[tid] = 0;
    __syncthreads();
    for (int e = blockIdx.x * 256 + tid; e < N_EDGES; e += EH_BLOCKS * 256) {
        atomicAdd(&deg[dst[e]], 1);
        atomicAdd(&hist[batch[src[e]]], 1);
    }
    __syncthreads();
    if (tid < G_GRAPHS) part[blockIdx.x * G_GRAPHS + tid] = hist[tid];
}

__global__ void stats_finalize_kernel(const int* __restrict__ gstart, const int* __restrict__ part,
                                      float* __restrict__ f_norm, float* __restrict__ size_norm)
{
    const int g = threadIdx.x;  // exactly 64
    const float nn = fmaxf((float)(gstart[g + 1] - gstart[g]), 1.0f);
    int ec = 0;
#pragma unroll 8
    for (int b = 0; b < EH_BLOCKS; ++b) ec += part[b * G_GRAPHS + g];
    const float ee = (float)ec;
    const float ln = logf(nn);
    const float le = log1pf(ee);
    float s0 = ln, s1 = le;
#pragma unroll
    for (int o = 32; o > 0; o >>= 1) { s0 += __shfl_xor(s0, o); s1 += __shfl_xor(s1, o); }
    const float m0 = s0 / 64.f, m1 = s1 / 64.f;
    const float d0 = ln - m0, d1 = le - m1;
    float v0 = d0 * d0, v1 = d1 * d1;
#pragma unroll
    for (int o = 32; o > 0; o >>= 1) { v0 += __shfl_xor(v0, o); v1 += __shfl_xor(v1, o); }
    const float sd0 = sqrtf(v0 / 64.f), sd1 = sqrtf(v1 / 64.f);
    float mn = ln, mx = ln;
#pragma unroll
    for (int o = 32; o > 0; o >>= 1) {
        mn = fminf(mn, __shfl_xor(mn, o));
        mx = fmaxf(mx, __shfl_xor(mx, o));
    }
    f_norm[g * 2 + 0] = d0 / (sd0 + 1e-6f);
    f_norm[g * 2 + 1] = d1 / (sd1 + 1e-6f);
    size_norm[g] = (ln - mn) / (mx - mn + 1e-6f);
}

__global__ void scan_kernel(const int* __restrict__ in, int* __restrict__ row_ptr,
                            int* __restrict__ cursor, int n)
{
    __shared__ int wsum[16];
    __shared__ int carry_s;
    const int tid = threadIdx.x;
    const int lane = tid & 63, wv = tid >> 6;
    if (tid == 0) carry_s = 0;
    __syncthreads();
    for (int base = 0; base < n; base += 1024) {
        const int idx = base + tid;
        const int v = (idx < n) ? in[idx] : 0;
        int x = v;
#pragma unroll
        for (int o = 1; o < 64; o <<= 1) { const int t = __shfl_up(x, o); if (lane >= o) x += t; }
        if (lane == 63) wsum[wv] = x;
        __syncthreads();
        const int carry = carry_s;
        if (wv == 0) {
            int y = (lane < 16) ? wsum[lane] : 0;
#pragma unroll
            for (int o = 1; o < 16; o <<= 1) { const int t = __shfl_up(y, o); if (lane >= o) y += t; }
            if (lane < 16) wsum[lane] = y;
        }
        __syncthreads();
        const int woff = (wv > 0) ? wsum[wv - 1] : 0;
        const int excl = x - v + woff + carry;
        if (idx < n) { row_ptr[idx] = excl; cursor[idx] = excl; }
        __syncthreads();
        if (tid == 0) carry_s = carry + wsum[15];
        __syncthreads();
    }
    if (tid == 0) row_ptr[n] = carry_s;
}

__global__ void scatter_kernel(const int* __restrict__ src, const int* __restrict__ dst,
                               int* __restrict__ cursor, int* __restrict__ csr_col)
{
    const int e = blockIdx.x * blockDim.x + threadIdx.x;
    if (e >= N_EDGES) return;
    const int d = dst[e];
    const int slot = atomicAdd(&cursor[d], 1);
    csr_col[slot] = src[e];
}

__global__ void sort_adj_kernel(const int* __restrict__ row_ptr, int* __restrict__ csr_col)
{
    const int i = blockIdx.x * blockDim.x + threadIdx.x;
    if (i >= N_NODES) return;
    const int b = row_ptr[i], e = row_ptr[i + 1];
    for (int p = b + 1; p < e; ++p) {
        const int key = csr_col[p];
        int q = p - 1;
        while (q >= b && csr_col[q] > key) { csr_col[q + 1] = csr_col[q]; --q; }
        csr_col[q + 1] = key;
    }
}

// agg[e][i,:] = sum over in-edges of z[e][src,:]
// wave-per-node, uint4 (16B/lane) loads; 4 nodes per 256-thr block. (R9-proven)
__global__ __launch_bounds__(256)
void aggregate_bf16(const uint4* __restrict__ z4, const int* __restrict__ row_ptr,
                    const int* __restrict__ csr_col, uint4* __restrict__ agg4)
{
    const size_t es = (size_t)blockIdx.y * P_ROWS * 64;   // uint4s per expert
    const uint4* __restrict__ zz = z4 + es;
    uint4* __restrict__ aa = agg4 + es;
    const int i = blockIdx.x * 4 + (threadIdx.x >> 6);     // node (grid 5000x4 exact)
    const int lane = threadIdx.x & 63;
    const int b = row_ptr[i], e = row_ptr[i + 1];
    float acc[8];
#pragma unroll
    for (int k = 0; k < 8; ++k) acc[k] = 0.f;
    auto add8 = [&](uint4 v) {
        acc[0] += bf2f((ushort)(v.x & 0xffffu)); acc[1] += bf2f((ushort)(v.x >> 16));
        acc[2] += bf2f((ushort)(v.y & 0xffffu)); acc[3] += bf2f((ushort)(v.y >> 16));
        acc[4] += bf2f((ushort)(v.z & 0xffffu)); acc[5] += bf2f((ushort)(v.z >> 16));
        acc[6] += bf2f((ushort)(v.w & 0xffffu)); acc[7] += bf2f((ushort)(v.w >> 16));
    };
    int p = b;
    for (; p + 2 <= e; p += 2) {
        const uint4 v0 = zz[(size_t)csr_col[p] * 64 + lane];
        const uint4 v1 = zz[(size_t)csr_col[p + 1] * 64 + lane];
        add8(v0);
        add8(v1);
    }
    if (p < e) add8(zz[(size_t)csr_col[p] * 64 + lane]);
    uint4 o;
    o.x = (uint)f2bf(acc[0]) | ((uint)f2bf(acc[1]) << 16);
    o.y = (uint)f2bf(acc[2]) | ((uint)f2bf(acc[3]) << 16);
    o.z = (uint)f2bf(acc[4]) | ((uint)f2bf(acc[5]) << 16);
    o.w = (uint)f2bf(acc[6]) | ((uint)f2bf(acc[7]) << 16);
    aa[(size_t)i * 64 + lane] = o;
}

// one 512x512 matrix per blockIdx.z: Wt[n][k] = bf16(W[k][n])
__global__ __launch_bounds__(256)
void transpose_f32_to_bf16(const float* __restrict__ W, ushort* __restrict__ Wt)
{
    __shared__ float tile[32][33];
    const float* Wm = W + (size_t)blockIdx.z * WSZ;
    ushort* Wtm = Wt + (size_t)blockIdx.z * WSZ;
    const int c0 = blockIdx.x * 32, r0 = blockIdx.y * 32;
    const int tc = threadIdx.x & 31, tr = threadIdx.x >> 5;
#pragma unroll
    for (int it = 0; it < 4; ++it)
        tile[tr + it * 8][tc] = Wm[(size_t)(r0 + tr + it * 8) * 512 + c0 + tc];
    __syncthreads();
#pragma unroll
    for (int it = 0; it < 4; ++it) {
        const int cr = tr + it * 8;
        Wtm[(size_t)(c0 + cr) * 512 + r0 + tc] = f2bf(tile[tc][cr]);
    }
}

// W [512][Nin] fp32 -> Wt hi/lo [Nin][512] bf16 (k-stride 512)
__global__ __launch_bounds__(256)
void transpose_split_kernel(const float* __restrict__ W, ushort* __restrict__ Whi,
                            ushort* __restrict__ Wlo, int Nin)
{
    __shared__ float tile[32][33];
    const int c0 = blockIdx.x * 32;
    const int r0 = blockIdx.y * 32;
    const int tc = threadIdx.x & 31, tr = threadIdx.x >> 5;
#pragma unroll
    for (int it = 0; it < 4; ++it)
        tile[tr + it * 8][tc] = W[(size_t)(r0 + tr + it * 8) * Nin + c0 + tc];
    __syncthreads();
#pragma unroll
    for (int it = 0; it < 4; ++it) {
        const int cr = tr + it * 8;
        const float v = tile[tc][cr];
        const ushort hi = f2bf(v);
        Whi[(size_t)(c0 + cr) * 512 + r0 + tc] = hi;
        Wlo[(size_t)(c0 + cr) * 512 + r0 + tc] = f2bf(v - bf2f(hi));
    }
}

// router tail (fp32)
__global__ __launch_bounds__(128)
void router_kernel(const float* __restrict__ rtmp, const int* __restrict__ batch,
                   const float* __restrict__ rW1, const float* __restrict__ rb1,
                   const float* __restrict__ lng, const float* __restrict__ lnb,
                   const float* __restrict__ rW2, const float* __restrict__ rb2,
                   const float* __restrict__ centers,
                   const float* __restrict__ f_norm, const float* __restrict__ size_norm,
                   float* __restrict__ weights)
{
    const int i = blockIdx.x;
    const int j = threadIdx.x;
    const int g = batch[i];
    const float f0 = f_norm[g * 2], f1 = f_norm[g * 2 + 1];
    float r = rtmp[(size_t)i * RH_DIM + j]
            + f0 * rW1[512 * RH_DIM + j] + f1 * rW1[513 * RH_DIM + j] + rb1[j];

    __shared__ float part[2];
    __shared__ float rbuf[RH_DIM];
    __shared__ float lbuf[4];
    const int lane = j & 63, wv = j >> 6;

    float s = r;
#pragma unroll
    for (int o = 32; o > 0; o >>= 1) s += __shfl_xor(s, o);
    if (lane == 0) part[wv] = s;
    __syncthreads();
    const float mean = (part[0] + part[1]) / 128.f;
    __syncthreads();
    const float d = r - mean;
    float v = d * d;
#pragma unroll
    for (int o = 32; o > 0; o >>= 1) v += __shfl_xor(v, o);
    if (lane == 0) part[wv] = v;
    __syncthreads();
    const float var = (part[0] + part[1]) / 128.f;
    const float rn = d / sqrtf(var + 1e-5f) * lng[j] + lnb[j];
    rbuf[j] = fmaxf(rn, 0.f);
    __syncthreads();

    if (j < 4) {
        float acc = rb2[j];
        for (int t = 0; t < RH_DIM; ++t) acc = fmaf(rbuf[t], rW2[t * 4 + j], acc);
        const float sn = size_norm[g];
        const float dd = sn - centers[j];
        lbuf[j] = 0.7f * acc + 0.3f * (-(dd * dd));
    }
    __syncthreads();
    if (j == 0) {
        float p[4];
        const float mx = fmaxf(fmaxf(lbuf[0], lbuf[1]), fmaxf(lbuf[2], lbuf[3]));
#pragma unroll
        for (int c = 0; c < 4; ++c) p[c] = expf(lbuf[c] - mx);
        const float ssum = p[0] + p[1] + p[2] + p[3];
#pragma unroll
        for (int c = 0; c < 4; ++c) p[c] /= ssum;
        int i1 = 0;
#pragma unroll
        for (int c = 1; c < 4; ++c) if (p[c] > p[i1]) i1 = c;
        int i2 = -1;
#pragma unroll
        for (int c = 0; c < 4; ++c) {
            if (c == i1) continue;
            if (i2 < 0 || p[c] > p[i2]) i2 = c;
        }
        const float vs = p[i1] + p[i2] + 1e-8f;
        float wout[4] = {0.f, 0.f, 0.f, 0.f};
        wout[i1] = p[i1] / vs;
        wout[i2] = p[i2] / vs;
#pragma unroll
        for (int c = 0; c < 4; ++c) weights[(size_t)i * 4 + c] = wout[c];
    }
}

extern "C" void kernel_launch(void* const* d_in, const int* in_sizes, int n_in,
                              void* d_out, int out_size, void* d_ws, size_t ws_size,
                              hipStream_t stream)
{
    const float* x       = (const float*)d_in[0];
    const int*   ei      = (const int*)d_in[1];
    const int*   batch   = (const int*)d_in[2];
    const float* enc_W1  = (const float*)d_in[4];
    const float* enc_b1  = (const float*)d_in[5];
    const float* enc_W2  = (const float*)d_in[6];
    const float* enc_b2  = (const float*)d_in[7];
    const float* r_W1    = (const float*)d_in[8];
    const float* r_b1    = (const float*)d_in[9];
    const float* ln_g    = (const float*)d_in[10];
    const float* ln_b    = (const float*)d_in[11];
    const float* r_W2    = (const float*)d_in[12];
    const float* r_b2    = (const float*)d_in[13];
    const float* centers = (const float*)d_in[14];
    const float* W_rel   = (const float*)d_in[15];
    const float* b_rel   = (const float*)d_in[16];
    const float* W_root  = (const float*)d_in[17];
    const int* src = ei;
    const int* dst = ei + N_EDGES;
    float* out = (float*)d_out;

    const size_t PF = (size_t)P_ROWS * H_DIM;
    const size_t PF2 = PF * 2;
    // mode selection (deterministic: ws_size fixed).
    // base (non-z buffers) ~118MB. PAIR: +6*PF2 ~241MB (proven fits).
    // HYB (zA 4-wide): +8*PF2 ~283MB. FULL (all 4-wide): +12*PF2 ~365MB.
    const int mode = (ws_size >= (size_t)375 * 1024 * 1024) ? 2
                   : (ws_size >= (size_t)295 * 1024 * 1024) ? 1 : 0;
    const int zaW = (mode >= 1) ? 4 : 2;
    const int zbW = (mode == 2) ? 4 : 2;

    char* wsp = (char*)d_ws;
    size_t off = 0;
    auto alloc = [&](size_t bytes) -> char* {
        char* p = wsp + off;
        off = (off + bytes + 255) & ~(size_t)255;
        return p;
    };
    // region1+region2 contiguous: t1hi|t1lo , h_hi|h_lo -> later wz4 (4 x PF bf16)
    char* region1 = alloc(PF * 4);
    ushort* t1hi = (ushort*)region1;
    ushort* t1lo = (ushort*)(region1 + PF * 2);
    ushort* wz4  = (ushort*)region1;           // spans region1+region2
    char* region2 = alloc(PF * 4);
    ushort* h_hi = (ushort*)region2;
    ushort* h_lo = (ushort*)(region2 + PF * 2);
    // z/agg buffers; rtmp fp32 aliases zA start (dead before expert L0)
    char* B_zA = alloc(PF2 * zaW);
    ushort* zAe = (ushort*)B_zA;
    float*  rtmp = (float*)B_zA;
    char* B_zB = alloc(PF2 * zbW);
    ushort* zBe = (ushort*)B_zB;
    char* B_ag = alloc(PF2 * zbW);
    ushort* agge = (ushort*)B_ag;
    ushort* aggH16 = (ushort*)alloc(PF * 2);
    ushort* Wt_rel16  = (ushort*)alloc((size_t)12 * WSZ * 2);
    ushort* Wt_root16 = (ushort*)alloc((size_t)12 * WSZ * 2);
    ushort* W2t_hi = (ushort*)alloc((size_t)WSZ * 2);
    ushort* W2t_lo = (ushort*)alloc((size_t)WSZ * 2);
    ushort* rW1t_hi = (ushort*)alloc((size_t)128 * 512 * 2);
    ushort* rW1t_lo = (ushort*)alloc((size_t)128 * 512 * 2);
    float*  weights = (float*)alloc((size_t)P_ROWS * 4 * 4);
    int* deg     = (int*)alloc((size_t)N_NODES * 4);
    int* gstart  = (int*)alloc((size_t)(G_GRAPHS + 1) * 4);
    int* part    = (int*)alloc((size_t)EH_BLOCKS * G_GRAPHS * 4);
    int* row_ptr = (int*)alloc((size_t)(N_NODES + 1) * 4);
    int* cursor  = (int*)alloc((size_t)N_NODES * 4);
    int* csr_col = (int*)alloc((size_t)N_EDGES * 4);
    float* f_norm    = (float*)alloc((size_t)G_GRAPHS * 2 * 4);
    float* size_norm = (float*)alloc((size_t)G_GRAPHS * 4);
    (void)in_sizes; (void)n_in; (void)out_size;

    const int enc_nwg  = 4 * (P_ROWS / 128);   // 628
    const int rtr_nwg  = 1 * (P_ROWS / 128);   // 157
    const int grp_nwg2 = 8 * (P_ROWS / 128);   // 1256 (pair)
    const int grp_nwg4 = 16 * (P_ROWS / 128);  // 2512 (4-expert)
    const dim3 tr_grid(16, 16, 12);
    const dim3 agg_grid1(N_NODES / 4, 1);
    const dim3 agg_grid2(N_NODES / 4, 2);
    const dim3 agg_grid4(N_NODES / 4, 4);

    // 0) zero deg + one-time weight transposes/splits
    zero_ints_kernel<<<(N_NODES + 255) / 256, 256, 0, stream>>>(deg, N_NODES);
    transpose_f32_to_bf16<<<tr_grid, 256, 0, stream>>>(W_rel, Wt_rel16);
    transpose_f32_to_bf16<<<tr_grid, 256, 0, stream>>>(W_root, Wt_root16);
    transpose_split_kernel<<<dim3(16, 16), 256, 0, stream>>>(enc_W2, W2t_hi, W2t_lo, 512);
    transpose_split_kernel<<<dim3(4, 16), 256, 0, stream>>>(r_W1, rW1t_hi, rW1t_lo, 128);
    // 1) graph stats (contention-free)
    graph_bounds_kernel<<<1, 128, 0, stream>>>(batch, gstart);
    edge_hist_kernel<<<EH_BLOCKS, 256, 0, stream>>>(src, dst, batch, part, deg);
    stats_finalize_kernel<<<1, 64, 0, stream>>>(gstart, part, f_norm, size_norm);
    // 2) encoder: t1 (split) then h = t1@W2 via bf16x3 -> h_hi/h_lo
    encoder1_kernel<<<(P_ROWS * H_DIM + 255) / 256, 256, 0, stream>>>(x, enc_W1, enc_b1, t1hi, t1lo);
    gemm_mfma<3, 4, 4><<<enc_nwg, 256, 0, stream>>>(
        t1hi, W2t_hi, t1hi, W2t_lo, t1lo, W2t_hi, enc_b2, h_hi, h_lo, 512);
    // 3) router: rtmp = h@rW1 via bf16x3 (t1 region dead now)
    gemm_mfma<3, 5, 1><<<rtr_nwg, 256, 0, stream>>>(
        h_hi, rW1t_hi, h_hi, rW1t_lo, h_lo, rW1t_hi, nullptr, rtmp, nullptr, 128);
    router_kernel<<<N_NODES, 128, 0, stream>>>(rtmp, batch, r_W1, r_b1, ln_g, ln_b,
                                               r_W2, r_b2, centers, f_norm, size_norm, weights);
    // 4) CSR build (deterministic: sorted adjacency)
    scan_kernel<<<1, 1024, 0, stream>>>(deg, row_ptr, cursor, N_NODES);
    scatter_kernel<<<(N_EDGES + 255) / 256, 256, 0, stream>>>(src, dst, cursor, csr_col);
    sort_adj_kernel<<<(N_NODES + 255) / 256, 256, 0, stream>>>(row_ptr, csr_col);
    // 5) shared layer-0 aggregation
    aggregate_bf16<<<agg_grid1, 256, 0, stream>>>((const uint4*)h_hi, row_ptr, csr_col,
                                                  (uint4*)aggH16);

    // 6) experts (proven 128x128 GEMM)
    const size_t WES = (size_t)3 * WSZ;   // expert stride in Wt buffers
    const size_t BES = (size_t)3 * 512;   // expert stride in b_rel
    if (mode == 2) {
        // all 4 experts per dispatch for every layer
        gemm_grp<true, 0, 4><<<grp_nwg4, 256, 0, stream>>>(
            aggH16, 0, Wt_rel16, WES, h_hi, 0, Wt_root16, WES, b_rel, BES, nullptr, zAe, PF);
        aggregate_bf16<<<agg_grid4, 256, 0, stream>>>((const uint4*)zAe, row_ptr, csr_col,
                                                      (uint4*)agge);
        gemm_grp<true, 0, 4><<<grp_nwg4, 256, 0, stream>>>(
            agge, PF, Wt_rel16 + WSZ, WES, zAe, PF, Wt_root16 + WSZ, WES, b_rel + 512, BES,
            nullptr, zBe, PF);
        aggregate_bf16<<<agg_grid4, 256, 0, stream>>>((const uint4*)zBe, row_ptr, csr_col,
                                                      (uint4*)agge);
        gemm_grp<false, 6, 4><<<grp_nwg4, 256, 0, stream>>>(
            agge, PF, Wt_rel16 + 2 * WSZ, WES, zBe, PF, Wt_root16 + 2 * WSZ, WES, b_rel + 1024, BES,
            weights, wz4, PF);
    } else if (mode == 1) {
        // L0 merged across 4 experts (shared A operands); L1/L2 paired
        gemm_grp<true, 0, 4><<<grp_nwg4, 256, 0, stream>>>(
            aggH16, 0, Wt_rel16, WES, h_hi, 0, Wt_root16, WES, b_rel, BES, nullptr, zAe, PF);
        for (int p = 0; p < 2; ++p) {
            const size_t eb = (size_t)(p * 2);
            const ushort* WrP = Wt_rel16  + eb * WES;
            const ushort* WoP = Wt_root16 + eb * WES;
            const float*  brP = b_rel + eb * BES;
            const ushort* zAp = zAe + eb * PF;
            ushort* wzP = wz4 + eb * PF;
            aggregate_bf16<<<agg_grid2, 256, 0, stream>>>((const uint4*)zAp, row_ptr, csr_col,
                                                          (uint4*)agge);
            gemm_grp<true, 0, 2><<<grp_nwg2, 256, 0, stream>>>(
                agge, PF, WrP + WSZ, WES, zAp, PF, WoP + WSZ, WES, brP + 512, BES, nullptr, zBe, PF);
            aggregate_bf16<<<agg_grid2, 256, 0, stream>>>((const uint4*)zBe, row_ptr, csr_col,
                                                          (uint4*)agge);
            gemm_grp<false, 6, 2><<<grp_nwg2, 256, 0, stream>>>(
                agge, PF, WrP + 2 * WSZ, WES, zBe, PF, WoP + 2 * WSZ, WES, brP + 1024, BES,
                weights + eb, wzP, PF);
        }
    } else {
        // proven pair path (R6/R8)
        for (int p = 0; p < 2; ++p) {
            const size_t eb = (size_t)(p * 2);
            const ushort* WrP = Wt_rel16  + eb * WES;
            const ushort* WoP = Wt_root16 + eb * WES;
            const float*  brP = b_rel + eb * BES;
            ushort* wzP = wz4 + eb * PF;
            gemm_grp<true, 0, 2><<<grp_nwg2, 256, 0, stream>>>(
                aggH16, 0, WrP, WES, h_hi, 0, WoP, WES, brP, BES, nullptr, zAe, PF);
            aggregate_bf16<<<agg_grid2, 256, 0, stream>>>((const uint4*)zAe, row_ptr, csr_col,
                                                          (uint4*)agge);
            gemm_grp<true, 0, 2><<<grp_nwg2, 256, 0, stream>>>(
                agge, PF, WrP + WSZ, WES, zAe, PF, WoP + WSZ, WES, brP + 512, BES, nullptr, zBe, PF);
            aggregate_bf16<<<agg_grid2, 256, 0, stream>>>((const uint4*)zBe, row_ptr, csr_col,
                                                          (uint4*)agge);
            gemm_grp<false, 6, 2><<<grp_nwg2, 256, 0, stream>>>(
                agge, PF, WrP + 2 * WSZ, WES, zBe, PF, WoP + 2 * WSZ, WES, brP + 1024, BES,
                weights + eb, wzP, PF);
        }
    }
    // 7) out = sum_e wz[e]
    reduce_wz_kernel<<<N_NODES, 256, 0, stream>>>((const uint*)wz4, (float2*)out);
}